// Round 9
// baseline (494.892 us; speedup 1.0000x reference)
//
#include <hip/hip_runtime.h>
#include <math.h>

#define BB 4
#define HH 8
#define TT 4096
#define DD 64
#define NCC 64
#define WSZW 128
#define TPK 160          // widened f32 top-k; f64 rescore picks exact top-128
#define MEMN 1
#define KVW (MEMN + WSZW)   // 129
constexpr float EPSF = 1e-5f;
constexpr float SCALE = 0.125f;  // 64^-0.5

typedef __attribute__((ext_vector_type(8))) short bf16x8;
typedef __attribute__((ext_vector_type(4))) float f32x4;

static __device__ __forceinline__ unsigned short f2bf(float f) {
    union { float f; unsigned int u; } v; v.f = f;
    unsigned int r = v.u + 0x7FFFu + ((v.u >> 16) & 1u);   // RNE
    return (unsigned short)(r >> 16);
}
static __device__ __forceinline__ unsigned int pk2(float a, float b) {
    return (unsigned int)f2bf(a) | ((unsigned int)f2bf(b) << 16);
}
static __device__ __forceinline__ bf16x8 pack8(float4 a, float4 b) {
    bf16x8 r;
    r[0]=(short)f2bf(a.x); r[1]=(short)f2bf(a.y); r[2]=(short)f2bf(a.z); r[3]=(short)f2bf(a.w);
    r[4]=(short)f2bf(b.x); r[5]=(short)f2bf(b.y); r[6]=(short)f2bf(b.z); r[7]=(short)f2bf(b.w);
    return r;
}

// ---------------- Kernel A: dists as tiled f32 GEMM + argmax + aux identity ------
// (round-5 kernel: selection precision recovered downstream by rescore_kernel)
__global__ __launch_bounds__(256, 4) void dists_kernel(
    const float* __restrict__ q, const float* __restrict__ k,
    const float* __restrict__ means,
    float* __restrict__ distsQ, float* __restrict__ distsK,
    float* __restrict__ aux_sum)
{
    __shared__ float xS[64][68];   // [d][tok]; reused as dS[tok][c] after GEMM
    __shared__ float mS[64][68];   // [d][cluster]
    __shared__ float mqS[64];      // per-cluster ||m||^2

    const int chunks = (2 * TT) / 64;          // 128
    int bid = blockIdx.x;                      // 4096
    int bh = bid / chunks;
    int chunk = bid % chunks;
    int h = bh % HH;
    bool isQ = chunk < (TT / 64);
    int tbase = (isQ ? chunk : chunk - 64) * 64;
    const float* src = (isQ ? q : k) + ((size_t)bh * TT + tbase) * DD;
    float* dst = isQ ? distsQ : distsK;

    int tid = threadIdx.x;
    int tok = tid >> 2, part = tid & 3;        // tok doubles as cluster idx below

    // ---- stage means (transposed) + per-cluster sumsq ----
    {
        const float* mp = means + ((size_t)h * NCC + tok) * DD + part * 16;
        float4 va[4];
        #pragma unroll
        for (int i = 0; i < 4; ++i) va[i] = *(const float4*)(mp + i * 4);
        float msq = 0.f;
        #pragma unroll
        for (int i = 0; i < 4; ++i) {
            msq += va[i].x*va[i].x + va[i].y*va[i].y + va[i].z*va[i].z + va[i].w*va[i].w;
            int d = part * 16 + i * 4;
            mS[d][tok] = va[i].x; mS[d+1][tok] = va[i].y;
            mS[d+2][tok] = va[i].z; mS[d+3][tok] = va[i].w;
        }
        msq += __shfl_xor(msq, 1);
        msq += __shfl_xor(msq, 2);
        if (part == 0) mqS[tok] = msq;
    }
    // ---- stage x normalized (transposed) ----
    float ssn;
    {
        const float* xp = src + (size_t)tok * DD + part * 16;
        float4 va[4];
        #pragma unroll
        for (int i = 0; i < 4; ++i) va[i] = *(const float4*)(xp + i * 4);
        float ss = 0.f;
        #pragma unroll
        for (int i = 0; i < 4; ++i)
            ss += va[i].x*va[i].x + va[i].y*va[i].y + va[i].z*va[i].z + va[i].w*va[i].w;
        ss += __shfl_xor(ss, 1);
        ss += __shfl_xor(ss, 2);
        float inv = 1.f / fmaxf(sqrtf(ss), 1e-12f);
        ssn = ss * inv * inv;
        #pragma unroll
        for (int i = 0; i < 4; ++i) {
            int d = part * 16 + i * 4;
            xS[d][tok] = va[i].x*inv; xS[d+1][tok] = va[i].y*inv;
            xS[d+2][tok] = va[i].z*inv; xS[d+3][tok] = va[i].w*inv;
        }
    }
    __syncthreads();

    // ---- GEMM: thread = 4 tokens x 4 clusters ----
    int l = tid & 63, w = tid >> 6;
    int ti = l & 15;                 // token tile 4*ti..
    int ci = w * 4 + (l >> 4);       // cluster tile 4*ci..
    float acc[4][4];
    #pragma unroll
    for (int i = 0; i < 4; ++i)
        #pragma unroll
        for (int j = 0; j < 4; ++j) acc[i][j] = 0.f;

    #pragma unroll 16
    for (int kk = 0; kk < 64; ++kk) {
        float4 xv = *(const float4*)(&xS[kk][ti * 4]);
        float4 mv = *(const float4*)(&mS[kk][ci * 4]);
        float xa[4] = {xv.x, xv.y, xv.z, xv.w};
        float ma[4] = {mv.x, mv.y, mv.z, mv.w};
        #pragma unroll
        for (int i = 0; i < 4; ++i)
            #pragma unroll
            for (int j = 0; j < 4; ++j) acc[i][j] += xa[i] * ma[j];
    }

    // ---- store dists to global (coalesced float4 over tokens) ----
    {
        size_t rowb = (size_t)(bh * NCC) * TT;
        #pragma unroll
        for (int j = 0; j < 4; ++j) {
            int c = ci * 4 + j;
            float4 o;
            o.x = acc[0][j]; o.y = acc[1][j]; o.z = acc[2][j]; o.w = acc[3][j];
            *(float4*)&dst[rowb + (size_t)c * TT + tbase + ti * 4] = o;
        }
    }

    // ---- argmax + aux via LDS round-trip (reuse xS as dS[tok][c]) ----
    __syncthreads();
    #pragma unroll
    for (int i = 0; i < 4; ++i)
        #pragma unroll
        for (int j = 0; j < 4; ++j)
            xS[ti * 4 + i][ci * 4 + j] = acc[i][j];
    __syncthreads();

    float bv = -1e30f; int bc = 0;
    #pragma unroll
    for (int j = 0; j < 16; ++j) {
        int c = part * 16 + j;
        float vv = xS[tok][c];
        if (vv > bv) { bv = vv; bc = c; }
    }
    #pragma unroll
    for (int off = 1; off <= 2; off <<= 1) {
        float ov = __shfl_xor(bv, off);
        int   oc = __shfl_xor(bc, off);
        if (ov > bv || (ov == bv && oc < bc)) { bv = ov; bc = oc; }
    }
    float auxv = (part == 0) ? (ssn + mqS[bc] - 2.f * bv) : 0.f;
    #pragma unroll
    for (int off = 32; off; off >>= 1) auxv += __shfl_xor(auxv, off);
    if (l == 0) atomicAdd(aux_sum, auxv);
}

// ---------------- Kernel B: top-TPK per row via 4-pass radix select ----------------
__global__ __launch_bounds__(256) void topk_kernel(
    const float* __restrict__ dists, int* __restrict__ idxOut)
{
    int row = blockIdx.x;
    const float* dv = dists + (size_t)row * TT;
    int t = threadIdx.x;

    unsigned u[16];
    #pragma unroll
    for (int j = 0; j < 16; ++j) {
        unsigned b = __float_as_uint(dv[j * 256 + t]);
        u[j] = (b & 0x80000000u) ? ~b : (b | 0x80000000u);
    }

    __shared__ int hist[256];
    __shared__ int sfx[256];
    __shared__ int binSel, tgtS;
    __shared__ int nGtS, posS, eqFilled;
    __shared__ int waveCnt[4];

    int target = TPK;
    unsigned prefix = 0;

    for (int shift = 24; shift >= 0; shift -= 8) {
        hist[t] = 0;
        __syncthreads();
        #pragma unroll
        for (int j = 0; j < 16; ++j) {
            bool act = (shift == 24) || ((u[j] >> (shift + 8)) == (prefix >> (shift + 8)));
            if (act) atomicAdd(&hist[(u[j] >> shift) & 255], 1);
        }
        __syncthreads();
        sfx[t] = hist[t];
        __syncthreads();
        for (int off = 1; off < 256; off <<= 1) {
            int add = (t + off < 256) ? sfx[t + off] : 0;
            int cur = sfx[t];
            __syncthreads();
            sfx[t] = cur + add;
            __syncthreads();
        }
        int nxt = (t == 255) ? 0 : sfx[t + 1];
        if (sfx[t] >= target && nxt < target) { binSel = t; tgtS = target - nxt; }
        __syncthreads();
        prefix |= ((unsigned)binSel) << shift;
        target = tgtS;
        __syncthreads();
    }

    unsigned pivot = prefix;
    if (t == 0) { nGtS = 0; posS = 0; eqFilled = 0; }
    __syncthreads();
    int myg = 0;
    #pragma unroll
    for (int j = 0; j < 16; ++j) myg += (u[j] > pivot) ? 1 : 0;
    if (myg) atomicAdd(&nGtS, myg);
    __syncthreads();
    int n_gt = nGtS;
    int n_need = TPK - n_gt;
    int* out = idxOut + (size_t)row * TPK;

    #pragma unroll
    for (int j = 0; j < 16; ++j)
        if (u[j] > pivot) { int p = atomicAdd(&posS, 1); out[p] = j * 256 + t; }

    int lane = t & 63, wv = t >> 6;
    for (int j = 0; j < 16; ++j) {
        if (eqFilled >= n_need) break;
        bool fl = (u[j] == pivot);
        unsigned long long bal = __ballot(fl);
        if (lane == 0) waveCnt[wv] = __popcll(bal);
        __syncthreads();
        int offw = 0;
        for (int w = 0; w < wv; ++w) offw += waveCnt[w];
        int mypos = eqFilled + offw + __popcll(bal & ((lane ? ((1ull << lane) - 1ull) : 0ull)));
        if (fl && mypos < n_need) out[n_gt + mypos] = j * 256 + t;
        __syncthreads();
        if (t == 0) eqFilled += waveCnt[0] + waveCnt[1] + waveCnt[2] + waveCnt[3];
        __syncthreads();
    }
}

// ---------------- Kernel B2: f64 rescore of TPK candidates -> exact top-128 ----
// grid 4096: rid = side*2048 + bh*NC + c. Recomputes dist in the exact f64 path
// (f64 dot, 1/max(sqrt,1e-12)), strict total order (value desc, token asc),
// keeps rank<128, compacts to idxQ/idxK.
__global__ __launch_bounds__(192) void rescore_kernel(
    const float* __restrict__ q, const float* __restrict__ k,
    const float* __restrict__ means,
    const int* __restrict__ candQ, const int* __restrict__ candK,
    int* __restrict__ idxQ, int* __restrict__ idxK)
{
    int rid = blockIdx.x;
    int side = rid >> 11;            // 0=Q, 1=K
    int row = rid & 2047;            // bh*NC + c
    int c = row & (NCC - 1);
    int bh = row >> 6;
    int h = bh % HH;

    const int* cand = (side ? candK : candQ) + (size_t)row * TPK;
    int* outIdx     = (side ? idxK : idxQ) + (size_t)row * WSZW;
    const float* xbase = (side ? k : q) + (size_t)bh * TT * DD;

    __shared__ double mD[DD];
    __shared__ double vS[TPK];
    __shared__ int    kiS[TPK];
    __shared__ int    wcnt[3];

    int tid = threadIdx.x;
    if (tid < DD) mD[tid] = (double)means[((size_t)h * NCC + c) * DD + tid];
    __syncthreads();

    double v = 0.0; int tok = 0x7FFFFFFF;
    if (tid < TPK) {
        tok = cand[tid];
        const float* xp = xbase + (size_t)tok * DD;
        double dot = 0.0, ss = 0.0;
        #pragma unroll
        for (int d = 0; d < DD; d += 4) {
            float4 va = *(const float4*)(xp + d);
            dot += (double)va.x * mD[d]   + (double)va.y * mD[d+1]
                 + (double)va.z * mD[d+2] + (double)va.w * mD[d+3];
            ss  += (double)va.x * va.x + (double)va.y * va.y
                 + (double)va.z * va.z + (double)va.w * va.w;
        }
        v = dot * (1.0 / fmax(sqrt(ss), 1e-12));
        vS[tid] = v; kiS[tid] = tok;
    }
    __syncthreads();

    bool keep = false;
    if (tid < TPK) {
        int rank = 0;
        for (int j = 0; j < TPK; ++j) {
            double vj = vS[j];
            rank += (vj > v || (vj == v && kiS[j] < tok)) ? 1 : 0;
        }
        keep = rank < WSZW;
    }
    int l = tid & 63, w = tid >> 6;
    unsigned long long bal = __ballot(keep);
    if (l == 0) wcnt[w] = __popcll(bal);
    __syncthreads();
    int base = 0;
    for (int ww = 0; ww < w; ++ww) base += wcnt[ww];
    int off = __popcll(bal & ((l ? ((1ull << l) - 1ull) : 0ull)));
    if (keep) outIdx[base + off] = tok;
}

// ---------------- Kernel C: bf16 MFMA attention -> dense so[] ----------------
__global__ __launch_bounds__(512, 2) void attn_kernel(
    const float* __restrict__ q, const float* __restrict__ k, const float* __restrict__ v,
    const float* __restrict__ mem_key, const float* __restrict__ mem_value,
    const int* __restrict__ idxQ, const int* __restrict__ idxK,
    float* __restrict__ so)
{
    int blk = blockIdx.x;        // bh*NC + c
    int c = blk % NCC;
    int bh = blk / NCC;
    int h = bh % HH;

    __shared__ __align__(16) unsigned short KsS[160 * 64];   // swizzled
    __shared__ __align__(16) unsigned short VsS[160 * 80];   // linear, stride 80
    __shared__ __align__(16) unsigned short PwS[8 * 16 * 40];

    int tid = threadIdx.x;

    if (tid < 320) {
        int row = tid >> 1, hh = tid & 1;
        const float* ksrc = nullptr; const float* vsrc = nullptr;
        if (row == 0) {
            ksrc = mem_key   + ((size_t)h * NCC + c) * (MEMN * DD);
            vsrc = mem_value + ((size_t)h * NCC + c) * (MEMN * DD);
        } else if (row < KVW) {
            int tk = idxK[(size_t)blk * WSZW + row - 1];
            ksrc = k + ((size_t)bh * TT + tk) * DD;
            vsrc = v + ((size_t)bh * TT + tk) * DD;
        }
        #pragma unroll
        for (int cch = 0; cch < 4; ++cch) {
            uint4 kw = {0,0,0,0}, vw = {0,0,0,0};
            if (ksrc) {
                int base = hh * 32 + cch * 8;
                float4 a = *(const float4*)(ksrc + base);
                float4 b = *(const float4*)(ksrc + base + 4);
                kw.x = pk2(a.x, a.y); kw.y = pk2(a.z, a.w);
                kw.z = pk2(b.x, b.y); kw.w = pk2(b.z, b.w);
                a = *(const float4*)(vsrc + base);
                b = *(const float4*)(vsrc + base + 4);
                vw.x = pk2(a.x, a.y); vw.y = pk2(a.z, a.w);
                vw.z = pk2(b.x, b.y); vw.w = pk2(b.z, b.w);
            }
            int chunk = hh * 4 + cch;
            int phys = chunk ^ (row & 7);
            *reinterpret_cast<uint4*>(&KsS[row * 64 + phys * 8]) = kw;
            *reinterpret_cast<uint4*>(&VsS[row * 80 + chunk * 8]) = vw;
        }
    }

    int w = tid >> 6, l = tid & 63;
    int lr = l & 15, lg = l >> 4;

    bf16x8 qf[2];
    {
        int tq = idxQ[(size_t)blk * WSZW + w * 16 + lr];
        const float* qp = q + ((size_t)bh * TT + tq) * DD;
        #pragma unroll
        for (int ks = 0; ks < 2; ++ks) {
            float4 a = *(const float4*)(qp + ks * 32 + lg * 8);
            float4 b = *(const float4*)(qp + ks * 32 + lg * 8 + 4);
            qf[ks] = pack8(a, b);
        }
    }

    f32x4 acc[4];
    #pragma unroll
    for (int dt = 0; dt < 4; ++dt) acc[dt] = (f32x4){0.f, 0.f, 0.f, 0.f};
    float s_acc[4] = {0.f, 0.f, 0.f, 0.f};

    __syncthreads();

    unsigned short* Pw = &PwS[w * 640];

    for (int kb = 0; kb < 5; ++kb) {
        bf16x8 kf[2][2];
        #pragma unroll
        for (int kvt = 0; kvt < 2; ++kvt)
            #pragma unroll
            for (int ks = 0; ks < 2; ++ks) {
                int row = kb * 32 + kvt * 16 + lr;
                int chunk = ks * 4 + lg;
                int phys = chunk ^ (row & 7);
                kf[kvt][ks] = *reinterpret_cast<const bf16x8*>(&KsS[row * 64 + phys * 8]);
            }
        #pragma unroll
        for (int kvt = 0; kvt < 2; ++kvt) {
            f32x4 sf = __builtin_amdgcn_mfma_f32_16x16x32_bf16(
                qf[0], kf[kvt][0], (f32x4){0.f,0.f,0.f,0.f}, 0, 0, 0);
            sf = __builtin_amdgcn_mfma_f32_16x16x32_bf16(qf[1], kf[kvt][1], sf, 0, 0, 0);
            int kvcol = kb * 32 + kvt * 16 + lr;
            bool valid = kvcol < KVW;
            #pragma unroll
            for (int r = 0; r < 4; ++r) {
                float e = valid ? __expf(sf[r] * SCALE) : 0.f;
                s_acc[r] += e;
                Pw[(lg * 4 + r) * 40 + kvt * 16 + lr] = f2bf(e);
            }
        }
        __builtin_amdgcn_sched_barrier(0);
        asm volatile("s_waitcnt lgkmcnt(0)" ::: "memory");
        __builtin_amdgcn_sched_barrier(0);
        bf16x8 pf = *reinterpret_cast<const bf16x8*>(&Pw[lr * 40 + lg * 8]);
        #pragma unroll
        for (int dt = 0; dt < 4; ++dt) {
            bf16x8 vf;
            #pragma unroll
            for (int j = 0; j < 8; ++j)
                vf[j] = (short)VsS[(kb * 32 + lg * 8 + j) * 80 + dt * 16 + lr];
            acc[dt] = __builtin_amdgcn_mfma_f32_16x16x32_bf16(pf, vf, acc[dt], 0, 0, 0);
        }
        __builtin_amdgcn_sched_barrier(0);
        asm volatile("s_waitcnt lgkmcnt(0)" ::: "memory");
        __builtin_amdgcn_sched_barrier(0);
    }

    #pragma unroll
    for (int r = 0; r < 4; ++r) {
        float s = s_acc[r];
        s += __shfl_xor(s, 1);
        s += __shfl_xor(s, 2);
        s += __shfl_xor(s, 4);
        s += __shfl_xor(s, 8);
        s_acc[r] = 1.f / s;
    }

    #pragma unroll
    for (int r = 0; r < 4; ++r) {
        int row = w * 16 + lg * 4 + r;
        float* op = so + (((size_t)blk * WSZW + row) * DD);
        #pragma unroll
        for (int dt = 0; dt < 4; ++dt)
            op[dt * 16 + lr] = acc[dt][r] * s_acc[r];
    }
}

// ---------------- Kernel E: histogram of token selections ----------------
__global__ __launch_bounds__(256) void count_kernel(
    const int* __restrict__ idxQ, int* __restrict__ counts)
{
    int i = blockIdx.x * 256 + threadIdx.x;
    int bh = i >> 13;
    atomicAdd(&counts[bh * TT + idxQ[i]], 1);
}

// ---------------- Kernel F: per-bh exclusive scan (4096 ints) ----------------
__global__ __launch_bounds__(256) void scan_kernel(
    const int* __restrict__ counts, int* __restrict__ offs)
{
    int bh = blockIdx.x;
    int t = threadIdx.x;
    const int* cb = counts + (size_t)bh * TT;
    int* ob = offs + (size_t)bh * TT;

    int loc[16]; int sum = 0;
    #pragma unroll
    for (int i = 0; i < 16; ++i) { loc[i] = sum; sum += cb[t * 16 + i]; }

    __shared__ int wsum[256];
    wsum[t] = sum;
    __syncthreads();
    for (int off = 1; off < 256; off <<= 1) {
        int vv = (t >= off) ? wsum[t - off] : 0;
        __syncthreads();
        wsum[t] += vv;
        __syncthreads();
    }
    int ex = (t == 0) ? 0 : wsum[t - 1];
    #pragma unroll
    for (int i = 0; i < 16; ++i) ob[t * 16 + i] = ex + loc[i];
}

// ---------------- Kernel G: fill CSR slot lists ----------------
__global__ __launch_bounds__(256) void fill_kernel(
    const int* __restrict__ idxQ, const int* __restrict__ offs,
    int* __restrict__ cur, int* __restrict__ csr)
{
    int i = blockIdx.x * 256 + threadIdx.x;
    int bh = i >> 13;
    int within = i & 8191;
    int tok = idxQ[i];
    int p = offs[bh * TT + tok] + atomicAdd(&cur[bh * TT + tok], 1);
    csr[((size_t)bh << 13) + p] = within;
}

// ---------------- Kernel H: gather-reduce + finalize + aux ----------------
__global__ __launch_bounds__(256) void reduce_kernel(
    const float* __restrict__ so, const int* __restrict__ counts,
    const int* __restrict__ offs, const int* __restrict__ csr,
    const float* __restrict__ aux_sum, float* __restrict__ out)
{
    int gt = blockIdx.x * 4 + (threadIdx.x >> 6);
    int lane = threadIdx.x & 63;
    int bh = gt >> 12;
    int n = counts[gt];
    int st = offs[gt];
    const int* cs = csr + ((size_t)bh << 13);
    float acc = 0.f;
    for (int j = 0; j < n; ++j) {
        int slot = cs[st + j];
        acc += so[(((size_t)bh << 13) + slot) * DD + lane];
    }
    out[(size_t)gt * DD + lane] = acc / ((float)n + EPSF);
    if (gt == 0 && threadIdx.x == 0)
        out[(size_t)BB * HH * TT * DD] =
            aux_sum[0] * (1.0f / (float)(BB * HH * 2 * TT * DD));
}

extern "C" void kernel_launch(void* const* d_in, const int* in_sizes, int n_in,
                              void* d_out, int out_size, void* d_ws, size_t ws_size,
                              hipStream_t stream) {
    const float* q        = (const float*)d_in[0];
    const float* k        = (const float*)d_in[1];
    const float* v        = (const float*)d_in[2];
    const float* means    = (const float*)d_in[3];
    const float* mem_key  = (const float*)d_in[4];
    const float* mem_val  = (const float*)d_in[5];
    float* out = (float*)d_out;

    const size_t nRows = (size_t)BB * HH * NCC;             // 2048
    const size_t nTok  = (size_t)BB * HH * TT;              // 131072
    float* wsf    = (float*)d_ws;
    float* distsQ = wsf;                                    // 8388608 f
    float* distsK = distsQ + (size_t)BB * HH * NCC * TT;    // 8388608 f
    float* so     = wsf;                                    // aliases dists; written after rescore
    int*   idxQ   = (int*)(distsK + (size_t)BB * HH * NCC * TT);  // 262144 i
    int*   idxK   = idxQ + nRows * WSZW;                    // 262144 i
    int*   counts = idxK + nRows * WSZW;                    // 131072 i
    int*   cur    = counts + nTok;                          // 131072 i
    float* aux    = (float*)(cur + nTok);                   // 1 f
    int*   offs   = (int*)(aux + 1);                        // 131072 i
    int*   csr    = offs + nTok;                            // 262144 i
    int*   candQ  = csr + nTok * 2;                         // 2048*160 i
    int*   candK  = candQ + nRows * TPK;                    // 2048*160 i

    hipMemsetAsync(counts, 0, (2 * nTok + 1) * sizeof(int), stream);

    dists_kernel<<<dim3(BB * HH * (2 * TT / 64)), dim3(256), 0, stream>>>(
        q, k, means, distsQ, distsK, aux);
    topk_kernel<<<dim3((unsigned)nRows), dim3(256), 0, stream>>>(distsQ, candQ);
    topk_kernel<<<dim3((unsigned)nRows), dim3(256), 0, stream>>>(distsK, candK);
    rescore_kernel<<<dim3((unsigned)(2 * nRows)), dim3(192), 0, stream>>>(
        q, k, means, candQ, candK, idxQ, idxK);
    count_kernel<<<dim3(1024), dim3(256), 0, stream>>>(idxQ, counts);
    scan_kernel<<<dim3(BB * HH), dim3(256), 0, stream>>>(counts, offs);
    fill_kernel<<<dim3(1024), dim3(256), 0, stream>>>(idxQ, offs, cur, csr);
    attn_kernel<<<dim3((unsigned)nRows), dim3(512), 0, stream>>>(
        q, k, v, mem_key, mem_val, idxQ, idxK, so);
    reduce_kernel<<<dim3((unsigned)(nTok / 4)), dim3(256), 0, stream>>>(
        so, counts, offs, csr, aux, out);
}

// Round 10
// 329.387 us; speedup vs baseline: 1.5025x; 1.5025x over previous
//
#include <hip/hip_runtime.h>
#include <math.h>

#define BB 4
#define HH 8
#define TT 4096
#define DD 64
#define NCC 64
#define WSZW 128
#define TPK 160          // widened f32 top-k; f64 rescore picks exact top-128
#define MEMN 1
#define KVW (MEMN + WSZW)   // 129
constexpr float EPSF = 1e-5f;
constexpr float SCALE = 0.125f;  // 64^-0.5

typedef __attribute__((ext_vector_type(8))) short bf16x8;
typedef __attribute__((ext_vector_type(4))) float f32x4;

static __device__ __forceinline__ unsigned short f2bf(float f) {
    union { float f; unsigned int u; } v; v.f = f;
    unsigned int r = v.u + 0x7FFFu + ((v.u >> 16) & 1u);   // RNE
    return (unsigned short)(r >> 16);
}
static __device__ __forceinline__ unsigned int pk2(float a, float b) {
    return (unsigned int)f2bf(a) | ((unsigned int)f2bf(b) << 16);
}
static __device__ __forceinline__ bf16x8 pack8(float4 a, float4 b) {
    bf16x8 r;
    r[0]=(short)f2bf(a.x); r[1]=(short)f2bf(a.y); r[2]=(short)f2bf(a.z); r[3]=(short)f2bf(a.w);
    r[4]=(short)f2bf(b.x); r[5]=(short)f2bf(b.y); r[6]=(short)f2bf(b.z); r[7]=(short)f2bf(b.w);
    return r;
}

// ---------------- Kernel A: dists as tiled f32 GEMM + argmax + aux partials ------
// aux: per-wave partial -> aux_part[bid*4+w] (plain store; the old single-address
// atomicAdd serialized 16K RMWs at ~33 cyc each = the entire 224 us kernel time).
__global__ __launch_bounds__(256, 4) void dists_kernel(
    const float* __restrict__ q, const float* __restrict__ k,
    const float* __restrict__ means,
    float* __restrict__ distsQ, float* __restrict__ distsK,
    float* __restrict__ aux_part)
{
    __shared__ float xS[64][68];   // [d][tok]; reused as dS[tok][c] after GEMM
    __shared__ float mS[64][68];   // [d][cluster]
    __shared__ float mqS[64];      // per-cluster ||m||^2

    const int chunks = (2 * TT) / 64;          // 128
    int bid = blockIdx.x;                      // 4096
    int bh = bid / chunks;
    int chunk = bid % chunks;
    int h = bh % HH;
    bool isQ = chunk < (TT / 64);
    int tbase = (isQ ? chunk : chunk - 64) * 64;
    const float* src = (isQ ? q : k) + ((size_t)bh * TT + tbase) * DD;
    float* dst = isQ ? distsQ : distsK;

    int tid = threadIdx.x;
    int tok = tid >> 2, part = tid & 3;        // tok doubles as cluster idx below

    // ---- stage means (transposed) + per-cluster sumsq ----
    {
        const float* mp = means + ((size_t)h * NCC + tok) * DD + part * 16;
        float4 va[4];
        #pragma unroll
        for (int i = 0; i < 4; ++i) va[i] = *(const float4*)(mp + i * 4);
        float msq = 0.f;
        #pragma unroll
        for (int i = 0; i < 4; ++i) {
            msq += va[i].x*va[i].x + va[i].y*va[i].y + va[i].z*va[i].z + va[i].w*va[i].w;
            int d = part * 16 + i * 4;
            mS[d][tok] = va[i].x; mS[d+1][tok] = va[i].y;
            mS[d+2][tok] = va[i].z; mS[d+3][tok] = va[i].w;
        }
        msq += __shfl_xor(msq, 1);
        msq += __shfl_xor(msq, 2);
        if (part == 0) mqS[tok] = msq;
    }
    // ---- stage x normalized (transposed) ----
    float ssn;
    {
        const float* xp = src + (size_t)tok * DD + part * 16;
        float4 va[4];
        #pragma unroll
        for (int i = 0; i < 4; ++i) va[i] = *(const float4*)(xp + i * 4);
        float ss = 0.f;
        #pragma unroll
        for (int i = 0; i < 4; ++i)
            ss += va[i].x*va[i].x + va[i].y*va[i].y + va[i].z*va[i].z + va[i].w*va[i].w;
        ss += __shfl_xor(ss, 1);
        ss += __shfl_xor(ss, 2);
        float inv = 1.f / fmaxf(sqrtf(ss), 1e-12f);
        ssn = ss * inv * inv;
        #pragma unroll
        for (int i = 0; i < 4; ++i) {
            int d = part * 16 + i * 4;
            xS[d][tok] = va[i].x*inv; xS[d+1][tok] = va[i].y*inv;
            xS[d+2][tok] = va[i].z*inv; xS[d+3][tok] = va[i].w*inv;
        }
    }
    __syncthreads();

    // ---- GEMM: thread = 4 tokens x 4 clusters ----
    int l = tid & 63, w = tid >> 6;
    int ti = l & 15;                 // token tile 4*ti..
    int ci = w * 4 + (l >> 4);       // cluster tile 4*ci..
    float acc[4][4];
    #pragma unroll
    for (int i = 0; i < 4; ++i)
        #pragma unroll
        for (int j = 0; j < 4; ++j) acc[i][j] = 0.f;

    #pragma unroll 16
    for (int kk = 0; kk < 64; ++kk) {
        float4 xv = *(const float4*)(&xS[kk][ti * 4]);
        float4 mv = *(const float4*)(&mS[kk][ci * 4]);
        float xa[4] = {xv.x, xv.y, xv.z, xv.w};
        float ma[4] = {mv.x, mv.y, mv.z, mv.w};
        #pragma unroll
        for (int i = 0; i < 4; ++i)
            #pragma unroll
            for (int j = 0; j < 4; ++j) acc[i][j] += xa[i] * ma[j];
    }

    // ---- store dists to global (coalesced float4 over tokens) ----
    {
        size_t rowb = (size_t)(bh * NCC) * TT;
        #pragma unroll
        for (int j = 0; j < 4; ++j) {
            int c = ci * 4 + j;
            float4 o;
            o.x = acc[0][j]; o.y = acc[1][j]; o.z = acc[2][j]; o.w = acc[3][j];
            *(float4*)&dst[rowb + (size_t)c * TT + tbase + ti * 4] = o;
        }
    }

    // ---- argmax + aux via LDS round-trip (reuse xS as dS[tok][c]) ----
    __syncthreads();
    #pragma unroll
    for (int i = 0; i < 4; ++i)
        #pragma unroll
        for (int j = 0; j < 4; ++j)
            xS[ti * 4 + i][ci * 4 + j] = acc[i][j];
    __syncthreads();

    float bv = -1e30f; int bc = 0;
    #pragma unroll
    for (int j = 0; j < 16; ++j) {
        int c = part * 16 + j;
        float vv = xS[tok][c];
        if (vv > bv) { bv = vv; bc = c; }
    }
    #pragma unroll
    for (int off = 1; off <= 2; off <<= 1) {
        float ov = __shfl_xor(bv, off);
        int   oc = __shfl_xor(bc, off);
        if (ov > bv || (ov == bv && oc < bc)) { bv = ov; bc = oc; }
    }
    float auxv = (part == 0) ? (ssn + mqS[bc] - 2.f * bv) : 0.f;
    #pragma unroll
    for (int off = 32; off; off >>= 1) auxv += __shfl_xor(auxv, off);
    if (l == 0) aux_part[bid * 4 + w] = auxv;
}

// ---------------- Kernel A2: reduce 16384 aux partials -> out[N] ----------------
__global__ __launch_bounds__(256) void aux_reduce_kernel(
    const float* __restrict__ aux_part, float* __restrict__ out)
{
    int t = threadIdx.x;
    float s = 0.f;
    for (int i = t; i < 16384; i += 256) s += aux_part[i];
    #pragma unroll
    for (int off = 32; off; off >>= 1) s += __shfl_xor(s, off);
    __shared__ float wsum[4];
    if ((t & 63) == 0) wsum[t >> 6] = s;
    __syncthreads();
    if (t == 0)
        out[(size_t)BB * HH * TT * DD] =
            (wsum[0] + wsum[1] + wsum[2] + wsum[3]) *
            (1.0f / (float)(BB * HH * 2 * TT * DD));
}

// ---------------- Kernel B: top-TPK per row via 4-pass radix select ----------------
__global__ __launch_bounds__(256) void topk_kernel(
    const float* __restrict__ dists, int* __restrict__ idxOut)
{
    int row = blockIdx.x;
    const float* dv = dists + (size_t)row * TT;
    int t = threadIdx.x;

    unsigned u[16];
    #pragma unroll
    for (int j = 0; j < 16; ++j) {
        unsigned b = __float_as_uint(dv[j * 256 + t]);
        u[j] = (b & 0x80000000u) ? ~b : (b | 0x80000000u);
    }

    __shared__ int hist[256];
    __shared__ int sfx[256];
    __shared__ int binSel, tgtS;
    __shared__ int nGtS, posS, eqFilled;
    __shared__ int waveCnt[4];

    int target = TPK;
    unsigned prefix = 0;

    for (int shift = 24; shift >= 0; shift -= 8) {
        hist[t] = 0;
        __syncthreads();
        #pragma unroll
        for (int j = 0; j < 16; ++j) {
            bool act = (shift == 24) || ((u[j] >> (shift + 8)) == (prefix >> (shift + 8)));
            if (act) atomicAdd(&hist[(u[j] >> shift) & 255], 1);
        }
        __syncthreads();
        sfx[t] = hist[t];
        __syncthreads();
        for (int off = 1; off < 256; off <<= 1) {
            int add = (t + off < 256) ? sfx[t + off] : 0;
            int cur = sfx[t];
            __syncthreads();
            sfx[t] = cur + add;
            __syncthreads();
        }
        int nxt = (t == 255) ? 0 : sfx[t + 1];
        if (sfx[t] >= target && nxt < target) { binSel = t; tgtS = target - nxt; }
        __syncthreads();
        prefix |= ((unsigned)binSel) << shift;
        target = tgtS;
        __syncthreads();
    }

    unsigned pivot = prefix;
    if (t == 0) { nGtS = 0; posS = 0; eqFilled = 0; }
    __syncthreads();
    int myg = 0;
    #pragma unroll
    for (int j = 0; j < 16; ++j) myg += (u[j] > pivot) ? 1 : 0;
    if (myg) atomicAdd(&nGtS, myg);
    __syncthreads();
    int n_gt = nGtS;
    int n_need = TPK - n_gt;
    int* out = idxOut + (size_t)row * TPK;

    #pragma unroll
    for (int j = 0; j < 16; ++j)
        if (u[j] > pivot) { int p = atomicAdd(&posS, 1); out[p] = j * 256 + t; }

    int lane = t & 63, wv = t >> 6;
    for (int j = 0; j < 16; ++j) {
        if (eqFilled >= n_need) break;
        bool fl = (u[j] == pivot);
        unsigned long long bal = __ballot(fl);
        if (lane == 0) waveCnt[wv] = __popcll(bal);
        __syncthreads();
        int offw = 0;
        for (int w = 0; w < wv; ++w) offw += waveCnt[w];
        int mypos = eqFilled + offw + __popcll(bal & ((lane ? ((1ull << lane) - 1ull) : 0ull)));
        if (fl && mypos < n_need) out[n_gt + mypos] = j * 256 + t;
        __syncthreads();
        if (t == 0) eqFilled += waveCnt[0] + waveCnt[1] + waveCnt[2] + waveCnt[3];
        __syncthreads();
    }
}

// ---------------- Kernel B2: f64 rescore of TPK candidates -> exact top-128 ----
__global__ __launch_bounds__(192) void rescore_kernel(
    const float* __restrict__ q, const float* __restrict__ k,
    const float* __restrict__ means,
    const int* __restrict__ candQ, const int* __restrict__ candK,
    int* __restrict__ idxQ, int* __restrict__ idxK)
{
    int rid = blockIdx.x;
    int side = rid >> 11;            // 0=Q, 1=K
    int row = rid & 2047;            // bh*NC + c
    int c = row & (NCC - 1);
    int bh = row >> 6;
    int h = bh % HH;

    const int* cand = (side ? candK : candQ) + (size_t)row * TPK;
    int* outIdx     = (side ? idxK : idxQ) + (size_t)row * WSZW;
    const float* xbase = (side ? k : q) + (size_t)bh * TT * DD;

    __shared__ double mD[DD];
    __shared__ double vS[TPK];
    __shared__ int    kiS[TPK];
    __shared__ int    wcnt[3];

    int tid = threadIdx.x;
    if (tid < DD) mD[tid] = (double)means[((size_t)h * NCC + c) * DD + tid];
    __syncthreads();

    double v = 0.0; int tok = 0x7FFFFFFF;
    if (tid < TPK) {
        tok = cand[tid];
        const float* xp = xbase + (size_t)tok * DD;
        double dot = 0.0, ss = 0.0;
        #pragma unroll
        for (int d = 0; d < DD; d += 4) {
            float4 va = *(const float4*)(xp + d);
            dot += (double)va.x * mD[d]   + (double)va.y * mD[d+1]
                 + (double)va.z * mD[d+2] + (double)va.w * mD[d+3];
            ss  += (double)va.x * va.x + (double)va.y * va.y
                 + (double)va.z * va.z + (double)va.w * va.w;
        }
        v = dot * (1.0 / fmax(sqrt(ss), 1e-12));
        vS[tid] = v; kiS[tid] = tok;
    }
    __syncthreads();

    bool keep = false;
    if (tid < TPK) {
        int rank = 0;
        for (int j = 0; j < TPK; ++j) {
            double vj = vS[j];
            rank += (vj > v || (vj == v && kiS[j] < tok)) ? 1 : 0;
        }
        keep = rank < WSZW;
    }
    int l = tid & 63, w = tid >> 6;
    unsigned long long bal = __ballot(keep);
    if (l == 0) wcnt[w] = __popcll(bal);
    __syncthreads();
    int base = 0;
    for (int ww = 0; ww < w; ++ww) base += wcnt[ww];
    int off = __popcll(bal & ((l ? ((1ull << l) - 1ull) : 0ull)));
    if (keep) outIdx[base + off] = tok;
}

// ---------------- Kernel C: bf16 MFMA attention -> dense so[] ----------------
__global__ __launch_bounds__(512, 2) void attn_kernel(
    const float* __restrict__ q, const float* __restrict__ k, const float* __restrict__ v,
    const float* __restrict__ mem_key, const float* __restrict__ mem_value,
    const int* __restrict__ idxQ, const int* __restrict__ idxK,
    float* __restrict__ so)
{
    int blk = blockIdx.x;        // bh*NC + c
    int c = blk % NCC;
    int bh = blk / NCC;
    int h = bh % HH;

    __shared__ __align__(16) unsigned short KsS[160 * 64];   // swizzled
    __shared__ __align__(16) unsigned short VsS[160 * 80];   // linear, stride 80
    __shared__ __align__(16) unsigned short PwS[8 * 16 * 40];

    int tid = threadIdx.x;

    if (tid < 320) {
        int row = tid >> 1, hh = tid & 1;
        const float* ksrc = nullptr; const float* vsrc = nullptr;
        if (row == 0) {
            ksrc = mem_key   + ((size_t)h * NCC + c) * (MEMN * DD);
            vsrc = mem_value + ((size_t)h * NCC + c) * (MEMN * DD);
        } else if (row < KVW) {
            int tk = idxK[(size_t)blk * WSZW + row - 1];
            ksrc = k + ((size_t)bh * TT + tk) * DD;
            vsrc = v + ((size_t)bh * TT + tk) * DD;
        }
        #pragma unroll
        for (int cch = 0; cch < 4; ++cch) {
            uint4 kw = {0,0,0,0}, vw = {0,0,0,0};
            if (ksrc) {
                int base = hh * 32 + cch * 8;
                float4 a = *(const float4*)(ksrc + base);
                float4 b = *(const float4*)(ksrc + base + 4);
                kw.x = pk2(a.x, a.y); kw.y = pk2(a.z, a.w);
                kw.z = pk2(b.x, b.y); kw.w = pk2(b.z, b.w);
                a = *(const float4*)(vsrc + base);
                b = *(const float4*)(vsrc + base + 4);
                vw.x = pk2(a.x, a.y); vw.y = pk2(a.z, a.w);
                vw.z = pk2(b.x, b.y); vw.w = pk2(b.z, b.w);
            }
            int chunk = hh * 4 + cch;
            int phys = chunk ^ (row & 7);
            *reinterpret_cast<uint4*>(&KsS[row * 64 + phys * 8]) = kw;
            *reinterpret_cast<uint4*>(&VsS[row * 80 + chunk * 8]) = vw;
        }
    }

    int w = tid >> 6, l = tid & 63;
    int lr = l & 15, lg = l >> 4;

    bf16x8 qf[2];
    {
        int tq = idxQ[(size_t)blk * WSZW + w * 16 + lr];
        const float* qp = q + ((size_t)bh * TT + tq) * DD;
        #pragma unroll
        for (int ks = 0; ks < 2; ++ks) {
            float4 a = *(const float4*)(qp + ks * 32 + lg * 8);
            float4 b = *(const float4*)(qp + ks * 32 + lg * 8 + 4);
            qf[ks] = pack8(a, b);
        }
    }

    f32x4 acc[4];
    #pragma unroll
    for (int dt = 0; dt < 4; ++dt) acc[dt] = (f32x4){0.f, 0.f, 0.f, 0.f};
    float s_acc[4] = {0.f, 0.f, 0.f, 0.f};

    __syncthreads();

    unsigned short* Pw = &PwS[w * 640];

    for (int kb = 0; kb < 5; ++kb) {
        bf16x8 kf[2][2];
        #pragma unroll
        for (int kvt = 0; kvt < 2; ++kvt)
            #pragma unroll
            for (int ks = 0; ks < 2; ++ks) {
                int row = kb * 32 + kvt * 16 + lr;
                int chunk = ks * 4 + lg;
                int phys = chunk ^ (row & 7);
                kf[kvt][ks] = *reinterpret_cast<const bf16x8*>(&KsS[row * 64 + phys * 8]);
            }
        #pragma unroll
        for (int kvt = 0; kvt < 2; ++kvt) {
            f32x4 sf = __builtin_amdgcn_mfma_f32_16x16x32_bf16(
                qf[0], kf[kvt][0], (f32x4){0.f,0.f,0.f,0.f}, 0, 0, 0);
            sf = __builtin_amdgcn_mfma_f32_16x16x32_bf16(qf[1], kf[kvt][1], sf, 0, 0, 0);
            int kvcol = kb * 32 + kvt * 16 + lr;
            bool valid = kvcol < KVW;
            #pragma unroll
            for (int r = 0; r < 4; ++r) {
                float e = valid ? __expf(sf[r] * SCALE) : 0.f;
                s_acc[r] += e;
                Pw[(lg * 4 + r) * 40 + kvt * 16 + lr] = f2bf(e);
            }
        }
        __builtin_amdgcn_sched_barrier(0);
        asm volatile("s_waitcnt lgkmcnt(0)" ::: "memory");
        __builtin_amdgcn_sched_barrier(0);
        bf16x8 pf = *reinterpret_cast<const bf16x8*>(&Pw[lr * 40 + lg * 8]);
        #pragma unroll
        for (int dt = 0; dt < 4; ++dt) {
            bf16x8 vf;
            #pragma unroll
            for (int j = 0; j < 8; ++j)
                vf[j] = (short)VsS[(kb * 32 + lg * 8 + j) * 80 + dt * 16 + lr];
            acc[dt] = __builtin_amdgcn_mfma_f32_16x16x32_bf16(pf, vf, acc[dt], 0, 0, 0);
        }
        __builtin_amdgcn_sched_barrier(0);
        asm volatile("s_waitcnt lgkmcnt(0)" ::: "memory");
        __builtin_amdgcn_sched_barrier(0);
    }

    #pragma unroll
    for (int r = 0; r < 4; ++r) {
        float s = s_acc[r];
        s += __shfl_xor(s, 1);
        s += __shfl_xor(s, 2);
        s += __shfl_xor(s, 4);
        s += __shfl_xor(s, 8);
        s_acc[r] = 1.f / s;
    }

    #pragma unroll
    for (int r = 0; r < 4; ++r) {
        int row = w * 16 + lg * 4 + r;
        float* op = so + (((size_t)blk * WSZW + row) * DD);
        #pragma unroll
        for (int dt = 0; dt < 4; ++dt)
            op[dt * 16 + lr] = acc[dt][r] * s_acc[r];
    }
}

// ---------------- Kernel E: histogram of token selections ----------------
__global__ __launch_bounds__(256) void count_kernel(
    const int* __restrict__ idxQ, int* __restrict__ counts)
{
    int i = blockIdx.x * 256 + threadIdx.x;
    int bh = i >> 13;
    atomicAdd(&counts[bh * TT + idxQ[i]], 1);
}

// ---------------- Kernel F: per-bh exclusive scan (4096 ints) ----------------
__global__ __launch_bounds__(256) void scan_kernel(
    const int* __restrict__ counts, int* __restrict__ offs)
{
    int bh = blockIdx.x;
    int t = threadIdx.x;
    const int* cb = counts + (size_t)bh * TT;
    int* ob = offs + (size_t)bh * TT;

    int loc[16]; int sum = 0;
    #pragma unroll
    for (int i = 0; i < 16; ++i) { loc[i] = sum; sum += cb[t * 16 + i]; }

    __shared__ int wsum[256];
    wsum[t] = sum;
    __syncthreads();
    for (int off = 1; off < 256; off <<= 1) {
        int vv = (t >= off) ? wsum[t - off] : 0;
        __syncthreads();
        wsum[t] += vv;
        __syncthreads();
    }
    int ex = (t == 0) ? 0 : wsum[t - 1];
    #pragma unroll
    for (int i = 0; i < 16; ++i) ob[t * 16 + i] = ex + loc[i];
}

// ---------------- Kernel G: fill CSR slot lists ----------------
__global__ __launch_bounds__(256) void fill_kernel(
    const int* __restrict__ idxQ, const int* __restrict__ offs,
    int* __restrict__ cur, int* __restrict__ csr)
{
    int i = blockIdx.x * 256 + threadIdx.x;
    int bh = i >> 13;
    int within = i & 8191;
    int tok = idxQ[i];
    int p = offs[bh * TT + tok] + atomicAdd(&cur[bh * TT + tok], 1);
    csr[((size_t)bh << 13) + p] = within;
}

// ---------------- Kernel H: gather-reduce + finalize ----------------
__global__ __launch_bounds__(256) void reduce_kernel(
    const float* __restrict__ so, const int* __restrict__ counts,
    const int* __restrict__ offs, const int* __restrict__ csr,
    float* __restrict__ out)
{
    int gt = blockIdx.x * 4 + (threadIdx.x >> 6);
    int lane = threadIdx.x & 63;
    int bh = gt >> 12;
    int n = counts[gt];
    int st = offs[gt];
    const int* cs = csr + ((size_t)bh << 13);
    float acc = 0.f;
    for (int j = 0; j < n; ++j) {
        int slot = cs[st + j];
        acc += so[(((size_t)bh << 13) + slot) * DD + lane];
    }
    out[(size_t)gt * DD + lane] = acc / ((float)n + EPSF);
}

extern "C" void kernel_launch(void* const* d_in, const int* in_sizes, int n_in,
                              void* d_out, int out_size, void* d_ws, size_t ws_size,
                              hipStream_t stream) {
    const float* q        = (const float*)d_in[0];
    const float* k        = (const float*)d_in[1];
    const float* v        = (const float*)d_in[2];
    const float* means    = (const float*)d_in[3];
    const float* mem_key  = (const float*)d_in[4];
    const float* mem_val  = (const float*)d_in[5];
    float* out = (float*)d_out;

    const size_t nRows = (size_t)BB * HH * NCC;             // 2048
    const size_t nTok  = (size_t)BB * HH * TT;              // 131072
    float* wsf    = (float*)d_ws;
    float* distsQ = wsf;                                    // 8388608 f
    float* distsK = distsQ + (size_t)BB * HH * NCC * TT;    // 8388608 f
    float* so     = wsf;                                    // aliases dists; written after rescore
    int*   idxQ   = (int*)(distsK + (size_t)BB * HH * NCC * TT);  // 262144 i
    int*   idxK   = idxQ + nRows * WSZW;                    // 262144 i
    int*   counts = idxK + nRows * WSZW;                    // 131072 i
    int*   cur    = counts + nTok;                          // 131072 i
    float* auxp   = (float*)(cur + nTok);                   // 16384 f (per-wave partials)
    int*   offs   = (int*)(auxp + 16384);                   // 131072 i
    int*   csr    = offs + nTok;                            // 262144 i
    int*   candQ  = csr + nTok * 2;                         // 2048*160 i
    int*   candK  = candQ + nRows * TPK;                    // 2048*160 i

    hipMemsetAsync(counts, 0, 2 * nTok * sizeof(int), stream);

    dists_kernel<<<dim3(BB * HH * (2 * TT / 64)), dim3(256), 0, stream>>>(
        q, k, means, distsQ, distsK, auxp);
    aux_reduce_kernel<<<dim3(1), dim3(256), 0, stream>>>(auxp, out);
    topk_kernel<<<dim3((unsigned)nRows), dim3(256), 0, stream>>>(distsQ, candQ);
    topk_kernel<<<dim3((unsigned)nRows), dim3(256), 0, stream>>>(distsK, candK);
    rescore_kernel<<<dim3((unsigned)(2 * nRows)), dim3(192), 0, stream>>>(
        q, k, means, candQ, candK, idxQ, idxK);
    count_kernel<<<dim3(1024), dim3(256), 0, stream>>>(idxQ, counts);
    scan_kernel<<<dim3(BB * HH), dim3(256), 0, stream>>>(counts, offs);
    fill_kernel<<<dim3(1024), dim3(256), 0, stream>>>(idxQ, offs, cur, csr);
    attn_kernel<<<dim3((unsigned)nRows), dim3(512), 0, stream>>>(
        q, k, v, mem_key, mem_val, idxQ, idxK, so);
    reduce_kernel<<<dim3((unsigned)(nTok / 4)), dim3(256), 0, stream>>>(
        so, counts, offs, csr, out);
}

// Round 11
// 313.396 us; speedup vs baseline: 1.5791x; 1.0510x over previous
//
#include <hip/hip_runtime.h>
#include <math.h>

#define BB 4
#define HH 8
#define TT 4096
#define DD 64
#define NCC 64
#define WSZW 128
#define TPK 160          // widened f32 top-k; f64 rescore picks exact top-128
#define MEMN 1
#define KVW (MEMN + WSZW)   // 129
constexpr float EPSF = 1e-5f;
constexpr float SCALE = 0.125f;  // 64^-0.5

typedef __attribute__((ext_vector_type(8))) short bf16x8;
typedef __attribute__((ext_vector_type(4))) float f32x4;

static __device__ __forceinline__ unsigned short f2bf(float f) {
    union { float f; unsigned int u; } v; v.f = f;
    unsigned int r = v.u + 0x7FFFu + ((v.u >> 16) & 1u);   // RNE
    return (unsigned short)(r >> 16);
}
static __device__ __forceinline__ unsigned int pk2(float a, float b) {
    return (unsigned int)f2bf(a) | ((unsigned int)f2bf(b) << 16);
}
static __device__ __forceinline__ bf16x8 pack8(float4 a, float4 b) {
    bf16x8 r;
    r[0]=(short)f2bf(a.x); r[1]=(short)f2bf(a.y); r[2]=(short)f2bf(a.z); r[3]=(short)f2bf(a.w);
    r[4]=(short)f2bf(b.x); r[5]=(short)f2bf(b.y); r[6]=(short)f2bf(b.z); r[7]=(short)f2bf(b.w);
    return r;
}

// ---------------- Kernel A: dists as tiled f32 GEMM + argmax + aux partials ------
__global__ __launch_bounds__(256, 4) void dists_kernel(
    const float* __restrict__ q, const float* __restrict__ k,
    const float* __restrict__ means,
    float* __restrict__ distsQ, float* __restrict__ distsK,
    float* __restrict__ aux_part)
{
    __shared__ float xS[64][68];   // [d][tok]; reused as dS[tok][c] after GEMM
    __shared__ float mS[64][68];   // [d][cluster]
    __shared__ float mqS[64];      // per-cluster ||m||^2

    const int chunks = (2 * TT) / 64;          // 128
    int bid = blockIdx.x;                      // 4096
    int bh = bid / chunks;
    int chunk = bid % chunks;
    int h = bh % HH;
    bool isQ = chunk < (TT / 64);
    int tbase = (isQ ? chunk : chunk - 64) * 64;
    const float* src = (isQ ? q : k) + ((size_t)bh * TT + tbase) * DD;
    float* dst = isQ ? distsQ : distsK;

    int tid = threadIdx.x;
    int tok = tid >> 2, part = tid & 3;        // tok doubles as cluster idx below

    // ---- stage means (transposed) + per-cluster sumsq ----
    {
        const float* mp = means + ((size_t)h * NCC + tok) * DD + part * 16;
        float4 va[4];
        #pragma unroll
        for (int i = 0; i < 4; ++i) va[i] = *(const float4*)(mp + i * 4);
        float msq = 0.f;
        #pragma unroll
        for (int i = 0; i < 4; ++i) {
            msq += va[i].x*va[i].x + va[i].y*va[i].y + va[i].z*va[i].z + va[i].w*va[i].w;
            int d = part * 16 + i * 4;
            mS[d][tok] = va[i].x; mS[d+1][tok] = va[i].y;
            mS[d+2][tok] = va[i].z; mS[d+3][tok] = va[i].w;
        }
        msq += __shfl_xor(msq, 1);
        msq += __shfl_xor(msq, 2);
        if (part == 0) mqS[tok] = msq;
    }
    // ---- stage x normalized (transposed) ----
    float ssn;
    {
        const float* xp = src + (size_t)tok * DD + part * 16;
        float4 va[4];
        #pragma unroll
        for (int i = 0; i < 4; ++i) va[i] = *(const float4*)(xp + i * 4);
        float ss = 0.f;
        #pragma unroll
        for (int i = 0; i < 4; ++i)
            ss += va[i].x*va[i].x + va[i].y*va[i].y + va[i].z*va[i].z + va[i].w*va[i].w;
        ss += __shfl_xor(ss, 1);
        ss += __shfl_xor(ss, 2);
        float inv = 1.f / fmaxf(sqrtf(ss), 1e-12f);
        ssn = ss * inv * inv;
        #pragma unroll
        for (int i = 0; i < 4; ++i) {
            int d = part * 16 + i * 4;
            xS[d][tok] = va[i].x*inv; xS[d+1][tok] = va[i].y*inv;
            xS[d+2][tok] = va[i].z*inv; xS[d+3][tok] = va[i].w*inv;
        }
    }
    __syncthreads();

    // ---- GEMM: thread = 4 tokens x 4 clusters ----
    int l = tid & 63, w = tid >> 6;
    int ti = l & 15;                 // token tile 4*ti..
    int ci = w * 4 + (l >> 4);       // cluster tile 4*ci..
    float acc[4][4];
    #pragma unroll
    for (int i = 0; i < 4; ++i)
        #pragma unroll
        for (int j = 0; j < 4; ++j) acc[i][j] = 0.f;

    #pragma unroll 16
    for (int kk = 0; kk < 64; ++kk) {
        float4 xv = *(const float4*)(&xS[kk][ti * 4]);
        float4 mv = *(const float4*)(&mS[kk][ci * 4]);
        float xa[4] = {xv.x, xv.y, xv.z, xv.w};
        float ma[4] = {mv.x, mv.y, mv.z, mv.w};
        #pragma unroll
        for (int i = 0; i < 4; ++i)
            #pragma unroll
            for (int j = 0; j < 4; ++j) acc[i][j] += xa[i] * ma[j];
    }

    // ---- store dists to global (coalesced float4 over tokens) ----
    {
        size_t rowb = (size_t)(bh * NCC) * TT;
        #pragma unroll
        for (int j = 0; j < 4; ++j) {
            int c = ci * 4 + j;
            float4 o;
            o.x = acc[0][j]; o.y = acc[1][j]; o.z = acc[2][j]; o.w = acc[3][j];
            *(float4*)&dst[rowb + (size_t)c * TT + tbase + ti * 4] = o;
        }
    }

    // ---- argmax + aux via LDS round-trip (reuse xS as dS[tok][c]) ----
    __syncthreads();
    #pragma unroll
    for (int i = 0; i < 4; ++i)
        #pragma unroll
        for (int j = 0; j < 4; ++j)
            xS[ti * 4 + i][ci * 4 + j] = acc[i][j];
    __syncthreads();

    float bv = -1e30f; int bc = 0;
    #pragma unroll
    for (int j = 0; j < 16; ++j) {
        int c = part * 16 + j;
        float vv = xS[tok][c];
        if (vv > bv) { bv = vv; bc = c; }
    }
    #pragma unroll
    for (int off = 1; off <= 2; off <<= 1) {
        float ov = __shfl_xor(bv, off);
        int   oc = __shfl_xor(bc, off);
        if (ov > bv || (ov == bv && oc < bc)) { bv = ov; bc = oc; }
    }
    float auxv = (part == 0) ? (ssn + mqS[bc] - 2.f * bv) : 0.f;
    #pragma unroll
    for (int off = 32; off; off >>= 1) auxv += __shfl_xor(auxv, off);
    if (l == 0) aux_part[bid * 4 + w] = auxv;
}

// ---------------- Kernel A2: reduce 16384 aux partials -> out[N] ----------------
__global__ __launch_bounds__(256) void aux_reduce_kernel(
    const float* __restrict__ aux_part, float* __restrict__ out)
{
    int t = threadIdx.x;
    float s = 0.f;
    for (int i = t; i < 16384; i += 256) s += aux_part[i];
    #pragma unroll
    for (int off = 32; off; off >>= 1) s += __shfl_xor(s, off);
    __shared__ float wsum[4];
    if ((t & 63) == 0) wsum[t >> 6] = s;
    __syncthreads();
    if (t == 0)
        out[(size_t)BB * HH * TT * DD] =
            (wsum[0] + wsum[1] + wsum[2] + wsum[3]) *
            (1.0f / (float)(BB * HH * 2 * TT * DD));
}

// ---------------- Kernel B: top-TPK per row via 4-pass radix select ----------------
__global__ __launch_bounds__(256) void topk_kernel(
    const float* __restrict__ dists, int* __restrict__ idxOut)
{
    int row = blockIdx.x;
    const float* dv = dists + (size_t)row * TT;
    int t = threadIdx.x;

    unsigned u[16];
    #pragma unroll
    for (int j = 0; j < 16; ++j) {
        unsigned b = __float_as_uint(dv[j * 256 + t]);
        u[j] = (b & 0x80000000u) ? ~b : (b | 0x80000000u);
    }

    __shared__ int hist[256];
    __shared__ int sfx[256];
    __shared__ int binSel, tgtS;
    __shared__ int nGtS, posS, eqFilled;
    __shared__ int waveCnt[4];

    int target = TPK;
    unsigned prefix = 0;

    for (int shift = 24; shift >= 0; shift -= 8) {
        hist[t] = 0;
        __syncthreads();
        #pragma unroll
        for (int j = 0; j < 16; ++j) {
            bool act = (shift == 24) || ((u[j] >> (shift + 8)) == (prefix >> (shift + 8)));
            if (act) atomicAdd(&hist[(u[j] >> shift) & 255], 1);
        }
        __syncthreads();
        sfx[t] = hist[t];
        __syncthreads();
        for (int off = 1; off < 256; off <<= 1) {
            int add = (t + off < 256) ? sfx[t + off] : 0;
            int cur = sfx[t];
            __syncthreads();
            sfx[t] = cur + add;
            __syncthreads();
        }
        int nxt = (t == 255) ? 0 : sfx[t + 1];
        if (sfx[t] >= target && nxt < target) { binSel = t; tgtS = target - nxt; }
        __syncthreads();
        prefix |= ((unsigned)binSel) << shift;
        target = tgtS;
        __syncthreads();
    }

    unsigned pivot = prefix;
    if (t == 0) { nGtS = 0; posS = 0; eqFilled = 0; }
    __syncthreads();
    int myg = 0;
    #pragma unroll
    for (int j = 0; j < 16; ++j) myg += (u[j] > pivot) ? 1 : 0;
    if (myg) atomicAdd(&nGtS, myg);
    __syncthreads();
    int n_gt = nGtS;
    int n_need = TPK - n_gt;
    int* out = idxOut + (size_t)row * TPK;

    #pragma unroll
    for (int j = 0; j < 16; ++j)
        if (u[j] > pivot) { int p = atomicAdd(&posS, 1); out[p] = j * 256 + t; }

    int lane = t & 63, wv = t >> 6;
    for (int j = 0; j < 16; ++j) {
        if (eqFilled >= n_need) break;
        bool fl = (u[j] == pivot);
        unsigned long long bal = __ballot(fl);
        if (lane == 0) waveCnt[wv] = __popcll(bal);
        __syncthreads();
        int offw = 0;
        for (int w = 0; w < wv; ++w) offw += waveCnt[w];
        int mypos = eqFilled + offw + __popcll(bal & ((lane ? ((1ull << lane) - 1ull) : 0ull)));
        if (fl && mypos < n_need) out[n_gt + mypos] = j * 256 + t;
        __syncthreads();
        if (t == 0) eqFilled += waveCnt[0] + waveCnt[1] + waveCnt[2] + waveCnt[3];
        __syncthreads();
    }
}

// ---------------- Kernel B2: f64 rescore, 4 lanes per candidate ----------------
// 640 threads = 160 candidates x 4 lanes (quarter-rows). Rank is a bijection
// under the strict order (value desc, token asc) -> outIdx[rank] = tok directly
// (also reproduces jax top_k output order).
__global__ __launch_bounds__(640) void rescore_kernel(
    const float* __restrict__ q, const float* __restrict__ k,
    const float* __restrict__ means,
    const int* __restrict__ candQ, const int* __restrict__ candK,
    int* __restrict__ idxQ, int* __restrict__ idxK)
{
    int rid = blockIdx.x;
    int side = rid >> 11;            // 0=Q, 1=K
    int row = rid & 2047;            // bh*NC + c
    int c = row & (NCC - 1);
    int bh = row >> 6;
    int h = bh % HH;

    const int* cand = (side ? candK : candQ) + (size_t)row * TPK;
    int* outIdx     = (side ? idxK : idxQ) + (size_t)row * WSZW;
    const float* xbase = (side ? k : q) + (size_t)bh * TT * DD;

    __shared__ double mD[DD];
    __shared__ double vS[TPK];
    __shared__ int    kiS[TPK];
    __shared__ int    rankS[TPK];

    int tid = threadIdx.x;
    if (tid < DD) mD[tid] = (double)means[((size_t)h * NCC + c) * DD + tid];
    __syncthreads();

    int g = tid >> 2;                // candidate 0..159
    int qt = tid & 3;                // quarter-row 0..3
    int tok = cand[g];
    const float* xp = xbase + (size_t)tok * DD + qt * 16;
    double dot = 0.0, ss = 0.0;
    #pragma unroll
    for (int i = 0; i < 4; ++i) {
        float4 va = *(const float4*)(xp + i * 4);
        int d = qt * 16 + i * 4;
        dot += (double)va.x * mD[d]   + (double)va.y * mD[d+1]
             + (double)va.z * mD[d+2] + (double)va.w * mD[d+3];
        ss  += (double)va.x * va.x + (double)va.y * va.y
             + (double)va.z * va.z + (double)va.w * va.w;
    }
    dot += __shfl_xor(dot, 1); dot += __shfl_xor(dot, 2);
    ss  += __shfl_xor(ss, 1);  ss  += __shfl_xor(ss, 2);
    double v = dot * (1.0 / fmax(sqrt(ss), 1e-12));
    if (qt == 0) { vS[g] = v; kiS[g] = tok; }
    __syncthreads();

    // rank: each lane counts its 40-candidate quarter, combine in-group
    int rk = 0;
    #pragma unroll 8
    for (int i = 0; i < TPK / 4; ++i) {
        int j = qt * (TPK / 4) + i;
        double vj = vS[j];
        int kj = kiS[j];
        rk += (vj > v || (vj == v && kj < tok)) ? 1 : 0;
    }
    rk += __shfl_xor(rk, 1); rk += __shfl_xor(rk, 2);
    if (qt == 0) rankS[g] = rk;
    __syncthreads();

    if (tid < TPK) {
        int r = rankS[tid];
        if (r < WSZW) outIdx[r] = kiS[tid];
    }
}

// ---------------- Kernel C: bf16 MFMA attention -> dense so[] ----------------
__global__ __launch_bounds__(512, 2) void attn_kernel(
    const float* __restrict__ q, const float* __restrict__ k, const float* __restrict__ v,
    const float* __restrict__ mem_key, const float* __restrict__ mem_value,
    const int* __restrict__ idxQ, const int* __restrict__ idxK,
    float* __restrict__ so)
{
    int blk = blockIdx.x;        // bh*NC + c
    int c = blk % NCC;
    int bh = blk / NCC;
    int h = bh % HH;

    __shared__ __align__(16) unsigned short KsS[160 * 64];   // swizzled
    __shared__ __align__(16) unsigned short VsS[160 * 80];   // linear, stride 80
    __shared__ __align__(16) unsigned short PwS[8 * 16 * 40];

    int tid = threadIdx.x;

    if (tid < 320) {
        int row = tid >> 1, hh = tid & 1;
        const float* ksrc = nullptr; const float* vsrc = nullptr;
        if (row == 0) {
            ksrc = mem_key   + ((size_t)h * NCC + c) * (MEMN * DD);
            vsrc = mem_value + ((size_t)h * NCC + c) * (MEMN * DD);
        } else if (row < KVW) {
            int tk = idxK[(size_t)blk * WSZW + row - 1];
            ksrc = k + ((size_t)bh * TT + tk) * DD;
            vsrc = v + ((size_t)bh * TT + tk) * DD;
        }
        #pragma unroll
        for (int cch = 0; cch < 4; ++cch) {
            uint4 kw = {0,0,0,0}, vw = {0,0,0,0};
            if (ksrc) {
                int base = hh * 32 + cch * 8;
                float4 a = *(const float4*)(ksrc + base);
                float4 b = *(const float4*)(ksrc + base + 4);
                kw.x = pk2(a.x, a.y); kw.y = pk2(a.z, a.w);
                kw.z = pk2(b.x, b.y); kw.w = pk2(b.z, b.w);
                a = *(const float4*)(vsrc + base);
                b = *(const float4*)(vsrc + base + 4);
                vw.x = pk2(a.x, a.y); vw.y = pk2(a.z, a.w);
                vw.z = pk2(b.x, b.y); vw.w = pk2(b.z, b.w);
            }
            int chunk = hh * 4 + cch;
            int phys = chunk ^ (row & 7);
            *reinterpret_cast<uint4*>(&KsS[row * 64 + phys * 8]) = kw;
            *reinterpret_cast<uint4*>(&VsS[row * 80 + chunk * 8]) = vw;
        }
    }

    int w = tid >> 6, l = tid & 63;
    int lr = l & 15, lg = l >> 4;

    bf16x8 qf[2];
    {
        int tq = idxQ[(size_t)blk * WSZW + w * 16 + lr];
        const float* qp = q + ((size_t)bh * TT + tq) * DD;
        #pragma unroll
        for (int ks = 0; ks < 2; ++ks) {
            float4 a = *(const float4*)(qp + ks * 32 + lg * 8);
            float4 b = *(const float4*)(qp + ks * 32 + lg * 8 + 4);
            qf[ks] = pack8(a, b);
        }
    }

    f32x4 acc[4];
    #pragma unroll
    for (int dt = 0; dt < 4; ++dt) acc[dt] = (f32x4){0.f, 0.f, 0.f, 0.f};
    float s_acc[4] = {0.f, 0.f, 0.f, 0.f};

    __syncthreads();

    unsigned short* Pw = &PwS[w * 640];

    for (int kb = 0; kb < 5; ++kb) {
        bf16x8 kf[2][2];
        #pragma unroll
        for (int kvt = 0; kvt < 2; ++kvt)
            #pragma unroll
            for (int ks = 0; ks < 2; ++ks) {
                int row = kb * 32 + kvt * 16 + lr;
                int chunk = ks * 4 + lg;
                int phys = chunk ^ (row & 7);
                kf[kvt][ks] = *reinterpret_cast<const bf16x8*>(&KsS[row * 64 + phys * 8]);
            }
        #pragma unroll
        for (int kvt = 0; kvt < 2; ++kvt) {
            f32x4 sf = __builtin_amdgcn_mfma_f32_16x16x32_bf16(
                qf[0], kf[kvt][0], (f32x4){0.f,0.f,0.f,0.f}, 0, 0, 0);
            sf = __builtin_amdgcn_mfma_f32_16x16x32_bf16(qf[1], kf[kvt][1], sf, 0, 0, 0);
            int kvcol = kb * 32 + kvt * 16 + lr;
            bool valid = kvcol < KVW;
            #pragma unroll
            for (int r = 0; r < 4; ++r) {
                float e = valid ? __expf(sf[r] * SCALE) : 0.f;
                s_acc[r] += e;
                Pw[(lg * 4 + r) * 40 + kvt * 16 + lr] = f2bf(e);
            }
        }
        __builtin_amdgcn_sched_barrier(0);
        asm volatile("s_waitcnt lgkmcnt(0)" ::: "memory");
        __builtin_amdgcn_sched_barrier(0);
        bf16x8 pf = *reinterpret_cast<const bf16x8*>(&Pw[lr * 40 + lg * 8]);
        #pragma unroll
        for (int dt = 0; dt < 4; ++dt) {
            bf16x8 vf;
            #pragma unroll
            for (int j = 0; j < 8; ++j)
                vf[j] = (short)VsS[(kb * 32 + lg * 8 + j) * 80 + dt * 16 + lr];
            acc[dt] = __builtin_amdgcn_mfma_f32_16x16x32_bf16(pf, vf, acc[dt], 0, 0, 0);
        }
        __builtin_amdgcn_sched_barrier(0);
        asm volatile("s_waitcnt lgkmcnt(0)" ::: "memory");
        __builtin_amdgcn_sched_barrier(0);
    }

    #pragma unroll
    for (int r = 0; r < 4; ++r) {
        float s = s_acc[r];
        s += __shfl_xor(s, 1);
        s += __shfl_xor(s, 2);
        s += __shfl_xor(s, 4);
        s += __shfl_xor(s, 8);
        s_acc[r] = 1.f / s;
    }

    #pragma unroll
    for (int r = 0; r < 4; ++r) {
        int row = w * 16 + lg * 4 + r;
        float* op = so + (((size_t)blk * WSZW + row) * DD);
        #pragma unroll
        for (int dt = 0; dt < 4; ++dt)
            op[dt * 16 + lr] = acc[dt][r] * s_acc[r];
    }
}

// ---------------- Kernel E: histogram of token selections ----------------
__global__ __launch_bounds__(256) void count_kernel(
    const int* __restrict__ idxQ, int* __restrict__ counts)
{
    int i = blockIdx.x * 256 + threadIdx.x;
    int bh = i >> 13;
    atomicAdd(&counts[bh * TT + idxQ[i]], 1);
}

// ---------------- Kernel F: per-bh exclusive scan (4096 ints) ----------------
__global__ __launch_bounds__(256) void scan_kernel(
    const int* __restrict__ counts, int* __restrict__ offs)
{
    int bh = blockIdx.x;
    int t = threadIdx.x;
    const int* cb = counts + (size_t)bh * TT;
    int* ob = offs + (size_t)bh * TT;

    int loc[16]; int sum = 0;
    #pragma unroll
    for (int i = 0; i < 16; ++i) { loc[i] = sum; sum += cb[t * 16 + i]; }

    __shared__ int wsum[256];
    wsum[t] = sum;
    __syncthreads();
    for (int off = 1; off < 256; off <<= 1) {
        int vv = (t >= off) ? wsum[t - off] : 0;
        __syncthreads();
        wsum[t] += vv;
        __syncthreads();
    }
    int ex = (t == 0) ? 0 : wsum[t - 1];
    #pragma unroll
    for (int i = 0; i < 16; ++i) ob[t * 16 + i] = ex + loc[i];
}

// ---------------- Kernel G: fill CSR slot lists ----------------
__global__ __launch_bounds__(256) void fill_kernel(
    const int* __restrict__ idxQ, const int* __restrict__ offs,
    int* __restrict__ cur, int* __restrict__ csr)
{
    int i = blockIdx.x * 256 + threadIdx.x;
    int bh = i >> 13;
    int within = i & 8191;
    int tok = idxQ[i];
    int p = offs[bh * TT + tok] + atomicAdd(&cur[bh * TT + tok], 1);
    csr[((size_t)bh << 13) + p] = within;
}

// ---------------- Kernel H: gather-reduce + finalize ----------------
__global__ __launch_bounds__(256) void reduce_kernel(
    const float* __restrict__ so, const int* __restrict__ counts,
    const int* __restrict__ offs, const int* __restrict__ csr,
    float* __restrict__ out)
{
    int gt = blockIdx.x * 4 + (threadIdx.x >> 6);
    int lane = threadIdx.x & 63;
    int bh = gt >> 12;
    int n = counts[gt];
    int st = offs[gt];
    const int* cs = csr + ((size_t)bh << 13);
    float acc = 0.f;
    for (int j = 0; j < n; ++j) {
        int slot = cs[st + j];
        acc += so[(((size_t)bh << 13) + slot) * DD + lane];
    }
    out[(size_t)gt * DD + lane] = acc / ((float)n + EPSF);
}

extern "C" void kernel_launch(void* const* d_in, const int* in_sizes, int n_in,
                              void* d_out, int out_size, void* d_ws, size_t ws_size,
                              hipStream_t stream) {
    const float* q        = (const float*)d_in[0];
    const float* k        = (const float*)d_in[1];
    const float* v        = (const float*)d_in[2];
    const float* means    = (const float*)d_in[3];
    const float* mem_key  = (const float*)d_in[4];
    const float* mem_val  = (const float*)d_in[5];
    float* out = (float*)d_out;

    const size_t nRows = (size_t)BB * HH * NCC;             // 2048
    const size_t nTok  = (size_t)BB * HH * TT;              // 131072
    float* wsf    = (float*)d_ws;
    float* distsQ = wsf;                                    // 8388608 f
    float* distsK = distsQ + (size_t)BB * HH * NCC * TT;    // 8388608 f
    float* so     = wsf;                                    // aliases dists; written after rescore
    int*   idxQ   = (int*)(distsK + (size_t)BB * HH * NCC * TT);  // 262144 i
    int*   idxK   = idxQ + nRows * WSZW;                    // 262144 i
    int*   counts = idxK + nRows * WSZW;                    // 131072 i
    int*   cur    = counts + nTok;                          // 131072 i
    float* auxp   = (float*)(cur + nTok);                   // 16384 f (per-wave partials)
    int*   offs   = (int*)(auxp + 16384);                   // 131072 i
    int*   csr    = offs + nTok;                            // 262144 i
    int*   candQ  = csr + nTok * 2;                         // 2048*160 i
    int*   candK  = candQ + nRows * TPK;                    // 2048*160 i

    hipMemsetAsync(counts, 0, 2 * nTok * sizeof(int), stream);

    dists_kernel<<<dim3(BB * HH * (2 * TT / 64)), dim3(256), 0, stream>>>(
        q, k, means, distsQ, distsK, auxp);
    aux_reduce_kernel<<<dim3(1), dim3(256), 0, stream>>>(auxp, out);
    topk_kernel<<<dim3((unsigned)nRows), dim3(256), 0, stream>>>(distsQ, candQ);
    topk_kernel<<<dim3((unsigned)nRows), dim3(256), 0, stream>>>(distsK, candK);
    rescore_kernel<<<dim3((unsigned)(2 * nRows)), dim3(640), 0, stream>>>(
        q, k, means, candQ, candK, idxQ, idxK);
    count_kernel<<<dim3(1024), dim3(256), 0, stream>>>(idxQ, counts);
    scan_kernel<<<dim3(BB * HH), dim3(256), 0, stream>>>(counts, offs);
    fill_kernel<<<dim3(1024), dim3(256), 0, stream>>>(idxQ, offs, cur, csr);
    attn_kernel<<<dim3((unsigned)nRows), dim3(512), 0, stream>>>(
        q, k, v, mem_key, mem_val, idxQ, idxK, so);
    reduce_kernel<<<dim3((unsigned)(nTok / 4)), dim3(256), 0, stream>>>(
        so, counts, offs, csr, out);
}

// Round 12
// 305.760 us; speedup vs baseline: 1.6186x; 1.0250x over previous
//
#include <hip/hip_runtime.h>
#include <math.h>

#define BB 4
#define HH 8
#define TT 4096
#define DD 64
#define NCC 64
#define WSZW 128
#define TPK 160          // widened f32 top-k; f64 rescore picks exact top-128
#define MEMN 1
#define KVW (MEMN + WSZW)   // 129
constexpr float EPSF = 1e-5f;
constexpr float SCALE = 0.125f;  // 64^-0.5

typedef __attribute__((ext_vector_type(8))) short bf16x8;
typedef __attribute__((ext_vector_type(4))) float f32x4;

static __device__ __forceinline__ unsigned short f2bf(float f) {
    union { float f; unsigned int u; } v; v.f = f;
    unsigned int r = v.u + 0x7FFFu + ((v.u >> 16) & 1u);   // RNE
    return (unsigned short)(r >> 16);
}
static __device__ __forceinline__ unsigned int pk2(float a, float b) {
    return (unsigned int)f2bf(a) | ((unsigned int)f2bf(b) << 16);
}
static __device__ __forceinline__ bf16x8 pack8(float4 a, float4 b) {
    bf16x8 r;
    r[0]=(short)f2bf(a.x); r[1]=(short)f2bf(a.y); r[2]=(short)f2bf(a.z); r[3]=(short)f2bf(a.w);
    r[4]=(short)f2bf(b.x); r[5]=(short)f2bf(b.y); r[6]=(short)f2bf(b.z); r[7]=(short)f2bf(b.w);
    return r;
}

// ---------------- Kernel A: dists as tiled f32 GEMM + argmax + aux partials ------
__global__ __launch_bounds__(256, 4) void dists_kernel(
    const float* __restrict__ q, const float* __restrict__ k,
    const float* __restrict__ means,
    float* __restrict__ distsQ, float* __restrict__ distsK,
    float* __restrict__ aux_part)
{
    __shared__ float xS[64][68];   // [d][tok]; reused as dS[tok][c] after GEMM
    __shared__ float mS[64][68];   // [d][cluster]
    __shared__ float mqS[64];      // per-cluster ||m||^2

    const int chunks = (2 * TT) / 64;          // 128
    int bid = blockIdx.x;                      // 4096
    int bh = bid / chunks;
    int chunk = bid % chunks;
    int h = bh % HH;
    bool isQ = chunk < (TT / 64);
    int tbase = (isQ ? chunk : chunk - 64) * 64;
    const float* src = (isQ ? q : k) + ((size_t)bh * TT + tbase) * DD;
    float* dst = isQ ? distsQ : distsK;

    int tid = threadIdx.x;
    int tok = tid >> 2, part = tid & 3;        // tok doubles as cluster idx below

    // ---- stage means (transposed) + per-cluster sumsq ----
    {
        const float* mp = means + ((size_t)h * NCC + tok) * DD + part * 16;
        float4 va[4];
        #pragma unroll
        for (int i = 0; i < 4; ++i) va[i] = *(const float4*)(mp + i * 4);
        float msq = 0.f;
        #pragma unroll
        for (int i = 0; i < 4; ++i) {
            msq += va[i].x*va[i].x + va[i].y*va[i].y + va[i].z*va[i].z + va[i].w*va[i].w;
            int d = part * 16 + i * 4;
            mS[d][tok] = va[i].x; mS[d+1][tok] = va[i].y;
            mS[d+2][tok] = va[i].z; mS[d+3][tok] = va[i].w;
        }
        msq += __shfl_xor(msq, 1);
        msq += __shfl_xor(msq, 2);
        if (part == 0) mqS[tok] = msq;
    }
    // ---- stage x normalized (transposed) ----
    float ssn;
    {
        const float* xp = src + (size_t)tok * DD + part * 16;
        float4 va[4];
        #pragma unroll
        for (int i = 0; i < 4; ++i) va[i] = *(const float4*)(xp + i * 4);
        float ss = 0.f;
        #pragma unroll
        for (int i = 0; i < 4; ++i)
            ss += va[i].x*va[i].x + va[i].y*va[i].y + va[i].z*va[i].z + va[i].w*va[i].w;
        ss += __shfl_xor(ss, 1);
        ss += __shfl_xor(ss, 2);
        float inv = 1.f / fmaxf(sqrtf(ss), 1e-12f);
        ssn = ss * inv * inv;
        #pragma unroll
        for (int i = 0; i < 4; ++i) {
            int d = part * 16 + i * 4;
            xS[d][tok] = va[i].x*inv; xS[d+1][tok] = va[i].y*inv;
            xS[d+2][tok] = va[i].z*inv; xS[d+3][tok] = va[i].w*inv;
        }
    }
    __syncthreads();

    // ---- GEMM: thread = 4 tokens x 4 clusters ----
    int l = tid & 63, w = tid >> 6;
    int ti = l & 15;                 // token tile 4*ti..
    int ci = w * 4 + (l >> 4);       // cluster tile 4*ci..
    float acc[4][4];
    #pragma unroll
    for (int i = 0; i < 4; ++i)
        #pragma unroll
        for (int j = 0; j < 4; ++j) acc[i][j] = 0.f;

    #pragma unroll 16
    for (int kk = 0; kk < 64; ++kk) {
        float4 xv = *(const float4*)(&xS[kk][ti * 4]);
        float4 mv = *(const float4*)(&mS[kk][ci * 4]);
        float xa[4] = {xv.x, xv.y, xv.z, xv.w};
        float ma[4] = {mv.x, mv.y, mv.z, mv.w};
        #pragma unroll
        for (int i = 0; i < 4; ++i)
            #pragma unroll
            for (int j = 0; j < 4; ++j) acc[i][j] += xa[i] * ma[j];
    }

    // ---- store dists to global (coalesced float4 over tokens) ----
    {
        size_t rowb = (size_t)(bh * NCC) * TT;
        #pragma unroll
        for (int j = 0; j < 4; ++j) {
            int c = ci * 4 + j;
            float4 o;
            o.x = acc[0][j]; o.y = acc[1][j]; o.z = acc[2][j]; o.w = acc[3][j];
            *(float4*)&dst[rowb + (size_t)c * TT + tbase + ti * 4] = o;
        }
    }

    // ---- argmax + aux via LDS round-trip (reuse xS as dS[tok][c]) ----
    __syncthreads();
    #pragma unroll
    for (int i = 0; i < 4; ++i)
        #pragma unroll
        for (int j = 0; j < 4; ++j)
            xS[ti * 4 + i][ci * 4 + j] = acc[i][j];
    __syncthreads();

    float bv = -1e30f; int bc = 0;
    #pragma unroll
    for (int j = 0; j < 16; ++j) {
        int c = part * 16 + j;
        float vv = xS[tok][c];
        if (vv > bv) { bv = vv; bc = c; }
    }
    #pragma unroll
    for (int off = 1; off <= 2; off <<= 1) {
        float ov = __shfl_xor(bv, off);
        int   oc = __shfl_xor(bc, off);
        if (ov > bv || (ov == bv && oc < bc)) { bv = ov; bc = oc; }
    }
    float auxv = (part == 0) ? (ssn + mqS[bc] - 2.f * bv) : 0.f;
    #pragma unroll
    for (int off = 32; off; off >>= 1) auxv += __shfl_xor(auxv, off);
    if (l == 0) aux_part[bid * 4 + w] = auxv;
}

// ---------------- Kernel A2: reduce 16384 aux partials -> out[N] ----------------
__global__ __launch_bounds__(256) void aux_reduce_kernel(
    const float* __restrict__ aux_part, float* __restrict__ out)
{
    int t = threadIdx.x;
    float s = 0.f;
    for (int i = t; i < 16384; i += 256) s += aux_part[i];
    #pragma unroll
    for (int off = 32; off; off >>= 1) s += __shfl_xor(s, off);
    __shared__ float wsum[4];
    if ((t & 63) == 0) wsum[t >> 6] = s;
    __syncthreads();
    if (t == 0)
        out[(size_t)BB * HH * TT * DD] =
            (wsum[0] + wsum[1] + wsum[2] + wsum[3]) *
            (1.0f / (float)(BB * HH * 2 * TT * DD));
}

// ---------------- Kernel B: top-TPK per row via 4-pass radix select ----------------
__global__ __launch_bounds__(256) void topk_kernel(
    const float* __restrict__ dists, int* __restrict__ idxOut)
{
    int row = blockIdx.x;
    const float* dv = dists + (size_t)row * TT;
    int t = threadIdx.x;

    unsigned u[16];
    #pragma unroll
    for (int j = 0; j < 16; ++j) {
        unsigned b = __float_as_uint(dv[j * 256 + t]);
        u[j] = (b & 0x80000000u) ? ~b : (b | 0x80000000u);
    }

    __shared__ int hist[256];
    __shared__ int sfx[256];
    __shared__ int binSel, tgtS;
    __shared__ int nGtS, posS, eqFilled;
    __shared__ int waveCnt[4];

    int target = TPK;
    unsigned prefix = 0;

    for (int shift = 24; shift >= 0; shift -= 8) {
        hist[t] = 0;
        __syncthreads();
        #pragma unroll
        for (int j = 0; j < 16; ++j) {
            bool act = (shift == 24) || ((u[j] >> (shift + 8)) == (prefix >> (shift + 8)));
            if (act) atomicAdd(&hist[(u[j] >> shift) & 255], 1);
        }
        __syncthreads();
        sfx[t] = hist[t];
        __syncthreads();
        for (int off = 1; off < 256; off <<= 1) {
            int add = (t + off < 256) ? sfx[t + off] : 0;
            int cur = sfx[t];
            __syncthreads();
            sfx[t] = cur + add;
            __syncthreads();
        }
        int nxt = (t == 255) ? 0 : sfx[t + 1];
        if (sfx[t] >= target && nxt < target) { binSel = t; tgtS = target - nxt; }
        __syncthreads();
        prefix |= ((unsigned)binSel) << shift;
        target = tgtS;
        __syncthreads();
    }

    unsigned pivot = prefix;
    if (t == 0) { nGtS = 0; posS = 0; eqFilled = 0; }
    __syncthreads();
    int myg = 0;
    #pragma unroll
    for (int j = 0; j < 16; ++j) myg += (u[j] > pivot) ? 1 : 0;
    if (myg) atomicAdd(&nGtS, myg);
    __syncthreads();
    int n_gt = nGtS;
    int n_need = TPK - n_gt;
    int* out = idxOut + (size_t)row * TPK;

    #pragma unroll
    for (int j = 0; j < 16; ++j)
        if (u[j] > pivot) { int p = atomicAdd(&posS, 1); out[p] = j * 256 + t; }

    int lane = t & 63, wv = t >> 6;
    for (int j = 0; j < 16; ++j) {
        if (eqFilled >= n_need) break;
        bool fl = (u[j] == pivot);
        unsigned long long bal = __ballot(fl);
        if (lane == 0) waveCnt[wv] = __popcll(bal);
        __syncthreads();
        int offw = 0;
        for (int w = 0; w < wv; ++w) offw += waveCnt[w];
        int mypos = eqFilled + offw + __popcll(bal & ((lane ? ((1ull << lane) - 1ull) : 0ull)));
        if (fl && mypos < n_need) out[n_gt + mypos] = j * 256 + t;
        __syncthreads();
        if (t == 0) eqFilled += waveCnt[0] + waveCnt[1] + waveCnt[2] + waveCnt[3];
        __syncthreads();
    }
}

// ---------------- Kernel B2: f64 rescore, 4 lanes per candidate ----------------
__global__ __launch_bounds__(640) void rescore_kernel(
    const float* __restrict__ q, const float* __restrict__ k,
    const float* __restrict__ means,
    const int* __restrict__ candQ, const int* __restrict__ candK,
    int* __restrict__ idxQ, int* __restrict__ idxK)
{
    int rid = blockIdx.x;
    int side = rid >> 11;            // 0=Q, 1=K
    int row = rid & 2047;            // bh*NC + c
    int c = row & (NCC - 1);
    int bh = row >> 6;
    int h = bh % HH;

    const int* cand = (side ? candK : candQ) + (size_t)row * TPK;
    int* outIdx     = (side ? idxK : idxQ) + (size_t)row * WSZW;
    const float* xbase = (side ? k : q) + (size_t)bh * TT * DD;

    __shared__ double mD[DD];
    __shared__ double vS[TPK];
    __shared__ int    kiS[TPK];
    __shared__ int    rankS[TPK];

    int tid = threadIdx.x;
    if (tid < DD) mD[tid] = (double)means[((size_t)h * NCC + c) * DD + tid];
    __syncthreads();

    int g = tid >> 2;                // candidate 0..159
    int qt = tid & 3;                // quarter-row 0..3
    int tok = cand[g];
    const float* xp = xbase + (size_t)tok * DD + qt * 16;
    double dot = 0.0, ss = 0.0;
    #pragma unroll
    for (int i = 0; i < 4; ++i) {
        float4 va = *(const float4*)(xp + i * 4);
        int d = qt * 16 + i * 4;
        dot += (double)va.x * mD[d]   + (double)va.y * mD[d+1]
             + (double)va.z * mD[d+2] + (double)va.w * mD[d+3];
        ss  += (double)va.x * va.x + (double)va.y * va.y
             + (double)va.z * va.z + (double)va.w * va.w;
    }
    dot += __shfl_xor(dot, 1); dot += __shfl_xor(dot, 2);
    ss  += __shfl_xor(ss, 1);  ss  += __shfl_xor(ss, 2);
    double v = dot * (1.0 / fmax(sqrt(ss), 1e-12));
    if (qt == 0) { vS[g] = v; kiS[g] = tok; }
    __syncthreads();

    // rank: each lane counts its 40-candidate quarter, combine in-group
    int rk = 0;
    #pragma unroll 8
    for (int i = 0; i < TPK / 4; ++i) {
        int j = qt * (TPK / 4) + i;
        double vj = vS[j];
        int kj = kiS[j];
        rk += (vj > v || (vj == v && kj < tok)) ? 1 : 0;
    }
    rk += __shfl_xor(rk, 1); rk += __shfl_xor(rk, 2);
    if (qt == 0) rankS[g] = rk;
    __syncthreads();

    if (tid < TPK) {
        int r = rankS[tid];
        if (r < WSZW) outIdx[r] = kiS[tid];
    }
}

// ---------------- Kernel C: bf16 MFMA attention, swapped-QK^T, V transposed ----
// 512 thr = 8 waves; wave w owns q rows w*16..+15. Swapped S^T = mfma(K,Q):
// lane holds P[q=lr][kv=kvt*16+lg*4+r] in regs -> PV A-frag built by 8 shfl
// (no LDS P, no fences). V staged transposed Vt[d][kv] (pad 168) -> PV B-frag
// is one aligned ds_read_b128.
__global__ __launch_bounds__(512, 2) void attn_kernel(
    const float* __restrict__ q, const float* __restrict__ k, const float* __restrict__ v,
    const float* __restrict__ mem_key, const float* __restrict__ mem_value,
    const int* __restrict__ idxQ, const int* __restrict__ idxK,
    float* __restrict__ so)
{
    int blk = blockIdx.x;        // bh*NC + c
    int c = blk % NCC;
    int bh = blk / NCC;
    int h = bh % HH;

    __shared__ __align__(16) unsigned short KsS[160 * 64];   // [kv][d] swizzled
    __shared__ __align__(16) unsigned short VtS[64 * 168];   // [d][kv], pad 168

    int tid = threadIdx.x;

    // ---- stage K (swizzled rows) + V transposed, f32 -> bf16 ----
    if (tid < 320) {
        int row = tid >> 1, hh = tid & 1;
        const float* ksrc = nullptr; const float* vsrc = nullptr;
        if (row == 0) {
            ksrc = mem_key   + ((size_t)h * NCC + c) * (MEMN * DD);
            vsrc = mem_value + ((size_t)h * NCC + c) * (MEMN * DD);
        } else if (row < KVW) {
            int tk = idxK[(size_t)blk * WSZW + row - 1];
            ksrc = k + ((size_t)bh * TT + tk) * DD;
            vsrc = v + ((size_t)bh * TT + tk) * DD;
        }
        #pragma unroll
        for (int cch = 0; cch < 4; ++cch) {
            uint4 kw = {0,0,0,0};
            unsigned short vs[8] = {0,0,0,0,0,0,0,0};
            if (ksrc) {
                int base = hh * 32 + cch * 8;
                float4 a = *(const float4*)(ksrc + base);
                float4 b = *(const float4*)(ksrc + base + 4);
                kw.x = pk2(a.x, a.y); kw.y = pk2(a.z, a.w);
                kw.z = pk2(b.x, b.y); kw.w = pk2(b.z, b.w);
                a = *(const float4*)(vsrc + base);
                b = *(const float4*)(vsrc + base + 4);
                vs[0]=f2bf(a.x); vs[1]=f2bf(a.y); vs[2]=f2bf(a.z); vs[3]=f2bf(a.w);
                vs[4]=f2bf(b.x); vs[5]=f2bf(b.y); vs[6]=f2bf(b.z); vs[7]=f2bf(b.w);
            }
            int chunk = hh * 4 + cch;
            int phys = chunk ^ (row & 7);
            *reinterpret_cast<uint4*>(&KsS[row * 64 + phys * 8]) = kw;
            int dbase = hh * 32 + cch * 8;
            #pragma unroll
            for (int i = 0; i < 8; ++i)
                VtS[(dbase + i) * 168 + row] = vs[i];
        }
    }

    int w = tid >> 6, l = tid & 63;
    int lr = l & 15, lg = l >> 4;

    // ---- Q frags (used as B operand; same per-lane data as A) ----
    bf16x8 qf[2];
    {
        int tq = idxQ[(size_t)blk * WSZW + w * 16 + lr];
        const float* qp = q + ((size_t)bh * TT + tq) * DD;
        #pragma unroll
        for (int ks = 0; ks < 2; ++ks) {
            float4 a = *(const float4*)(qp + ks * 32 + lg * 8);
            float4 b = *(const float4*)(qp + ks * 32 + lg * 8 + 4);
            qf[ks] = pack8(a, b);
        }
    }

    f32x4 acc[4];
    #pragma unroll
    for (int dt = 0; dt < 4; ++dt) acc[dt] = (f32x4){0.f, 0.f, 0.f, 0.f};
    float s_sum = 0.f;     // per lane: partial denom for q = lr

    __syncthreads();

    int src0 = lr + ((lg & 1) * 2) * 16;
    int src1 = src0 + 16;
    bool hi = (lg >> 1) != 0;

    for (int kb = 0; kb < 5; ++kb) {
        // K frags (A operand): row = kv, swizzled chunks
        bf16x8 kf[2][2];
        #pragma unroll
        for (int kvt = 0; kvt < 2; ++kvt)
            #pragma unroll
            for (int ks = 0; ks < 2; ++ks) {
                int row = kb * 32 + kvt * 16 + lr;
                int chunk = ks * 4 + lg;
                int phys = chunk ^ (row & 7);
                kf[kvt][ks] = *reinterpret_cast<const bf16x8*>(&KsS[row * 64 + phys * 8]);
            }
        // S^T tiles + exp (P stays in registers)
        unsigned pk[2][2];
        #pragma unroll
        for (int kvt = 0; kvt < 2; ++kvt) {
            f32x4 sf = __builtin_amdgcn_mfma_f32_16x16x32_bf16(
                kf[kvt][0], qf[0], (f32x4){0.f,0.f,0.f,0.f}, 0, 0, 0);
            sf = __builtin_amdgcn_mfma_f32_16x16x32_bf16(kf[kvt][1], qf[1], sf, 0, 0, 0);
            float e[4];
            #pragma unroll
            for (int r = 0; r < 4; ++r) {
                int kv = kb * 32 + kvt * 16 + lg * 4 + r;
                e[r] = (kv < KVW) ? __expf(sf[r] * SCALE) : 0.f;
                s_sum += e[r];
            }
            pk[kvt][0] = pk2(e[0], e[1]);
            pk[kvt][1] = pk2(e[2], e[3]);
        }
        // assemble PV A-frag: pa[j] = P[q=lr][kv32 = lg*8+j]
        unsigned a00 = __shfl(pk[0][0], src0), a01 = __shfl(pk[0][1], src0);
        unsigned a10 = __shfl(pk[1][0], src0), a11 = __shfl(pk[1][1], src0);
        unsigned b00 = __shfl(pk[0][0], src1), b01 = __shfl(pk[0][1], src1);
        unsigned b10 = __shfl(pk[1][0], src1), b11 = __shfl(pk[1][1], src1);
        union { unsigned u[4]; bf16x8 v; } pu;
        pu.u[0] = hi ? a10 : a00;
        pu.u[1] = hi ? a11 : a01;
        pu.u[2] = hi ? b10 : b00;
        pu.u[3] = hi ? b11 : b01;
        // PV: B-frag = single b128 from Vt
        #pragma unroll
        for (int dt = 0; dt < 4; ++dt) {
            bf16x8 vf = *reinterpret_cast<const bf16x8*>(
                &VtS[(dt * 16 + lr) * 168 + kb * 32 + lg * 8]);
            acc[dt] = __builtin_amdgcn_mfma_f32_16x16x32_bf16(pu.v, vf, acc[dt], 0, 0, 0);
        }
    }

    // denom: full sum for q=lr at every lane, then broadcast to row owners
    s_sum += __shfl_xor(s_sum, 16);
    s_sum += __shfl_xor(s_sum, 32);
    float sinv[4];
    #pragma unroll
    for (int r = 0; r < 4; ++r)
        sinv[r] = 1.f / __shfl(s_sum, lg * 4 + r);

    // store O: row q = w*16 + lg*4 + r, col d = dt*16 + lr
    #pragma unroll
    for (int r = 0; r < 4; ++r) {
        int row = w * 16 + lg * 4 + r;
        float* op = so + (((size_t)blk * WSZW + row) * DD);
        #pragma unroll
        for (int dt = 0; dt < 4; ++dt)
            op[dt * 16 + lr] = acc[dt][r] * sinv[r];
    }
}

// ---------------- Kernel E: histogram of token selections ----------------
__global__ __launch_bounds__(256) void count_kernel(
    const int* __restrict__ idxQ, int* __restrict__ counts)
{
    int i = blockIdx.x * 256 + threadIdx.x;
    int bh = i >> 13;
    atomicAdd(&counts[bh * TT + idxQ[i]], 1);
}

// ---------------- Kernel F: per-bh exclusive scan (4096 ints) ----------------
__global__ __launch_bounds__(256) void scan_kernel(
    const int* __restrict__ counts, int* __restrict__ offs)
{
    int bh = blockIdx.x;
    int t = threadIdx.x;
    const int* cb = counts + (size_t)bh * TT;
    int* ob = offs + (size_t)bh * TT;

    int loc[16]; int sum = 0;
    #pragma unroll
    for (int i = 0; i < 16; ++i) { loc[i] = sum; sum += cb[t * 16 + i]; }

    __shared__ int wsum[256];
    wsum[t] = sum;
    __syncthreads();
    for (int off = 1; off < 256; off <<= 1) {
        int vv = (t >= off) ? wsum[t - off] : 0;
        __syncthreads();
        wsum[t] += vv;
        __syncthreads();
    }
    int ex = (t == 0) ? 0 : wsum[t - 1];
    #pragma unroll
    for (int i = 0; i < 16; ++i) ob[t * 16 + i] = ex + loc[i];
}

// ---------------- Kernel G: fill CSR slot lists ----------------
__global__ __launch_bounds__(256) void fill_kernel(
    const int* __restrict__ idxQ, const int* __restrict__ offs,
    int* __restrict__ cur, int* __restrict__ csr)
{
    int i = blockIdx.x * 256 + threadIdx.x;
    int bh = i >> 13;
    int within = i & 8191;
    int tok = idxQ[i];
    int p = offs[bh * TT + tok] + atomicAdd(&cur[bh * TT + tok], 1);
    csr[((size_t)bh << 13) + p] = within;
}

// ---------------- Kernel H: gather-reduce + finalize ----------------
__global__ __launch_bounds__(256) void reduce_kernel(
    const float* __restrict__ so, const int* __restrict__ counts,
    const int* __restrict__ offs, const int* __restrict__ csr,
    float* __restrict__ out)
{
    int gt = blockIdx.x * 4 + (threadIdx.x >> 6);
    int lane = threadIdx.x & 63;
    int bh = gt >> 12;
    int n = counts[gt];
    int st = offs[gt];
    const int* cs = csr + ((size_t)bh << 13);
    float acc = 0.f;
    for (int j = 0; j < n; ++j) {
        int slot = cs[st + j];
        acc += so[(((size_t)bh << 13) + slot) * DD + lane];
    }
    out[(size_t)gt * DD + lane] = acc / ((float)n + EPSF);
}

extern "C" void kernel_launch(void* const* d_in, const int* in_sizes, int n_in,
                              void* d_out, int out_size, void* d_ws, size_t ws_size,
                              hipStream_t stream) {
    const float* q        = (const float*)d_in[0];
    const float* k        = (const float*)d_in[1];
    const float* v        = (const float*)d_in[2];
    const float* means    = (const float*)d_in[3];
    const float* mem_val  = (const float*)d_in[5];
    const float* mem_key  = (const float*)d_in[4];
    float* out = (float*)d_out;

    const size_t nRows = (size_t)BB * HH * NCC;             // 2048
    const size_t nTok  = (size_t)BB * HH * TT;              // 131072
    float* wsf    = (float*)d_ws;
    float* distsQ = wsf;                                    // 8388608 f
    float* distsK = distsQ + (size_t)BB * HH * NCC * TT;    // 8388608 f
    float* so     = wsf;                                    // aliases dists; written after rescore
    int*   idxQ   = (int*)(distsK + (size_t)BB * HH * NCC * TT);  // 262144 i
    int*   idxK   = idxQ + nRows * WSZW;                    // 262144 i
    int*   counts = idxK + nRows * WSZW;                    // 131072 i
    int*   cur    = counts + nTok;                          // 131072 i
    float* auxp   = (float*)(cur + nTok);                   // 16384 f (per-wave partials)
    int*   offs   = (int*)(auxp + 16384);                   // 131072 i
    int*   csr    = offs + nTok;                            // 262144 i
    int*   candQ  = csr + nTok * 2;                         // 2048*160 i
    int*   candK  = candQ + nRows * TPK;                    // 2048*160 i

    hipMemsetAsync(counts, 0, 2 * nTok * sizeof(int), stream);

    dists_kernel<<<dim3(BB * HH * (2 * TT / 64)), dim3(256), 0, stream>>>(
        q, k, means, distsQ, distsK, auxp);
    aux_reduce_kernel<<<dim3(1), dim3(256), 0, stream>>>(auxp, out);
    topk_kernel<<<dim3((unsigned)nRows), dim3(256), 0, stream>>>(distsQ, candQ);
    topk_kernel<<<dim3((unsigned)nRows), dim3(256), 0, stream>>>(distsK, candK);
    rescore_kernel<<<dim3((unsigned)(2 * nRows)), dim3(640), 0, stream>>>(
        q, k, means, candQ, candK, idxQ, idxK);
    count_kernel<<<dim3(1024), dim3(256), 0, stream>>>(idxQ, counts);
    scan_kernel<<<dim3(BB * HH), dim3(256), 0, stream>>>(counts, offs);
    fill_kernel<<<dim3(1024), dim3(256), 0, stream>>>(idxQ, offs, cur, csr);
    attn_kernel<<<dim3((unsigned)nRows), dim3(512), 0, stream>>>(
        q, k, v, mem_key, mem_val, idxQ, idxK, so);
    reduce_kernel<<<dim3((unsigned)(nTok / 4)), dim3(256), 0, stream>>>(
        so, counts, offs, csr, out);
}

// Round 13
// 296.142 us; speedup vs baseline: 1.6711x; 1.0325x over previous
//
#include <hip/hip_runtime.h>
#include <math.h>

#define BB 4
#define HH 8
#define TT 4096
#define DD 64
#define NCC 64
#define WSZW 128
#define TPK 160          // widened f32 top-k; f64 rescore picks exact top-128
#define MEMN 1
#define KVW (MEMN + WSZW)   // 129
constexpr float EPSF = 1e-5f;
constexpr float SCALE = 0.125f;  // 64^-0.5

typedef __attribute__((ext_vector_type(8))) short bf16x8;
typedef __attribute__((ext_vector_type(4))) float f32x4;

static __device__ __forceinline__ unsigned short f2bf(float f) {
    union { float f; unsigned int u; } v; v.f = f;
    unsigned int r = v.u + 0x7FFFu + ((v.u >> 16) & 1u);   // RNE
    return (unsigned short)(r >> 16);
}
static __device__ __forceinline__ unsigned int pk2(float a, float b) {
    return (unsigned int)f2bf(a) | ((unsigned int)f2bf(b) << 16);
}
static __device__ __forceinline__ bf16x8 pack8(float4 a, float4 b) {
    bf16x8 r;
    r[0]=(short)f2bf(a.x); r[1]=(short)f2bf(a.y); r[2]=(short)f2bf(a.z); r[3]=(short)f2bf(a.w);
    r[4]=(short)f2bf(b.x); r[5]=(short)f2bf(b.y); r[6]=(short)f2bf(b.z); r[7]=(short)f2bf(b.w);
    return r;
}

// ---------------- Kernel A: dists as tiled f32 GEMM + argmax + aux partials ------
__global__ __launch_bounds__(256, 4) void dists_kernel(
    const float* __restrict__ q, const float* __restrict__ k,
    const float* __restrict__ means,
    float* __restrict__ distsQ, float* __restrict__ distsK,
    float* __restrict__ aux_part)
{
    __shared__ float xS[64][68];   // [d][tok]; reused as dS[tok][c] after GEMM
    __shared__ float mS[64][68];   // [d][cluster]
    __shared__ float mqS[64];      // per-cluster ||m||^2

    const int chunks = (2 * TT) / 64;          // 128
    int bid = blockIdx.x;                      // 4096
    int bh = bid / chunks;
    int chunk = bid % chunks;
    int h = bh % HH;
    bool isQ = chunk < (TT / 64);
    int tbase = (isQ ? chunk : chunk - 64) * 64;
    const float* src = (isQ ? q : k) + ((size_t)bh * TT + tbase) * DD;
    float* dst = isQ ? distsQ : distsK;

    int tid = threadIdx.x;
    int tok = tid >> 2, part = tid & 3;        // tok doubles as cluster idx below

    // ---- stage means (transposed) + per-cluster sumsq ----
    {
        const float* mp = means + ((size_t)h * NCC + tok) * DD + part * 16;
        float4 va[4];
        #pragma unroll
        for (int i = 0; i < 4; ++i) va[i] = *(const float4*)(mp + i * 4);
        float msq = 0.f;
        #pragma unroll
        for (int i = 0; i < 4; ++i) {
            msq += va[i].x*va[i].x + va[i].y*va[i].y + va[i].z*va[i].z + va[i].w*va[i].w;
            int d = part * 16 + i * 4;
            mS[d][tok] = va[i].x; mS[d+1][tok] = va[i].y;
            mS[d+2][tok] = va[i].z; mS[d+3][tok] = va[i].w;
        }
        msq += __shfl_xor(msq, 1);
        msq += __shfl_xor(msq, 2);
        if (part == 0) mqS[tok] = msq;
    }
    // ---- stage x normalized (transposed) ----
    float ssn;
    {
        const float* xp = src + (size_t)tok * DD + part * 16;
        float4 va[4];
        #pragma unroll
        for (int i = 0; i < 4; ++i) va[i] = *(const float4*)(xp + i * 4);
        float ss = 0.f;
        #pragma unroll
        for (int i = 0; i < 4; ++i)
            ss += va[i].x*va[i].x + va[i].y*va[i].y + va[i].z*va[i].z + va[i].w*va[i].w;
        ss += __shfl_xor(ss, 1);
        ss += __shfl_xor(ss, 2);
        float inv = 1.f / fmaxf(sqrtf(ss), 1e-12f);
        ssn = ss * inv * inv;
        #pragma unroll
        for (int i = 0; i < 4; ++i) {
            int d = part * 16 + i * 4;
            xS[d][tok] = va[i].x*inv; xS[d+1][tok] = va[i].y*inv;
            xS[d+2][tok] = va[i].z*inv; xS[d+3][tok] = va[i].w*inv;
        }
    }
    __syncthreads();

    // ---- GEMM: thread = 4 tokens x 4 clusters ----
    int l = tid & 63, w = tid >> 6;
    int ti = l & 15;                 // token tile 4*ti..
    int ci = w * 4 + (l >> 4);       // cluster tile 4*ci..
    float acc[4][4];
    #pragma unroll
    for (int i = 0; i < 4; ++i)
        #pragma unroll
        for (int j = 0; j < 4; ++j) acc[i][j] = 0.f;

    #pragma unroll 16
    for (int kk = 0; kk < 64; ++kk) {
        float4 xv = *(const float4*)(&xS[kk][ti * 4]);
        float4 mv = *(const float4*)(&mS[kk][ci * 4]);
        float xa[4] = {xv.x, xv.y, xv.z, xv.w};
        float ma[4] = {mv.x, mv.y, mv.z, mv.w};
        #pragma unroll
        for (int i = 0; i < 4; ++i)
            #pragma unroll
            for (int j = 0; j < 4; ++j) acc[i][j] += xa[i] * ma[j];
    }

    // ---- store dists to global (coalesced float4 over tokens) ----
    {
        size_t rowb = (size_t)(bh * NCC) * TT;
        #pragma unroll
        for (int j = 0; j < 4; ++j) {
            int c = ci * 4 + j;
            float4 o;
            o.x = acc[0][j]; o.y = acc[1][j]; o.z = acc[2][j]; o.w = acc[3][j];
            *(float4*)&dst[rowb + (size_t)c * TT + tbase + ti * 4] = o;
        }
    }

    // ---- argmax + aux via LDS round-trip (reuse xS as dS[tok][c]) ----
    __syncthreads();
    #pragma unroll
    for (int i = 0; i < 4; ++i)
        #pragma unroll
        for (int j = 0; j < 4; ++j)
            xS[ti * 4 + i][ci * 4 + j] = acc[i][j];
    __syncthreads();

    float bv = -1e30f; int bc = 0;
    #pragma unroll
    for (int j = 0; j < 16; ++j) {
        int c = part * 16 + j;
        float vv = xS[tok][c];
        if (vv > bv) { bv = vv; bc = c; }
    }
    #pragma unroll
    for (int off = 1; off <= 2; off <<= 1) {
        float ov = __shfl_xor(bv, off);
        int   oc = __shfl_xor(bc, off);
        if (ov > bv || (ov == bv && oc < bc)) { bv = ov; bc = oc; }
    }
    float auxv = (part == 0) ? (ssn + mqS[bc] - 2.f * bv) : 0.f;
    #pragma unroll
    for (int off = 32; off; off >>= 1) auxv += __shfl_xor(auxv, off);
    if (l == 0) aux_part[bid * 4 + w] = auxv;
}

// ---------------- Kernel A2: reduce 16384 aux partials -> out[N] ----------------
__global__ __launch_bounds__(256) void aux_reduce_kernel(
    const float* __restrict__ aux_part, float* __restrict__ out)
{
    int t = threadIdx.x;
    float s = 0.f;
    for (int i = t; i < 16384; i += 256) s += aux_part[i];
    #pragma unroll
    for (int off = 32; off; off >>= 1) s += __shfl_xor(s, off);
    __shared__ float wsum[4];
    if ((t & 63) == 0) wsum[t >> 6] = s;
    __syncthreads();
    if (t == 0)
        out[(size_t)BB * HH * TT * DD] =
            (wsum[0] + wsum[1] + wsum[2] + wsum[3]) *
            (1.0f / (float)(BB * HH * 2 * TT * DD));
}

// ---------------- Kernel B: top-TPK per row via 4-pass radix select ----------------
__global__ __launch_bounds__(256) void topk_kernel(
    const float* __restrict__ dists, int* __restrict__ idxOut)
{
    int row = blockIdx.x;
    const float* dv = dists + (size_t)row * TT;
    int t = threadIdx.x;

    unsigned u[16];
    #pragma unroll
    for (int j = 0; j < 16; ++j) {
        unsigned b = __float_as_uint(dv[j * 256 + t]);
        u[j] = (b & 0x80000000u) ? ~b : (b | 0x80000000u);
    }

    __shared__ int hist[256];
    __shared__ int sfx[256];
    __shared__ int binSel, tgtS;
    __shared__ int nGtS, posS, eqFilled;
    __shared__ int waveCnt[4];

    int target = TPK;
    unsigned prefix = 0;

    for (int shift = 24; shift >= 0; shift -= 8) {
        hist[t] = 0;
        __syncthreads();
        #pragma unroll
        for (int j = 0; j < 16; ++j) {
            bool act = (shift == 24) || ((u[j] >> (shift + 8)) == (prefix >> (shift + 8)));
            if (act) atomicAdd(&hist[(u[j] >> shift) & 255], 1);
        }
        __syncthreads();
        sfx[t] = hist[t];
        __syncthreads();
        for (int off = 1; off < 256; off <<= 1) {
            int add = (t + off < 256) ? sfx[t + off] : 0;
            int cur = sfx[t];
            __syncthreads();
            sfx[t] = cur + add;
            __syncthreads();
        }
        int nxt = (t == 255) ? 0 : sfx[t + 1];
        if (sfx[t] >= target && nxt < target) { binSel = t; tgtS = target - nxt; }
        __syncthreads();
        prefix |= ((unsigned)binSel) << shift;
        target = tgtS;
        __syncthreads();
    }

    unsigned pivot = prefix;
    if (t == 0) { nGtS = 0; posS = 0; eqFilled = 0; }
    __syncthreads();
    int myg = 0;
    #pragma unroll
    for (int j = 0; j < 16; ++j) myg += (u[j] > pivot) ? 1 : 0;
    if (myg) atomicAdd(&nGtS, myg);
    __syncthreads();
    int n_gt = nGtS;
    int n_need = TPK - n_gt;
    int* out = idxOut + (size_t)row * TPK;

    #pragma unroll
    for (int j = 0; j < 16; ++j)
        if (u[j] > pivot) { int p = atomicAdd(&posS, 1); out[p] = j * 256 + t; }

    int lane = t & 63, wv = t >> 6;
    for (int j = 0; j < 16; ++j) {
        if (eqFilled >= n_need) break;
        bool fl = (u[j] == pivot);
        unsigned long long bal = __ballot(fl);
        if (lane == 0) waveCnt[wv] = __popcll(bal);
        __syncthreads();
        int offw = 0;
        for (int w = 0; w < wv; ++w) offw += waveCnt[w];
        int mypos = eqFilled + offw + __popcll(bal & ((lane ? ((1ull << lane) - 1ull) : 0ull)));
        if (fl && mypos < n_need) out[n_gt + mypos] = j * 256 + t;
        __syncthreads();
        if (t == 0) eqFilled += waveCnt[0] + waveCnt[1] + waveCnt[2] + waveCnt[3];
        __syncthreads();
    }
}

// ---------------- Kernel B2: f64 rescore, 4 lanes per candidate ----------------
__global__ __launch_bounds__(640) void rescore_kernel(
    const float* __restrict__ q, const float* __restrict__ k,
    const float* __restrict__ means,
    const int* __restrict__ candQ, const int* __restrict__ candK,
    int* __restrict__ idxQ, int* __restrict__ idxK)
{
    int rid = blockIdx.x;
    int side = rid >> 11;            // 0=Q, 1=K
    int row = rid & 2047;            // bh*NC + c
    int c = row & (NCC - 1);
    int bh = row >> 6;
    int h = bh % HH;

    const int* cand = (side ? candK : candQ) + (size_t)row * TPK;
    int* outIdx     = (side ? idxK : idxQ) + (size_t)row * WSZW;
    const float* xbase = (side ? k : q) + (size_t)bh * TT * DD;

    __shared__ double mD[DD];
    __shared__ double vS[TPK];
    __shared__ int    kiS[TPK];
    __shared__ int    rankS[TPK];

    int tid = threadIdx.x;
    if (tid < DD) mD[tid] = (double)means[((size_t)h * NCC + c) * DD + tid];
    __syncthreads();

    int g = tid >> 2;                // candidate 0..159
    int qt = tid & 3;                // quarter-row 0..3
    int tok = cand[g];
    const float* xp = xbase + (size_t)tok * DD + qt * 16;
    double dot = 0.0, ss = 0.0;
    #pragma unroll
    for (int i = 0; i < 4; ++i) {
        float4 va = *(const float4*)(xp + i * 4);
        int d = qt * 16 + i * 4;
        dot += (double)va.x * mD[d]   + (double)va.y * mD[d+1]
             + (double)va.z * mD[d+2] + (double)va.w * mD[d+3];
        ss  += (double)va.x * va.x + (double)va.y * va.y
             + (double)va.z * va.z + (double)va.w * va.w;
    }
    dot += __shfl_xor(dot, 1); dot += __shfl_xor(dot, 2);
    ss  += __shfl_xor(ss, 1);  ss  += __shfl_xor(ss, 2);
    double v = dot * (1.0 / fmax(sqrt(ss), 1e-12));
    if (qt == 0) { vS[g] = v; kiS[g] = tok; }
    __syncthreads();

    // rank: each lane counts its 40-candidate quarter, combine in-group
    int rk = 0;
    #pragma unroll 8
    for (int i = 0; i < TPK / 4; ++i) {
        int j = qt * (TPK / 4) + i;
        double vj = vS[j];
        int kj = kiS[j];
        rk += (vj > v || (vj == v && kj < tok)) ? 1 : 0;
    }
    rk += __shfl_xor(rk, 1); rk += __shfl_xor(rk, 2);
    if (qt == 0) rankS[g] = rk;
    __syncthreads();

    if (tid < TPK) {
        int r = rankS[tid];
        if (r < WSZW) outIdx[r] = kiS[tid];
    }
}

// ---------------- Kernel C: bf16 MFMA attention, swapped-QK^T, V transposed ----
// 512 thr = 8 waves. Three-phase fully-vectorized staging:
//  P1: V -> row-major swizzled buffer (KsS space), b128 writes.
//  P2: Vt column segments -> regs (scalar reads, 2 lanes/dword broadcast-class);
//      K gathers -> regs.
//  P3: Vt rows as b128 (64 distinct d/wave = 8-phase minimum); K b128 swizzled.
// Compute identical to round-12 (swapped QK^T, P in regs, Vt b128 B-frags).
__global__ __launch_bounds__(512, 2) void attn_kernel(
    const float* __restrict__ q, const float* __restrict__ k, const float* __restrict__ v,
    const float* __restrict__ mem_key, const float* __restrict__ mem_value,
    const int* __restrict__ idxQ, const int* __restrict__ idxK,
    float* __restrict__ so)
{
    // XCD-bijective swizzle (2048 % 8 == 0): 256 consecutive blks per XCD
    int bid = blockIdx.x;
    int blk = (bid & 7) * 256 + (bid >> 3);
    int c = blk % NCC;
    int bh = blk / NCC;
    int h = bh % HH;

    __shared__ __align__(16) unsigned short KsS[160 * 64];   // [kv][d] swizzled (temp V row-major in P1/P2)
    __shared__ __align__(16) unsigned short VtS[64 * 168];   // [d][kv], pad 168

    int tid = threadIdx.x;
    int w = tid >> 6, l = tid & 63;
    int lr = l & 15, lg = l >> 4;

    const float* memK = mem_key   + ((size_t)h * NCC + c) * (MEMN * DD);
    const float* memV = mem_value + ((size_t)h * NCC + c) * (MEMN * DD);

    // ---- Q frags early (independent of LDS phases) ----
    bf16x8 qf[2];
    {
        int tq = idxQ[(size_t)blk * WSZW + w * 16 + lr];
        const float* qp = q + ((size_t)bh * TT + tq) * DD;
        #pragma unroll
        for (int ks = 0; ks < 2; ++ks) {
            float4 a = *(const float4*)(qp + ks * 32 + lg * 8);
            float4 b = *(const float4*)(qp + ks * 32 + lg * 8 + 4);
            qf[ks] = pack8(a, b);
        }
    }

    // ---- P1: V -> row-major swizzled (in KsS space) ----
    for (int idx = tid; idx < 1280; idx += 512) {
        int row = idx >> 3, ch = idx & 7;
        uint4 vw = {0,0,0,0};
        if (row < KVW) {
            const float* vsrc = (row == 0) ? memV
                : v + ((size_t)bh * TT + idxK[(size_t)blk * WSZW + row - 1]) * DD;
            float4 a = *(const float4*)(vsrc + ch * 8);
            float4 b = *(const float4*)(vsrc + ch * 8 + 4);
            vw.x = pk2(a.x, a.y); vw.y = pk2(a.z, a.w);
            vw.z = pk2(b.x, b.y); vw.w = pk2(b.z, b.w);
        }
        *reinterpret_cast<uint4*>(&KsS[row * 64 + ((ch ^ (row & 7)) * 8)]) = vw;
    }
    __syncthreads();

    // ---- P2: Vt column segments -> regs; K gathers -> regs ----
    unsigned short vreg[3][8];
    #pragma unroll
    for (int s = 0; s < 3; ++s) {
        int idx = tid + s * 512;
        if (idx < 1280) {
            int d = idx & 63, rowblk = idx >> 6;
            #pragma unroll
            for (int i = 0; i < 8; ++i) {
                int row = rowblk * 8 + i;
                vreg[s][i] = KsS[row * 64 + (((d >> 3) ^ (row & 7)) * 8) + (d & 7)];
            }
        }
    }
    uint4 kreg[3];
    #pragma unroll
    for (int s = 0; s < 3; ++s) {
        int idx = tid + s * 512;
        kreg[s] = (uint4){0,0,0,0};
        if (idx < 1280) {
            int row = idx >> 3, ch = idx & 7;
            if (row < KVW) {
                const float* ksrc = (row == 0) ? memK
                    : k + ((size_t)bh * TT + idxK[(size_t)blk * WSZW + row - 1]) * DD;
                float4 a = *(const float4*)(ksrc + ch * 8);
                float4 b = *(const float4*)(ksrc + ch * 8 + 4);
                kreg[s].x = pk2(a.x, a.y); kreg[s].y = pk2(a.z, a.w);
                kreg[s].z = pk2(b.x, b.y); kreg[s].w = pk2(b.z, b.w);
            }
        }
    }
    __syncthreads();

    // ---- P3: write Vt (b128 rows) + K (b128 swizzled) ----
    #pragma unroll
    for (int s = 0; s < 3; ++s) {
        int idx = tid + s * 512;
        if (idx < 1280) {
            int d = idx & 63, rowblk = idx >> 6;
            uint4 ow;
            ow.x = (unsigned)vreg[s][0] | ((unsigned)vreg[s][1] << 16);
            ow.y = (unsigned)vreg[s][2] | ((unsigned)vreg[s][3] << 16);
            ow.z = (unsigned)vreg[s][4] | ((unsigned)vreg[s][5] << 16);
            ow.w = (unsigned)vreg[s][6] | ((unsigned)vreg[s][7] << 16);
            *reinterpret_cast<uint4*>(&VtS[d * 168 + rowblk * 8]) = ow;
        }
    }
    #pragma unroll
    for (int s = 0; s < 3; ++s) {
        int idx = tid + s * 512;
        if (idx < 1280) {
            int row = idx >> 3, ch = idx & 7;
            *reinterpret_cast<uint4*>(&KsS[row * 64 + ((ch ^ (row & 7)) * 8)]) = kreg[s];
        }
    }
    __syncthreads();

    // ---- compute (identical to round-12) ----
    f32x4 acc[4];
    #pragma unroll
    for (int dt = 0; dt < 4; ++dt) acc[dt] = (f32x4){0.f, 0.f, 0.f, 0.f};
    float s_sum = 0.f;

    int src0 = lr + ((lg & 1) * 2) * 16;
    int src1 = src0 + 16;
    bool hi = (lg >> 1) != 0;

    for (int kb = 0; kb < 5; ++kb) {
        bf16x8 kf[2][2];
        #pragma unroll
        for (int kvt = 0; kvt < 2; ++kvt)
            #pragma unroll
            for (int ks = 0; ks < 2; ++ks) {
                int row = kb * 32 + kvt * 16 + lr;
                int chunk = ks * 4 + lg;
                int phys = chunk ^ (row & 7);
                kf[kvt][ks] = *reinterpret_cast<const bf16x8*>(&KsS[row * 64 + phys * 8]);
            }
        unsigned pk[2][2];
        #pragma unroll
        for (int kvt = 0; kvt < 2; ++kvt) {
            f32x4 sf = __builtin_amdgcn_mfma_f32_16x16x32_bf16(
                kf[kvt][0], qf[0], (f32x4){0.f,0.f,0.f,0.f}, 0, 0, 0);
            sf = __builtin_amdgcn_mfma_f32_16x16x32_bf16(kf[kvt][1], qf[1], sf, 0, 0, 0);
            float e[4];
            #pragma unroll
            for (int r = 0; r < 4; ++r) {
                int kv = kb * 32 + kvt * 16 + lg * 4 + r;
                e[r] = (kv < KVW) ? __expf(sf[r] * SCALE) : 0.f;
                s_sum += e[r];
            }
            pk[kvt][0] = pk2(e[0], e[1]);
            pk[kvt][1] = pk2(e[2], e[3]);
        }
        unsigned a00 = __shfl(pk[0][0], src0), a01 = __shfl(pk[0][1], src0);
        unsigned a10 = __shfl(pk[1][0], src0), a11 = __shfl(pk[1][1], src0);
        unsigned b00 = __shfl(pk[0][0], src1), b01 = __shfl(pk[0][1], src1);
        unsigned b10 = __shfl(pk[1][0], src1), b11 = __shfl(pk[1][1], src1);
        union { unsigned u[4]; bf16x8 v; } pu;
        pu.u[0] = hi ? a10 : a00;
        pu.u[1] = hi ? a11 : a01;
        pu.u[2] = hi ? b10 : b00;
        pu.u[3] = hi ? b11 : b01;
        #pragma unroll
        for (int dt = 0; dt < 4; ++dt) {
            bf16x8 vf = *reinterpret_cast<const bf16x8*>(
                &VtS[(dt * 16 + lr) * 168 + kb * 32 + lg * 8]);
            acc[dt] = __builtin_amdgcn_mfma_f32_16x16x32_bf16(pu.v, vf, acc[dt], 0, 0, 0);
        }
    }

    s_sum += __shfl_xor(s_sum, 16);
    s_sum += __shfl_xor(s_sum, 32);
    float sinv[4];
    #pragma unroll
    for (int r = 0; r < 4; ++r)
        sinv[r] = 1.f / __shfl(s_sum, lg * 4 + r);

    #pragma unroll
    for (int r = 0; r < 4; ++r) {
        int row = w * 16 + lg * 4 + r;
        float* op = so + (((size_t)blk * WSZW + row) * DD);
        #pragma unroll
        for (int dt = 0; dt < 4; ++dt)
            op[dt * 16 + lr] = acc[dt][r] * sinv[r];
    }
}

// ---------------- Kernel E: histogram of token selections ----------------
__global__ __launch_bounds__(256) void count_kernel(
    const int* __restrict__ idxQ, int* __restrict__ counts)
{
    int i = blockIdx.x * 256 + threadIdx.x;
    int bh = i >> 13;
    atomicAdd(&counts[bh * TT + idxQ[i]], 1);
}

// ---------------- Kernel F: per-bh exclusive scan (4096 ints) ----------------
__global__ __launch_bounds__(256) void scan_kernel(
    const int* __restrict__ counts, int* __restrict__ offs)
{
    int bh = blockIdx.x;
    int t = threadIdx.x;
    const int* cb = counts + (size_t)bh * TT;
    int* ob = offs + (size_t)bh * TT;

    int loc[16]; int sum = 0;
    #pragma unroll
    for (int i = 0; i < 16; ++i) { loc[i] = sum; sum += cb[t * 16 + i]; }

    __shared__ int wsum[256];
    wsum[t] = sum;
    __syncthreads();
    for (int off = 1; off < 256; off <<= 1) {
        int vv = (t >= off) ? wsum[t - off] : 0;
        __syncthreads();
        wsum[t] += vv;
        __syncthreads();
    }
    int ex = (t == 0) ? 0 : wsum[t - 1];
    #pragma unroll
    for (int i = 0; i < 16; ++i) ob[t * 16 + i] = ex + loc[i];
}

// ---------------- Kernel G: fill CSR slot lists ----------------
__global__ __launch_bounds__(256) void fill_kernel(
    const int* __restrict__ idxQ, const int* __restrict__ offs,
    int* __restrict__ cur, int* __restrict__ csr)
{
    int i = blockIdx.x * 256 + threadIdx.x;
    int bh = i >> 13;
    int within = i & 8191;
    int tok = idxQ[i];
    int p = offs[bh * TT + tok] + atomicAdd(&cur[bh * TT + tok], 1);
    csr[((size_t)bh << 13) + p] = within;
}

// ---------------- Kernel H: gather-reduce + finalize ----------------
__global__ __launch_bounds__(256) void reduce_kernel(
    const float* __restrict__ so, const int* __restrict__ counts,
    const int* __restrict__ offs, const int* __restrict__ csr,
    float* __restrict__ out)
{
    int gt = blockIdx.x * 4 + (threadIdx.x >> 6);
    int lane = threadIdx.x & 63;
    int bh = gt >> 12;
    int n = counts[gt];
    int st = offs[gt];
    const int* cs = csr + ((size_t)bh << 13);
    float acc = 0.f;
    for (int j = 0; j < n; ++j) {
        int slot = cs[st + j];
        acc += so[(((size_t)bh << 13) + slot) * DD + lane];
    }
    out[(size_t)gt * DD + lane] = acc / ((float)n + EPSF);
}

extern "C" void kernel_launch(void* const* d_in, const int* in_sizes, int n_in,
                              void* d_out, int out_size, void* d_ws, size_t ws_size,
                              hipStream_t stream) {
    const float* q        = (const float*)d_in[0];
    const float* k        = (const float*)d_in[1];
    const float* v        = (const float*)d_in[2];
    const float* means    = (const float*)d_in[3];
    const float* mem_key  = (const float*)d_in[4];
    const float* mem_val  = (const float*)d_in[5];
    float* out = (float*)d_out;

    const size_t nRows = (size_t)BB * HH * NCC;             // 2048
    const size_t nTok  = (size_t)BB * HH * TT;              // 131072
    float* wsf    = (float*)d_ws;
    float* distsQ = wsf;                                    // 8388608 f
    float* distsK = distsQ + (size_t)BB * HH * NCC * TT;    // 8388608 f
    float* so     = wsf;                                    // aliases dists; written after rescore
    int*   idxQ   = (int*)(distsK + (size_t)BB * HH * NCC * TT);  // 262144 i
    int*   idxK   = idxQ + nRows * WSZW;                    // 262144 i
    int*   counts = idxK + nRows * WSZW;                    // 131072 i
    int*   cur    = counts + nTok;                          // 131072 i
    float* auxp   = (float*)(cur + nTok);                   // 16384 f (per-wave partials)
    int*   offs   = (int*)(auxp + 16384);                   // 131072 i
    int*   csr    = offs + nTok;                            // 262144 i
    int*   candQ  = csr + nTok * 2;                         // 2048*160 i
    int*   candK  = candQ + nRows * TPK;                    // 2048*160 i

    hipMemsetAsync(counts, 0, 2 * nTok * sizeof(int), stream);

    dists_kernel<<<dim3(BB * HH * (2 * TT / 64)), dim3(256), 0, stream>>>(
        q, k, means, distsQ, distsK, auxp);
    aux_reduce_kernel<<<dim3(1), dim3(256), 0, stream>>>(auxp, out);
    topk_kernel<<<dim3((unsigned)nRows), dim3(256), 0, stream>>>(distsQ, candQ);
    topk_kernel<<<dim3((unsigned)nRows), dim3(256), 0, stream>>>(distsK, candK);
    rescore_kernel<<<dim3((unsigned)(2 * nRows)), dim3(640), 0, stream>>>(
        q, k, means, candQ, candK, idxQ, idxK);
    count_kernel<<<dim3(1024), dim3(256), 0, stream>>>(idxQ, counts);
    scan_kernel<<<dim3(BB * HH), dim3(256), 0, stream>>>(counts, offs);
    fill_kernel<<<dim3(1024), dim3(256), 0, stream>>>(idxQ, offs, cur, csr);
    attn_kernel<<<dim3((unsigned)nRows), dim3(512), 0, stream>>>(
        q, k, v, mem_key, mem_val, idxQ, idxK, so);
    reduce_kernel<<<dim3((unsigned)(nTok / 4)), dim3(256), 0, stream>>>(
        so, counts, offs, csr, out);
}

// Round 14
// 274.988 us; speedup vs baseline: 1.7997x; 1.0769x over previous
//
#include <hip/hip_runtime.h>
#include <math.h>

#define BB 4
#define HH 8
#define TT 4096
#define DD 64
#define NCC 64
#define WSZW 128
#define TPK 160          // widened f32 top-k; f64 rescore picks exact top-128
#define MEMN 1
#define KVW (MEMN + WSZW)   // 129
constexpr float EPSF = 1e-5f;
constexpr float SCALE = 0.125f;  // 64^-0.5

typedef __attribute__((ext_vector_type(8))) short bf16x8;
typedef __attribute__((ext_vector_type(4))) float f32x4;

// HW packed f32->bf16 (RNE), 1 instruction vs ~7 for the manual bit-twiddle
static __device__ __forceinline__ unsigned int pk2(float a, float b) {
    unsigned int r;
    asm("v_cvt_pk_bf16_f32 %0, %1, %2" : "=v"(r) : "v"(a), "v"(b));
    return r;
}
static __device__ __forceinline__ bf16x8 pack8(float4 a, float4 b) {
    union { unsigned int u[4]; bf16x8 v; } r;
    r.u[0] = pk2(a.x, a.y); r.u[1] = pk2(a.z, a.w);
    r.u[2] = pk2(b.x, b.y); r.u[3] = pk2(b.z, b.w);
    return r.v;
}

// ---------------- Kernel A: dists as tiled f32 GEMM + argmax + aux partials ------
__global__ __launch_bounds__(256, 4) void dists_kernel(
    const float* __restrict__ q, const float* __restrict__ k,
    const float* __restrict__ means,
    float* __restrict__ distsQ, float* __restrict__ distsK,
    float* __restrict__ aux_part)
{
    __shared__ float xS[64][68];   // [d][tok]; reused as dS[tok][c] after GEMM
    __shared__ float mS[64][68];   // [d][cluster]
    __shared__ float mqS[64];      // per-cluster ||m||^2

    const int chunks = (2 * TT) / 64;          // 128
    int bid = blockIdx.x;                      // 4096
    int bh = bid / chunks;
    int chunk = bid % chunks;
    int h = bh % HH;
    bool isQ = chunk < (TT / 64);
    int tbase = (isQ ? chunk : chunk - 64) * 64;
    const float* src = (isQ ? q : k) + ((size_t)bh * TT + tbase) * DD;
    float* dst = isQ ? distsQ : distsK;

    int tid = threadIdx.x;
    int tok = tid >> 2, part = tid & 3;        // tok doubles as cluster idx below

    // ---- stage means (transposed) + per-cluster sumsq ----
    {
        const float* mp = means + ((size_t)h * NCC + tok) * DD + part * 16;
        float4 va[4];
        #pragma unroll
        for (int i = 0; i < 4; ++i) va[i] = *(const float4*)(mp + i * 4);
        float msq = 0.f;
        #pragma unroll
        for (int i = 0; i < 4; ++i) {
            msq += va[i].x*va[i].x + va[i].y*va[i].y + va[i].z*va[i].z + va[i].w*va[i].w;
            int d = part * 16 + i * 4;
            mS[d][tok] = va[i].x; mS[d+1][tok] = va[i].y;
            mS[d+2][tok] = va[i].z; mS[d+3][tok] = va[i].w;
        }
        msq += __shfl_xor(msq, 1);
        msq += __shfl_xor(msq, 2);
        if (part == 0) mqS[tok] = msq;
    }
    // ---- stage x normalized (transposed) ----
    float ssn;
    {
        const float* xp = src + (size_t)tok * DD + part * 16;
        float4 va[4];
        #pragma unroll
        for (int i = 0; i < 4; ++i) va[i] = *(const float4*)(xp + i * 4);
        float ss = 0.f;
        #pragma unroll
        for (int i = 0; i < 4; ++i)
            ss += va[i].x*va[i].x + va[i].y*va[i].y + va[i].z*va[i].z + va[i].w*va[i].w;
        ss += __shfl_xor(ss, 1);
        ss += __shfl_xor(ss, 2);
        float inv = 1.f / fmaxf(sqrtf(ss), 1e-12f);
        ssn = ss * inv * inv;
        #pragma unroll
        for (int i = 0; i < 4; ++i) {
            int d = part * 16 + i * 4;
            xS[d][tok] = va[i].x*inv; xS[d+1][tok] = va[i].y*inv;
            xS[d+2][tok] = va[i].z*inv; xS[d+3][tok] = va[i].w*inv;
        }
    }
    __syncthreads();

    // ---- GEMM: thread = 4 tokens x 4 clusters ----
    int l = tid & 63, w = tid >> 6;
    int ti = l & 15;                 // token tile 4*ti..
    int ci = w * 4 + (l >> 4);       // cluster tile 4*ci..
    float acc[4][4];
    #pragma unroll
    for (int i = 0; i < 4; ++i)
        #pragma unroll
        for (int j = 0; j < 4; ++j) acc[i][j] = 0.f;

    #pragma unroll 16
    for (int kk = 0; kk < 64; ++kk) {
        float4 xv = *(const float4*)(&xS[kk][ti * 4]);
        float4 mv = *(const float4*)(&mS[kk][ci * 4]);
        float xa[4] = {xv.x, xv.y, xv.z, xv.w};
        float ma[4] = {mv.x, mv.y, mv.z, mv.w};
        #pragma unroll
        for (int i = 0; i < 4; ++i)
            #pragma unroll
            for (int j = 0; j < 4; ++j) acc[i][j] += xa[i] * ma[j];
    }

    // ---- store dists to global (coalesced float4 over tokens) ----
    {
        size_t rowb = (size_t)(bh * NCC) * TT;
        #pragma unroll
        for (int j = 0; j < 4; ++j) {
            int c = ci * 4 + j;
            float4 o;
            o.x = acc[0][j]; o.y = acc[1][j]; o.z = acc[2][j]; o.w = acc[3][j];
            *(float4*)&dst[rowb + (size_t)c * TT + tbase + ti * 4] = o;
        }
    }

    // ---- argmax + aux via LDS round-trip (reuse xS as dS[tok][c]) ----
    __syncthreads();
    #pragma unroll
    for (int i = 0; i < 4; ++i)
        #pragma unroll
        for (int j = 0; j < 4; ++j)
            xS[ti * 4 + i][ci * 4 + j] = acc[i][j];
    __syncthreads();

    float bv = -1e30f; int bc = 0;
    #pragma unroll
    for (int j = 0; j < 16; ++j) {
        int c = part * 16 + j;
        float vv = xS[tok][c];
        if (vv > bv) { bv = vv; bc = c; }
    }
    #pragma unroll
    for (int off = 1; off <= 2; off <<= 1) {
        float ov = __shfl_xor(bv, off);
        int   oc = __shfl_xor(bc, off);
        if (ov > bv || (ov == bv && oc < bc)) { bv = ov; bc = oc; }
    }
    float auxv = (part == 0) ? (ssn + mqS[bc] - 2.f * bv) : 0.f;
    #pragma unroll
    for (int off = 32; off; off >>= 1) auxv += __shfl_xor(auxv, off);
    if (l == 0) aux_part[bid * 4 + w] = auxv;
}

// ---------------- Kernel A2: reduce 16384 aux partials -> out[N] ----------------
__global__ __launch_bounds__(256) void aux_reduce_kernel(
    const float* __restrict__ aux_part, float* __restrict__ out)
{
    int t = threadIdx.x;
    float s = 0.f;
    for (int i = t; i < 16384; i += 256) s += aux_part[i];
    #pragma unroll
    for (int off = 32; off; off >>= 1) s += __shfl_xor(s, off);
    __shared__ float wsum[4];
    if ((t & 63) == 0) wsum[t >> 6] = s;
    __syncthreads();
    if (t == 0)
        out[(size_t)BB * HH * TT * DD] =
            (wsum[0] + wsum[1] + wsum[2] + wsum[3]) *
            (1.0f / (float)(BB * HH * 2 * TT * DD));
}

// ---------------- Kernel B: top-TPK per row (grid 2*nRows: Q rows then K rows) --
__global__ __launch_bounds__(256) void topk_kernel(
    const float* __restrict__ dists, int* __restrict__ idxOut)
{
    int row = blockIdx.x;
    const float* dv = dists + (size_t)row * TT;
    int t = threadIdx.x;

    unsigned u[16];
    #pragma unroll
    for (int j = 0; j < 16; ++j) {
        unsigned b = __float_as_uint(dv[j * 256 + t]);
        u[j] = (b & 0x80000000u) ? ~b : (b | 0x80000000u);
    }

    __shared__ int hist[256];
    __shared__ int sfx[256];
    __shared__ int binSel, tgtS;
    __shared__ int nGtS, posS, eqFilled;
    __shared__ int waveCnt[4];

    int target = TPK;
    unsigned prefix = 0;

    for (int shift = 24; shift >= 0; shift -= 8) {
        hist[t] = 0;
        __syncthreads();
        #pragma unroll
        for (int j = 0; j < 16; ++j) {
            bool act = (shift == 24) || ((u[j] >> (shift + 8)) == (prefix >> (shift + 8)));
            if (act) atomicAdd(&hist[(u[j] >> shift) & 255], 1);
        }
        __syncthreads();
        sfx[t] = hist[t];
        __syncthreads();
        for (int off = 1; off < 256; off <<= 1) {
            int add = (t + off < 256) ? sfx[t + off] : 0;
            int cur = sfx[t];
            __syncthreads();
            sfx[t] = cur + add;
            __syncthreads();
        }
        int nxt = (t == 255) ? 0 : sfx[t + 1];
        if (sfx[t] >= target && nxt < target) { binSel = t; tgtS = target - nxt; }
        __syncthreads();
        prefix |= ((unsigned)binSel) << shift;
        target = tgtS;
        __syncthreads();
    }

    unsigned pivot = prefix;
    if (t == 0) { nGtS = 0; posS = 0; eqFilled = 0; }
    __syncthreads();
    int myg = 0;
    #pragma unroll
    for (int j = 0; j < 16; ++j) myg += (u[j] > pivot) ? 1 : 0;
    if (myg) atomicAdd(&nGtS, myg);
    __syncthreads();
    int n_gt = nGtS;
    int n_need = TPK - n_gt;
    int* out = idxOut + (size_t)row * TPK;

    #pragma unroll
    for (int j = 0; j < 16; ++j)
        if (u[j] > pivot) { int p = atomicAdd(&posS, 1); out[p] = j * 256 + t; }

    int lane = t & 63, wv = t >> 6;
    for (int j = 0; j < 16; ++j) {
        if (eqFilled >= n_need) break;
        bool fl = (u[j] == pivot);
        unsigned long long bal = __ballot(fl);
        if (lane == 0) waveCnt[wv] = __popcll(bal);
        __syncthreads();
        int offw = 0;
        for (int w = 0; w < wv; ++w) offw += waveCnt[w];
        int mypos = eqFilled + offw + __popcll(bal & ((lane ? ((1ull << lane) - 1ull) : 0ull)));
        if (fl && mypos < n_need) out[n_gt + mypos] = j * 256 + t;
        __syncthreads();
        if (t == 0) eqFilled += waveCnt[0] + waveCnt[1] + waveCnt[2] + waveCnt[3];
        __syncthreads();
    }
}

// ---------------- Kernel B2: f64 rescore, 4 lanes per candidate (+count fusion) --
__global__ __launch_bounds__(640) void rescore_kernel(
    const float* __restrict__ q, const float* __restrict__ k,
    const float* __restrict__ means,
    const int* __restrict__ candQ, const int* __restrict__ candK,
    int* __restrict__ idxQ, int* __restrict__ idxK,
    int* __restrict__ counts)
{
    int rid = blockIdx.x;
    int side = rid >> 11;            // 0=Q, 1=K
    int row = rid & 2047;            // bh*NC + c
    int c = row & (NCC - 1);
    int bh = row >> 6;
    int h = bh % HH;

    const int* cand = (side ? candK : candQ) + (size_t)row * TPK;
    int* outIdx     = (side ? idxK : idxQ) + (size_t)row * WSZW;
    const float* xbase = (side ? k : q) + (size_t)bh * TT * DD;

    __shared__ double mD[DD];
    __shared__ double vS[TPK];
    __shared__ int    kiS[TPK];
    __shared__ int    rankS[TPK];

    int tid = threadIdx.x;
    if (tid < DD) mD[tid] = (double)means[((size_t)h * NCC + c) * DD + tid];
    __syncthreads();

    int g = tid >> 2;                // candidate 0..159
    int qt = tid & 3;                // quarter-row 0..3
    int tok = cand[g];
    const float* xp = xbase + (size_t)tok * DD + qt * 16;
    double dot = 0.0, ss = 0.0;
    #pragma unroll
    for (int i = 0; i < 4; ++i) {
        float4 va = *(const float4*)(xp + i * 4);
        int d = qt * 16 + i * 4;
        dot += (double)va.x * mD[d]   + (double)va.y * mD[d+1]
             + (double)va.z * mD[d+2] + (double)va.w * mD[d+3];
        ss  += (double)va.x * va.x + (double)va.y * va.y
             + (double)va.z * va.z + (double)va.w * va.w;
    }
    dot += __shfl_xor(dot, 1); dot += __shfl_xor(dot, 2);
    ss  += __shfl_xor(ss, 1);  ss  += __shfl_xor(ss, 2);
    double v = dot * (1.0 / fmax(sqrt(ss), 1e-12));
    if (qt == 0) { vS[g] = v; kiS[g] = tok; }
    __syncthreads();

    // rank: each lane counts its 40-candidate quarter, combine in-group
    int rk = 0;
    #pragma unroll 8
    for (int i = 0; i < TPK / 4; ++i) {
        int j = qt * (TPK / 4) + i;
        double vj = vS[j];
        int kj = kiS[j];
        rk += (vj > v || (vj == v && kj < tok)) ? 1 : 0;
    }
    rk += __shfl_xor(rk, 1); rk += __shfl_xor(rk, 2);
    if (qt == 0) rankS[g] = rk;
    __syncthreads();

    if (tid < TPK) {
        int r = rankS[tid];
        if (r < WSZW) {
            outIdx[r] = kiS[tid];
            if (side == 0) atomicAdd(&counts[bh * TT + kiS[tid]], 1);
        }
    }
}

// ---------------- Kernel C: bf16 MFMA attention, swapped-QK^T, V transposed ----
__global__ __launch_bounds__(512, 2) void attn_kernel(
    const float* __restrict__ q, const float* __restrict__ k, const float* __restrict__ v,
    const float* __restrict__ mem_key, const float* __restrict__ mem_value,
    const int* __restrict__ idxQ, const int* __restrict__ idxK,
    float* __restrict__ so)
{
    // XCD-bijective swizzle (2048 % 8 == 0): 256 consecutive blks per XCD
    int bid = blockIdx.x;
    int blk = (bid & 7) * 256 + (bid >> 3);
    int c = blk % NCC;
    int bh = blk / NCC;
    int h = bh % HH;

    __shared__ __align__(16) unsigned short KsS[160 * 64];   // [kv][d] swizzled (temp V row-major in P1/P2)
    __shared__ __align__(16) unsigned short VtS[64 * 168];   // [d][kv], pad 168

    int tid = threadIdx.x;
    int w = tid >> 6, l = tid & 63;
    int lr = l & 15, lg = l >> 4;

    const float* memK = mem_key   + ((size_t)h * NCC + c) * (MEMN * DD);
    const float* memV = mem_value + ((size_t)h * NCC + c) * (MEMN * DD);

    // ---- Q frags early (independent of LDS phases) ----
    bf16x8 qf[2];
    {
        int tq = idxQ[(size_t)blk * WSZW + w * 16 + lr];
        const float* qp = q + ((size_t)bh * TT + tq) * DD;
        #pragma unroll
        for (int ks = 0; ks < 2; ++ks) {
            float4 a = *(const float4*)(qp + ks * 32 + lg * 8);
            float4 b = *(const float4*)(qp + ks * 32 + lg * 8 + 4);
            qf[ks] = pack8(a, b);
        }
    }

    // ---- P1: V -> row-major swizzled (in KsS space) ----
    for (int idx = tid; idx < 1280; idx += 512) {
        int row = idx >> 3, ch = idx & 7;
        uint4 vw = {0,0,0,0};
        if (row < KVW) {
            const float* vsrc = (row == 0) ? memV
                : v + ((size_t)bh * TT + idxK[(size_t)blk * WSZW + row - 1]) * DD;
            float4 a = *(const float4*)(vsrc + ch * 8);
            float4 b = *(const float4*)(vsrc + ch * 8 + 4);
            vw.x = pk2(a.x, a.y); vw.y = pk2(a.z, a.w);
            vw.z = pk2(b.x, b.y); vw.w = pk2(b.z, b.w);
        }
        *reinterpret_cast<uint4*>(&KsS[row * 64 + ((ch ^ (row & 7)) * 8)]) = vw;
    }
    __syncthreads();

    // ---- P2: Vt column segments -> regs; K gathers -> regs ----
    unsigned short vreg[3][8];
    #pragma unroll
    for (int s = 0; s < 3; ++s) {
        int idx = tid + s * 512;
        if (idx < 1280) {
            int d = idx & 63, rowblk = idx >> 6;
            #pragma unroll
            for (int i = 0; i < 8; ++i) {
                int row = rowblk * 8 + i;
                vreg[s][i] = KsS[row * 64 + (((d >> 3) ^ (row & 7)) * 8) + (d & 7)];
            }
        }
    }
    uint4 kreg[3];
    #pragma unroll
    for (int s = 0; s < 3; ++s) {
        int idx = tid + s * 512;
        kreg[s] = (uint4){0,0,0,0};
        if (idx < 1280) {
            int row = idx >> 3, ch = idx & 7;
            if (row < KVW) {
                const float* ksrc = (row == 0) ? memK
                    : k + ((size_t)bh * TT + idxK[(size_t)blk * WSZW + row - 1]) * DD;
                float4 a = *(const float4*)(ksrc + ch * 8);
                float4 b = *(const float4*)(ksrc + ch * 8 + 4);
                kreg[s].x = pk2(a.x, a.y); kreg[s].y = pk2(a.z, a.w);
                kreg[s].z = pk2(b.x, b.y); kreg[s].w = pk2(b.z, b.w);
            }
        }
    }
    __syncthreads();

    // ---- P3: write Vt (b128 rows) + K (b128 swizzled) ----
    #pragma unroll
    for (int s = 0; s < 3; ++s) {
        int idx = tid + s * 512;
        if (idx < 1280) {
            int d = idx & 63, rowblk = idx >> 6;
            uint4 ow;
            ow.x = (unsigned)vreg[s][0] | ((unsigned)vreg[s][1] << 16);
            ow.y = (unsigned)vreg[s][2] | ((unsigned)vreg[s][3] << 16);
            ow.z = (unsigned)vreg[s][4] | ((unsigned)vreg[s][5] << 16);
            ow.w = (unsigned)vreg[s][6] | ((unsigned)vreg[s][7] << 16);
            *reinterpret_cast<uint4*>(&VtS[d * 168 + rowblk * 8]) = ow;
        }
    }
    #pragma unroll
    for (int s = 0; s < 3; ++s) {
        int idx = tid + s * 512;
        if (idx < 1280) {
            int row = idx >> 3, ch = idx & 7;
            *reinterpret_cast<uint4*>(&KsS[row * 64 + ((ch ^ (row & 7)) * 8)]) = kreg[s];
        }
    }
    __syncthreads();

    // ---- compute (swapped QK^T, P in regs, Vt b128 B-frags) ----
    f32x4 acc[4];
    #pragma unroll
    for (int dt = 0; dt < 4; ++dt) acc[dt] = (f32x4){0.f, 0.f, 0.f, 0.f};
    float s_sum = 0.f;

    int src0 = lr + ((lg & 1) * 2) * 16;
    int src1 = src0 + 16;
    bool hi = (lg >> 1) != 0;

    for (int kb = 0; kb < 5; ++kb) {
        bf16x8 kf[2][2];
        #pragma unroll
        for (int kvt = 0; kvt < 2; ++kvt)
            #pragma unroll
            for (int ks = 0; ks < 2; ++ks) {
                int row = kb * 32 + kvt * 16 + lr;
                int chunk = ks * 4 + lg;
                int phys = chunk ^ (row & 7);
                kf[kvt][ks] = *reinterpret_cast<const bf16x8*>(&KsS[row * 64 + phys * 8]);
            }
        __builtin_amdgcn_s_setprio(1);
        unsigned pk[2][2];
        #pragma unroll
        for (int kvt = 0; kvt < 2; ++kvt) {
            f32x4 sf = __builtin_amdgcn_mfma_f32_16x16x32_bf16(
                kf[kvt][0], qf[0], (f32x4){0.f,0.f,0.f,0.f}, 0, 0, 0);
            sf = __builtin_amdgcn_mfma_f32_16x16x32_bf16(kf[kvt][1], qf[1], sf, 0, 0, 0);
            float e[4];
            #pragma unroll
            for (int r = 0; r < 4; ++r) {
                int kv = kb * 32 + kvt * 16 + lg * 4 + r;
                e[r] = (kv < KVW) ? __expf(sf[r] * SCALE) : 0.f;
                s_sum += e[r];
            }
            pk[kvt][0] = pk2(e[0], e[1]);
            pk[kvt][1] = pk2(e[2], e[3]);
        }
        unsigned a00 = __shfl(pk[0][0], src0), a01 = __shfl(pk[0][1], src0);
        unsigned a10 = __shfl(pk[1][0], src0), a11 = __shfl(pk[1][1], src0);
        unsigned b00 = __shfl(pk[0][0], src1), b01 = __shfl(pk[0][1], src1);
        unsigned b10 = __shfl(pk[1][0], src1), b11 = __shfl(pk[1][1], src1);
        union { unsigned u[4]; bf16x8 v; } pu;
        pu.u[0] = hi ? a10 : a00;
        pu.u[1] = hi ? a11 : a01;
        pu.u[2] = hi ? b10 : b00;
        pu.u[3] = hi ? b11 : b01;
        #pragma unroll
        for (int dt = 0; dt < 4; ++dt) {
            bf16x8 vf = *reinterpret_cast<const bf16x8*>(
                &VtS[(dt * 16 + lr) * 168 + kb * 32 + lg * 8]);
            acc[dt] = __builtin_amdgcn_mfma_f32_16x16x32_bf16(pu.v, vf, acc[dt], 0, 0, 0);
        }
        __builtin_amdgcn_s_setprio(0);
    }

    s_sum += __shfl_xor(s_sum, 16);
    s_sum += __shfl_xor(s_sum, 32);
    float sinv[4];
    #pragma unroll
    for (int r = 0; r < 4; ++r)
        sinv[r] = 1.f / __shfl(s_sum, lg * 4 + r);

    #pragma unroll
    for (int r = 0; r < 4; ++r) {
        int row = w * 16 + lg * 4 + r;
        float* op = so + (((size_t)blk * WSZW + row) * DD);
        #pragma unroll
        for (int dt = 0; dt < 4; ++dt)
            op[dt * 16 + lr] = acc[dt][r] * sinv[r];
    }
}

// ---------------- Kernel F: per-bh exclusive scan (4096 ints) ----------------
__global__ __launch_bounds__(256) void scan_kernel(
    const int* __restrict__ counts, int* __restrict__ offs)
{
    int bh = blockIdx.x;
    int t = threadIdx.x;
    const int* cb = counts + (size_t)bh * TT;
    int* ob = offs + (size_t)bh * TT;

    int loc[16]; int sum = 0;
    #pragma unroll
    for (int i = 0; i < 16; ++i) { loc[i] = sum; sum += cb[t * 16 + i]; }

    __shared__ int wsum[256];
    wsum[t] = sum;
    __syncthreads();
    for (int off = 1; off < 256; off <<= 1) {
        int vv = (t >= off) ? wsum[t - off] : 0;
        __syncthreads();
        wsum[t] += vv;
        __syncthreads();
    }
    int ex = (t == 0) ? 0 : wsum[t - 1];
    #pragma unroll
    for (int i = 0; i < 16; ++i) ob[t * 16 + i] = ex + loc[i];
}

// ---------------- Kernel G: fill CSR slot lists ----------------
__global__ __launch_bounds__(256) void fill_kernel(
    const int* __restrict__ idxQ, const int* __restrict__ offs,
    int* __restrict__ cur, int* __restrict__ csr)
{
    int i = blockIdx.x * 256 + threadIdx.x;
    int bh = i >> 13;
    int within = i & 8191;
    int tok = idxQ[i];
    int p = offs[bh * TT + tok] + atomicAdd(&cur[bh * TT + tok], 1);
    csr[((size_t)bh << 13) + p] = within;
}

// ---------------- Kernel H: gather-reduce + finalize ----------------
__global__ __launch_bounds__(256) void reduce_kernel(
    const float* __restrict__ so, const int* __restrict__ counts,
    const int* __restrict__ offs, const int* __restrict__ csr,
    float* __restrict__ out)
{
    int gt = blockIdx.x * 4 + (threadIdx.x >> 6);
    int lane = threadIdx.x & 63;
    int bh = gt >> 12;
    int n = counts[gt];
    int st = offs[gt];
    const int* cs = csr + ((size_t)bh << 13);
    float acc = 0.f;
    for (int j = 0; j < n; ++j) {
        int slot = cs[st + j];
        acc += so[(((size_t)bh << 13) + slot) * DD + lane];
    }
    out[(size_t)gt * DD + lane] = acc / ((float)n + EPSF);
}

extern "C" void kernel_launch(void* const* d_in, const int* in_sizes, int n_in,
                              void* d_out, int out_size, void* d_ws, size_t ws_size,
                              hipStream_t stream) {
    const float* q        = (const float*)d_in[0];
    const float* k        = (const float*)d_in[1];
    const float* v        = (const float*)d_in[2];
    const float* means    = (const float*)d_in[3];
    const float* mem_key  = (const float*)d_in[4];
    const float* mem_val  = (const float*)d_in[5];
    float* out = (float*)d_out;

    const size_t nRows = (size_t)BB * HH * NCC;             // 2048
    const size_t nTok  = (size_t)BB * HH * TT;              // 131072
    float* wsf    = (float*)d_ws;
    float* distsQ = wsf;                                    // 8388608 f
    float* distsK = distsQ + (size_t)BB * HH * NCC * TT;    // 8388608 f (contiguous after distsQ)
    float* so     = wsf;                                    // aliases dists; written after rescore
    int*   idxQ   = (int*)(distsK + (size_t)BB * HH * NCC * TT);  // 262144 i
    int*   idxK   = idxQ + nRows * WSZW;                    // 262144 i
    int*   counts = idxK + nRows * WSZW;                    // 131072 i
    int*   cur    = counts + nTok;                          // 131072 i
    float* auxp   = (float*)(cur + nTok);                   // 16384 f (per-wave partials)
    int*   offs   = (int*)(auxp + 16384);                   // 131072 i
    int*   csr    = offs + nTok;                            // 262144 i
    int*   candQ  = csr + nTok * 2;                         // 2048*160 i
    int*   candK  = candQ + nRows * TPK;                    // 2048*160 i (contiguous after candQ)

    hipMemsetAsync(counts, 0, 2 * nTok * sizeof(int), stream);

    dists_kernel<<<dim3(BB * HH * (2 * TT / 64)), dim3(256), 0, stream>>>(
        q, k, means, distsQ, distsK, auxp);
    aux_reduce_kernel<<<dim3(1), dim3(256), 0, stream>>>(auxp, out);
    // single launch covers Q rows (0..2047 over distsQ/candQ) and K rows
    // (2048..4095 over distsK/candK) via buffer contiguity
    topk_kernel<<<dim3((unsigned)(2 * nRows)), dim3(256), 0, stream>>>(distsQ, candQ);
    rescore_kernel<<<dim3((unsigned)(2 * nRows)), dim3(640), 0, stream>>>(
        q, k, means, candQ, candK, idxQ, idxK, counts);
    scan_kernel<<<dim3(BB * HH), dim3(256), 0, stream>>>(counts, offs);
    fill_kernel<<<dim3(1024), dim3(256), 0, stream>>>(idxQ, offs, cur, csr);
    attn_kernel<<<dim3((unsigned)nRows), dim3(512), 0, stream>>>(
        q, k, v, mem_key, mem_val, idxQ, idxK, so);
    reduce_kernel<<<dim3((unsigned)(nTok / 4)), dim3(256), 0, stream>>>(
        so, counts, offs, csr, out);
}

// Round 15
// 257.689 us; speedup vs baseline: 1.9205x; 1.0671x over previous
//
#include <hip/hip_runtime.h>
#include <math.h>

#define BB 4
#define HH 8
#define TT 4096
#define DD 64
#define NCC 64
#define WSZW 128
#define TPK 160          // widened f32 top-k; f64 rescore picks exact top-128
#define MEMN 1
#define KVW (MEMN + WSZW)   // 129
constexpr float EPSF = 1e-5f;
constexpr float SCALE = 0.125f;  // 64^-0.5

typedef __attribute__((ext_vector_type(8))) short bf16x8;
typedef __attribute__((ext_vector_type(4))) float f32x4;

// HW packed f32->bf16 (RNE), 1 instruction vs ~7 for the manual bit-twiddle
static __device__ __forceinline__ unsigned int pk2(float a, float b) {
    unsigned int r;
    asm("v_cvt_pk_bf16_f32 %0, %1, %2" : "=v"(r) : "v"(a), "v"(b));
    return r;
}
static __device__ __forceinline__ bf16x8 pack8(float4 a, float4 b) {
    union { unsigned int u[4]; bf16x8 v; } r;
    r.u[0] = pk2(a.x, a.y); r.u[1] = pk2(a.z, a.w);
    r.u[2] = pk2(b.x, b.y); r.u[3] = pk2(b.z, b.w);
    return r.v;
}
static __device__ __forceinline__ unsigned mono(float f) {
    unsigned b = __float_as_uint(f);
    return b ^ ((unsigned)(((int)b) >> 31) | 0x80000000u);
}

// ---------------- Kernel A: dists as tiled f32 GEMM + argmax + aux partials ------
__global__ __launch_bounds__(256, 4) void dists_kernel(
    const float* __restrict__ q, const float* __restrict__ k,
    const float* __restrict__ means,
    float* __restrict__ distsQ, float* __restrict__ distsK,
    float* __restrict__ aux_part)
{
    __shared__ float xS[64][68];   // [d][tok]; reused as dS[tok][c] after GEMM
    __shared__ float mS[64][68];   // [d][cluster]
    __shared__ float mqS[64];      // per-cluster ||m||^2

    const int chunks = (2 * TT) / 64;          // 128
    int bid = blockIdx.x;                      // 4096
    int bh = bid / chunks;
    int chunk = bid % chunks;
    int h = bh % HH;
    bool isQ = chunk < (TT / 64);
    int tbase = (isQ ? chunk : chunk - 64) * 64;
    const float* src = (isQ ? q : k) + ((size_t)bh * TT + tbase) * DD;
    float* dst = isQ ? distsQ : distsK;

    int tid = threadIdx.x;
    int tok = tid >> 2, part = tid & 3;        // tok doubles as cluster idx below

    // ---- stage means (transposed) + per-cluster sumsq ----
    {
        const float* mp = means + ((size_t)h * NCC + tok) * DD + part * 16;
        float4 va[4];
        #pragma unroll
        for (int i = 0; i < 4; ++i) va[i] = *(const float4*)(mp + i * 4);
        float msq = 0.f;
        #pragma unroll
        for (int i = 0; i < 4; ++i) {
            msq += va[i].x*va[i].x + va[i].y*va[i].y + va[i].z*va[i].z + va[i].w*va[i].w;
            int d = part * 16 + i * 4;
            mS[d][tok] = va[i].x; mS[d+1][tok] = va[i].y;
            mS[d+2][tok] = va[i].z; mS[d+3][tok] = va[i].w;
        }
        msq += __shfl_xor(msq, 1);
        msq += __shfl_xor(msq, 2);
        if (part == 0) mqS[tok] = msq;
    }
    // ---- stage x normalized (transposed) ----
    float ssn;
    {
        const float* xp = src + (size_t)tok * DD + part * 16;
        float4 va[4];
        #pragma unroll
        for (int i = 0; i < 4; ++i) va[i] = *(const float4*)(xp + i * 4);
        float ss = 0.f;
        #pragma unroll
        for (int i = 0; i < 4; ++i)
            ss += va[i].x*va[i].x + va[i].y*va[i].y + va[i].z*va[i].z + va[i].w*va[i].w;
        ss += __shfl_xor(ss, 1);
        ss += __shfl_xor(ss, 2);
        float inv = 1.f / fmaxf(sqrtf(ss), 1e-12f);
        ssn = ss * inv * inv;
        #pragma unroll
        for (int i = 0; i < 4; ++i) {
            int d = part * 16 + i * 4;
            xS[d][tok] = va[i].x*inv; xS[d+1][tok] = va[i].y*inv;
            xS[d+2][tok] = va[i].z*inv; xS[d+3][tok] = va[i].w*inv;
        }
    }
    __syncthreads();

    // ---- GEMM: thread = 4 tokens x 4 clusters ----
    int l = tid & 63, w = tid >> 6;
    int ti = l & 15;                 // token tile 4*ti..
    int ci = w * 4 + (l >> 4);       // cluster tile 4*ci..
    float acc[4][4];
    #pragma unroll
    for (int i = 0; i < 4; ++i)
        #pragma unroll
        for (int j = 0; j < 4; ++j) acc[i][j] = 0.f;

    #pragma unroll 16
    for (int kk = 0; kk < 64; ++kk) {
        float4 xv = *(const float4*)(&xS[kk][ti * 4]);
        float4 mv = *(const float4*)(&mS[kk][ci * 4]);
        float xa[4] = {xv.x, xv.y, xv.z, xv.w};
        float ma[4] = {mv.x, mv.y, mv.z, mv.w};
        #pragma unroll
        for (int i = 0; i < 4; ++i)
            #pragma unroll
            for (int j = 0; j < 4; ++j) acc[i][j] += xa[i] * ma[j];
    }

    // ---- store dists to global (coalesced float4 over tokens) ----
    {
        size_t rowb = (size_t)(bh * NCC) * TT;
        #pragma unroll
        for (int j = 0; j < 4; ++j) {
            int c = ci * 4 + j;
            float4 o;
            o.x = acc[0][j]; o.y = acc[1][j]; o.z = acc[2][j]; o.w = acc[3][j];
            *(float4*)&dst[rowb + (size_t)c * TT + tbase + ti * 4] = o;
        }
    }

    // ---- argmax + aux via LDS round-trip (reuse xS as dS[tok][c]) ----
    __syncthreads();
    #pragma unroll
    for (int i = 0; i < 4; ++i)
        #pragma unroll
        for (int j = 0; j < 4; ++j)
            xS[ti * 4 + i][ci * 4 + j] = acc[i][j];
    __syncthreads();

    float bv = -1e30f; int bc = 0;
    #pragma unroll
    for (int j = 0; j < 16; ++j) {
        int c = part * 16 + j;
        float vv = xS[tok][c];
        if (vv > bv) { bv = vv; bc = c; }
    }
    #pragma unroll
    for (int off = 1; off <= 2; off <<= 1) {
        float ov = __shfl_xor(bv, off);
        int   oc = __shfl_xor(bc, off);
        if (ov > bv || (ov == bv && oc < bc)) { bv = ov; bc = oc; }
    }
    float auxv = (part == 0) ? (ssn + mqS[bc] - 2.f * bv) : 0.f;
    #pragma unroll
    for (int off = 32; off; off >>= 1) auxv += __shfl_xor(auxv, off);
    if (l == 0) aux_part[bid * 4 + w] = auxv;
}

// ---------------- Kernel A2: reduce 16384 aux partials -> out[N] ----------------
__global__ __launch_bounds__(256) void aux_reduce_kernel(
    const float* __restrict__ aux_part, float* __restrict__ out)
{
    int t = threadIdx.x;
    float s = 0.f;
    for (int i = t; i < 16384; i += 256) s += aux_part[i];
    #pragma unroll
    for (int off = 32; off; off >>= 1) s += __shfl_xor(s, off);
    __shared__ float wsum[4];
    if ((t & 63) == 0) wsum[t >> 6] = s;
    __syncthreads();
    if (t == 0)
        out[(size_t)BB * HH * TT * DD] =
            (wsum[0] + wsum[1] + wsum[2] + wsum[3]) *
            (1.0f / (float)(BB * HH * 2 * TT * DD));
}

// ---------------- Kernel B: top-TPK per row, 3-pass radix (12/12/8 bits) -------
// Thread t owns indices t*16..t*16+15 (float4 loads). 12-bit first digit
// spreads float exponent concentration over ~256 bins (vs ~16 at 8-bit) ->
// ~2-way histogram atomics. Scan = reg suffix + wave shfl suffix (4 barriers
// per pass vs 20). Tie-fill = unordered predicated atomics (safe: rescore
// re-ranks; an excluded bit-identical twin can't reach f64 top-128).
__global__ __launch_bounds__(256) void topk_kernel(
    const float* __restrict__ dists, int* __restrict__ idxOut)
{
    int row = blockIdx.x;
    const float* dv = dists + (size_t)row * TT;
    int t = threadIdx.x;
    int lane = t & 63, w = t >> 6;

    unsigned u[16];
    #pragma unroll
    for (int j0 = 0; j0 < 4; ++j0) {
        float4 f = *(const float4*)(dv + t * 16 + j0 * 4);
        u[j0*4+0] = mono(f.x); u[j0*4+1] = mono(f.y);
        u[j0*4+2] = mono(f.z); u[j0*4+3] = mono(f.w);
    }

    __shared__ int hist[4096];
    __shared__ int wtot[4];
    __shared__ int binSel, tgtS;
    __shared__ int nGtS, posS, eqPos;

    int target = TPK;
    unsigned prefix = 0;

    // ---- passes 1,2: 12-bit digits over 4096 bins ----
    #pragma unroll
    for (int pass = 0; pass < 2; ++pass) {
        int4* hz = (int4*)&hist[t * 16];
        hz[0] = (int4){0,0,0,0}; hz[1] = (int4){0,0,0,0};
        hz[2] = (int4){0,0,0,0}; hz[3] = (int4){0,0,0,0};
        __syncthreads();
        if (pass == 0) {
            #pragma unroll
            for (int j = 0; j < 16; ++j) atomicAdd(&hist[u[j] >> 20], 1);
        } else {
            #pragma unroll
            for (int j = 0; j < 16; ++j)
                if ((u[j] >> 20) == (prefix >> 20))
                    atomicAdd(&hist[(u[j] >> 8) & 0xFFF], 1);
        }
        __syncthreads();
        int cnt[16], ls[16];
        {
            const int4* hp = (const int4*)&hist[t * 16];
            int4 c0 = hp[0], c1 = hp[1], c2 = hp[2], c3 = hp[3];
            cnt[0]=c0.x; cnt[1]=c0.y; cnt[2]=c0.z; cnt[3]=c0.w;
            cnt[4]=c1.x; cnt[5]=c1.y; cnt[6]=c1.z; cnt[7]=c1.w;
            cnt[8]=c2.x; cnt[9]=c2.y; cnt[10]=c2.z; cnt[11]=c2.w;
            cnt[12]=c3.x; cnt[13]=c3.y; cnt[14]=c3.z; cnt[15]=c3.w;
        }
        int run = 0;
        int ls_tmp;
        #pragma unroll
        for (int i = 15; i >= 0; --i) { run += cnt[i]; ls[i] = run; }
        (void)ls_tmp;
        int S = run;
        #pragma unroll
        for (int off = 1; off < 64; off <<= 1) {
            int o = __shfl_down(S, off);
            if (lane + off < 64) S += o;
        }
        if (lane == 0) wtot[w] = S;
        __syncthreads();
        int after = 0;
        for (int ww = w + 1; ww < 4; ++ww) after += wtot[ww];
        int St1 = S - run + after;      // suffix of bins owned by later threads
        #pragma unroll
        for (int i = 0; i < 16; ++i) {
            int sfxb = ls[i] + St1;
            if (sfxb >= target && sfxb - cnt[i] < target) {
                binSel = t * 16 + i; tgtS = target - (sfxb - cnt[i]);
            }
        }
        __syncthreads();
        prefix |= (pass == 0) ? ((unsigned)binSel << 20) : ((unsigned)binSel << 8);
        target = tgtS;
        __syncthreads();
    }

    // ---- pass 3: low 8 bits (256 bins) ----
    hist[t] = 0;
    __syncthreads();
    #pragma unroll
    for (int j = 0; j < 16; ++j)
        if ((u[j] >> 8) == (prefix >> 8))
            atomicAdd(&hist[u[j] & 0xFF], 1);
    __syncthreads();
    {
        int cnt = hist[t];
        int S = cnt;
        #pragma unroll
        for (int off = 1; off < 64; off <<= 1) {
            int o = __shfl_down(S, off);
            if (lane + off < 64) S += o;
        }
        if (lane == 0) wtot[w] = S;
        __syncthreads();
        int after = 0;
        for (int ww = w + 1; ww < 4; ++ww) after += wtot[ww];
        int sfx = S + after;
        if (sfx >= target && sfx - cnt < target) { binSel = t; tgtS = target - (sfx - cnt); }
    }
    __syncthreads();
    unsigned pivot = prefix | (unsigned)binSel;

    // ---- epilogue: compact >pivot, then ==pivot (unordered, capped) ----
    if (t == 0) { nGtS = 0; posS = 0; eqPos = 0; }
    __syncthreads();
    int myg = 0;
    #pragma unroll
    for (int j = 0; j < 16; ++j) myg += (u[j] > pivot) ? 1 : 0;
    if (myg) atomicAdd(&nGtS, myg);
    __syncthreads();
    int n_gt = nGtS;
    int n_need = TPK - n_gt;
    int* out = idxOut + (size_t)row * TPK;
    #pragma unroll
    for (int j = 0; j < 16; ++j) {
        if (u[j] > pivot) {
            int p = atomicAdd(&posS, 1);
            out[p] = t * 16 + j;
        } else if (u[j] == pivot) {
            int p = atomicAdd(&eqPos, 1);
            if (p < n_need) out[n_gt + p] = t * 16 + j;
        }
    }
}

// ---------------- Kernel B2: f64 rescore, 4 lanes per candidate (+count fusion) --
__global__ __launch_bounds__(640) void rescore_kernel(
    const float* __restrict__ q, const float* __restrict__ k,
    const float* __restrict__ means,
    const int* __restrict__ candQ, const int* __restrict__ candK,
    int* __restrict__ idxQ, int* __restrict__ idxK,
    int* __restrict__ counts)
{
    int rid = blockIdx.x;
    int side = rid >> 11;            // 0=Q, 1=K
    int row = rid & 2047;            // bh*NC + c
    int c = row & (NCC - 1);
    int bh = row >> 6;
    int h = bh % HH;

    const int* cand = (side ? candK : candQ) + (size_t)row * TPK;
    int* outIdx     = (side ? idxK : idxQ) + (size_t)row * WSZW;
    const float* xbase = (side ? k : q) + (size_t)bh * TT * DD;

    __shared__ double mD[DD];
    __shared__ double vS[TPK];
    __shared__ int    kiS[TPK];
    __shared__ int    rankS[TPK];

    int tid = threadIdx.x;
    if (tid < DD) mD[tid] = (double)means[((size_t)h * NCC + c) * DD + tid];
    __syncthreads();

    int g = tid >> 2;                // candidate 0..159
    int qt = tid & 3;                // quarter-row 0..3
    int tok = cand[g];
    const float* xp = xbase + (size_t)tok * DD + qt * 16;
    double dot = 0.0, ss = 0.0;
    #pragma unroll
    for (int i = 0; i < 4; ++i) {
        float4 va = *(const float4*)(xp + i * 4);
        int d = qt * 16 + i * 4;
        dot += (double)va.x * mD[d]   + (double)va.y * mD[d+1]
             + (double)va.z * mD[d+2] + (double)va.w * mD[d+3];
        ss  += (double)va.x * va.x + (double)va.y * va.y
             + (double)va.z * va.z + (double)va.w * va.w;
    }
    dot += __shfl_xor(dot, 1); dot += __shfl_xor(dot, 2);
    ss  += __shfl_xor(ss, 1);  ss  += __shfl_xor(ss, 2);
    double v = dot * (1.0 / fmax(sqrt(ss), 1e-12));
    if (qt == 0) { vS[g] = v; kiS[g] = tok; }
    __syncthreads();

    // rank: each lane counts its 40-candidate quarter, combine in-group
    int rk = 0;
    #pragma unroll 8
    for (int i = 0; i < TPK / 4; ++i) {
        int j = qt * (TPK / 4) + i;
        double vj = vS[j];
        int kj = kiS[j];
        rk += (vj > v || (vj == v && kj < tok)) ? 1 : 0;
    }
    rk += __shfl_xor(rk, 1); rk += __shfl_xor(rk, 2);
    if (qt == 0) rankS[g] = rk;
    __syncthreads();

    if (tid < TPK) {
        int r = rankS[tid];
        if (r < WSZW) {
            outIdx[r] = kiS[tid];
            if (side == 0) atomicAdd(&counts[bh * TT + kiS[tid]], 1);
        }
    }
}

// ---------------- Kernel C: bf16 MFMA attention, swapped-QK^T, V transposed ----
__global__ __launch_bounds__(512, 2) void attn_kernel(
    const float* __restrict__ q, const float* __restrict__ k, const float* __restrict__ v,
    const float* __restrict__ mem_key, const float* __restrict__ mem_value,
    const int* __restrict__ idxQ, const int* __restrict__ idxK,
    float* __restrict__ so)
{
    // XCD-bijective swizzle (2048 % 8 == 0): 256 consecutive blks per XCD
    int bid = blockIdx.x;
    int blk = (bid & 7) * 256 + (bid >> 3);
    int c = blk % NCC;
    int bh = blk / NCC;
    int h = bh % HH;

    __shared__ __align__(16) unsigned short KsS[160 * 64];   // [kv][d] swizzled (temp V row-major in P1/P2)
    __shared__ __align__(16) unsigned short VtS[64 * 168];   // [d][kv], pad 168

    int tid = threadIdx.x;
    int w = tid >> 6, l = tid & 63;
    int lr = l & 15, lg = l >> 4;

    const float* memK = mem_key   + ((size_t)h * NCC + c) * (MEMN * DD);
    const float* memV = mem_value + ((size_t)h * NCC + c) * (MEMN * DD);

    // ---- Q frags early (independent of LDS phases) ----
    bf16x8 qf[2];
    {
        int tq = idxQ[(size_t)blk * WSZW + w * 16 + lr];
        const float* qp = q + ((size_t)bh * TT + tq) * DD;
        #pragma unroll
        for (int ks = 0; ks < 2; ++ks) {
            float4 a = *(const float4*)(qp + ks * 32 + lg * 8);
            float4 b = *(const float4*)(qp + ks * 32 + lg * 8 + 4);
            qf[ks] = pack8(a, b);
        }
    }

    // ---- P1: V -> row-major swizzled (in KsS space) ----
    for (int idx = tid; idx < 1280; idx += 512) {
        int row = idx >> 3, ch = idx & 7;
        uint4 vw = {0,0,0,0};
        if (row < KVW) {
            const float* vsrc = (row == 0) ? memV
                : v + ((size_t)bh * TT + idxK[(size_t)blk * WSZW + row - 1]) * DD;
            float4 a = *(const float4*)(vsrc + ch * 8);
            float4 b = *(const float4*)(vsrc + ch * 8 + 4);
            vw.x = pk2(a.x, a.y); vw.y = pk2(a.z, a.w);
            vw.z = pk2(b.x, b.y); vw.w = pk2(b.z, b.w);
        }
        *reinterpret_cast<uint4*>(&KsS[row * 64 + ((ch ^ (row & 7)) * 8)]) = vw;
    }
    __syncthreads();

    // ---- P2: Vt column segments -> regs; K gathers -> regs ----
    unsigned short vreg[3][8];
    #pragma unroll
    for (int s = 0; s < 3; ++s) {
        int idx = tid + s * 512;
        if (idx < 1280) {
            int d = idx & 63, rowblk = idx >> 6;
            #pragma unroll
            for (int i = 0; i < 8; ++i) {
                int row = rowblk * 8 + i;
                vreg[s][i] = KsS[row * 64 + (((d >> 3) ^ (row & 7)) * 8) + (d & 7)];
            }
        }
    }
    uint4 kreg[3];
    #pragma unroll
    for (int s = 0; s < 3; ++s) {
        int idx = tid + s * 512;
        kreg[s] = (uint4){0,0,0,0};
        if (idx < 1280) {
            int row = idx >> 3, ch = idx & 7;
            if (row < KVW) {
                const float* ksrc = (row == 0) ? memK
                    : k + ((size_t)bh * TT + idxK[(size_t)blk * WSZW + row - 1]) * DD;
                float4 a = *(const float4*)(ksrc + ch * 8);
                float4 b = *(const float4*)(ksrc + ch * 8 + 4);
                kreg[s].x = pk2(a.x, a.y); kreg[s].y = pk2(a.z, a.w);
                kreg[s].z = pk2(b.x, b.y); kreg[s].w = pk2(b.z, b.w);
            }
        }
    }
    __syncthreads();

    // ---- P3: write Vt (b128 rows) + K (b128 swizzled) ----
    #pragma unroll
    for (int s = 0; s < 3; ++s) {
        int idx = tid + s * 512;
        if (idx < 1280) {
            int d = idx & 63, rowblk = idx >> 6;
            uint4 ow;
            ow.x = (unsigned)vreg[s][0] | ((unsigned)vreg[s][1] << 16);
            ow.y = (unsigned)vreg[s][2] | ((unsigned)vreg[s][3] << 16);
            ow.z = (unsigned)vreg[s][4] | ((unsigned)vreg[s][5] << 16);
            ow.w = (unsigned)vreg[s][6] | ((unsigned)vreg[s][7] << 16);
            *reinterpret_cast<uint4*>(&VtS[d * 168 + rowblk * 8]) = ow;
        }
    }
    #pragma unroll
    for (int s = 0; s < 3; ++s) {
        int idx = tid + s * 512;
        if (idx < 1280) {
            int row = idx >> 3, ch = idx & 7;
            *reinterpret_cast<uint4*>(&KsS[row * 64 + ((ch ^ (row & 7)) * 8)]) = kreg[s];
        }
    }
    __syncthreads();

    // ---- compute (swapped QK^T, P in regs, Vt b128 B-frags) ----
    f32x4 acc[4];
    #pragma unroll
    for (int dt = 0; dt < 4; ++dt) acc[dt] = (f32x4){0.f, 0.f, 0.f, 0.f};
    float s_sum = 0.f;

    int src0 = lr + ((lg & 1) * 2) * 16;
    int src1 = src0 + 16;
    bool hi = (lg >> 1) != 0;

    for (int kb = 0; kb < 5; ++kb) {
        bf16x8 kf[2][2];
        #pragma unroll
        for (int kvt = 0; kvt < 2; ++kvt)
            #pragma unroll
            for (int ks = 0; ks < 2; ++ks) {
                int row = kb * 32 + kvt * 16 + lr;
                int chunk = ks * 4 + lg;
                int phys = chunk ^ (row & 7);
                kf[kvt][ks] = *reinterpret_cast<const bf16x8*>(&KsS[row * 64 + phys * 8]);
            }
        __builtin_amdgcn_s_setprio(1);
        unsigned pk[2][2];
        #pragma unroll
        for (int kvt = 0; kvt < 2; ++kvt) {
            f32x4 sf = __builtin_amdgcn_mfma_f32_16x16x32_bf16(
                kf[kvt][0], qf[0], (f32x4){0.f,0.f,0.f,0.f}, 0, 0, 0);
            sf = __builtin_amdgcn_mfma_f32_16x16x32_bf16(kf[kvt][1], qf[1], sf, 0, 0, 0);
            float e[4];
            #pragma unroll
            for (int r = 0; r < 4; ++r) {
                int kv = kb * 32 + kvt * 16 + lg * 4 + r;
                e[r] = (kv < KVW) ? __expf(sf[r] * SCALE) : 0.f;
                s_sum += e[r];
            }
            pk[kvt][0] = pk2(e[0], e[1]);
            pk[kvt][1] = pk2(e[2], e[3]);
        }
        unsigned a00 = __shfl(pk[0][0], src0), a01 = __shfl(pk[0][1], src0);
        unsigned a10 = __shfl(pk[1][0], src0), a11 = __shfl(pk[1][1], src0);
        unsigned b00 = __shfl(pk[0][0], src1), b01 = __shfl(pk[0][1], src1);
        unsigned b10 = __shfl(pk[1][0], src1), b11 = __shfl(pk[1][1], src1);
        union { unsigned u[4]; bf16x8 v; } pu;
        pu.u[0] = hi ? a10 : a00;
        pu.u[1] = hi ? a11 : a01;
        pu.u[2] = hi ? b10 : b00;
        pu.u[3] = hi ? b11 : b01;
        #pragma unroll
        for (int dt = 0; dt < 4; ++dt) {
            bf16x8 vf = *reinterpret_cast<const bf16x8*>(
                &VtS[(dt * 16 + lr) * 168 + kb * 32 + lg * 8]);
            acc[dt] = __builtin_amdgcn_mfma_f32_16x16x32_bf16(pu.v, vf, acc[dt], 0, 0, 0);
        }
        __builtin_amdgcn_s_setprio(0);
    }

    s_sum += __shfl_xor(s_sum, 16);
    s_sum += __shfl_xor(s_sum, 32);
    float sinv[4];
    #pragma unroll
    for (int r = 0; r < 4; ++r)
        sinv[r] = 1.f / __shfl(s_sum, lg * 4 + r);

    #pragma unroll
    for (int r = 0; r < 4; ++r) {
        int row = w * 16 + lg * 4 + r;
        float* op = so + (((size_t)blk * WSZW + row) * DD);
        #pragma unroll
        for (int dt = 0; dt < 4; ++dt)
            op[dt * 16 + lr] = acc[dt][r] * sinv[r];
    }
}

// ---------------- Kernel F: per-bh exclusive scan (4096 ints) ----------------
__global__ __launch_bounds__(256) void scan_kernel(
    const int* __restrict__ counts, int* __restrict__ offs)
{
    int bh = blockIdx.x;
    int t = threadIdx.x;
    const int* cb = counts + (size_t)bh * TT;
    int* ob = offs + (size_t)bh * TT;

    int loc[16]; int sum = 0;
    #pragma unroll
    for (int i = 0; i < 16; ++i) { loc[i] = sum; sum += cb[t * 16 + i]; }

    __shared__ int wsum[256];
    wsum[t] = sum;
    __syncthreads();
    for (int off = 1; off < 256; off <<= 1) {
        int vv = (t >= off) ? wsum[t - off] : 0;
        __syncthreads();
        wsum[t] += vv;
        __syncthreads();
    }
    int ex = (t == 0) ? 0 : wsum[t - 1];
    #pragma unroll
    for (int i = 0; i < 16; ++i) ob[t * 16 + i] = ex + loc[i];
}

// ---------------- Kernel G: fill CSR slot lists ----------------
__global__ __launch_bounds__(256) void fill_kernel(
    const int* __restrict__ idxQ, const int* __restrict__ offs,
    int* __restrict__ cur, int* __restrict__ csr)
{
    int i = blockIdx.x * 256 + threadIdx.x;
    int bh = i >> 13;
    int within = i & 8191;
    int tok = idxQ[i];
    int p = offs[bh * TT + tok] + atomicAdd(&cur[bh * TT + tok], 1);
    csr[((size_t)bh << 13) + p] = within;
}

// ---------------- Kernel H: gather-reduce + finalize ----------------
__global__ __launch_bounds__(256) void reduce_kernel(
    const float* __restrict__ so, const int* __restrict__ counts,
    const int* __restrict__ offs, const int* __restrict__ csr,
    float* __restrict__ out)
{
    int gt = blockIdx.x * 4 + (threadIdx.x >> 6);
    int lane = threadIdx.x & 63;
    int bh = gt >> 12;
    int n = counts[gt];
    int st = offs[gt];
    const int* cs = csr + ((size_t)bh << 13);
    float acc = 0.f;
    for (int j = 0; j < n; ++j) {
        int slot = cs[st + j];
        acc += so[(((size_t)bh << 13) + slot) * DD + lane];
    }
    out[(size_t)gt * DD + lane] = acc / ((float)n + EPSF);
}

extern "C" void kernel_launch(void* const* d_in, const int* in_sizes, int n_in,
                              void* d_out, int out_size, void* d_ws, size_t ws_size,
                              hipStream_t stream) {
    const float* q        = (const float*)d_in[0];
    const float* k        = (const float*)d_in[1];
    const float* v        = (const float*)d_in[2];
    const float* means    = (const float*)d_in[3];
    const float* mem_key  = (const float*)d_in[4];
    const float* mem_val  = (const float*)d_in[5];
    float* out = (float*)d_out;

    const size_t nRows = (size_t)BB * HH * NCC;             // 2048
    const size_t nTok  = (size_t)BB * HH * TT;              // 131072
    float* wsf    = (float*)d_ws;
    float* distsQ = wsf;                                    // 8388608 f
    float* distsK = distsQ + (size_t)BB * HH * NCC * TT;    // 8388608 f (contiguous after distsQ)
    float* so     = wsf;                                    // aliases dists; written after rescore
    int*   idxQ   = (int*)(distsK + (size_t)BB * HH * NCC * TT);  // 262144 i
    int*   idxK   = idxQ + nRows * WSZW;                    // 262144 i
    int*   counts = idxK + nRows * WSZW;                    // 131072 i
    int*   cur    = counts + nTok;                          // 131072 i
    float* auxp   = (float*)(cur + nTok);                   // 16384 f (per-wave partials)
    int*   offs   = (int*)(auxp + 16384);                   // 131072 i
    int*   csr    = offs + nTok;                            // 262144 i
    int*   candQ  = csr + nTok * 2;                         // 2048*160 i
    int*   candK  = candQ + nRows * TPK;                    // 2048*160 i (contiguous after candQ)

    hipMemsetAsync(counts, 0, 2 * nTok * sizeof(int), stream);

    dists_kernel<<<dim3(BB * HH * (2 * TT / 64)), dim3(256), 0, stream>>>(
        q, k, means, distsQ, distsK, auxp);
    aux_reduce_kernel<<<dim3(1), dim3(256), 0, stream>>>(auxp, out);
    // single launch covers Q rows (0..2047 over distsQ/candQ) and K rows
    // (2048..4095 over distsK/candK) via buffer contiguity
    topk_kernel<<<dim3((unsigned)(2 * nRows)), dim3(256), 0, stream>>>(distsQ, candQ);
    rescore_kernel<<<dim3((unsigned)(2 * nRows)), dim3(640), 0, stream>>>(
        q, k, means, candQ, candK, idxQ, idxK, counts);
    scan_kernel<<<dim3(BB * HH), dim3(256), 0, stream>>>(counts, offs);
    fill_kernel<<<dim3(1024), dim3(256), 0, stream>>>(idxQ, offs, cur, csr);
    attn_kernel<<<dim3((unsigned)nRows), dim3(512), 0, stream>>>(
        q, k, v, mem_key, mem_val, idxQ, idxK, so);
    reduce_kernel<<<dim3((unsigned)(nTok / 4)), dim3(256), 0, stream>>>(
        so, counts, offs, csr, out);
}

// Round 16
// 256.782 us; speedup vs baseline: 1.9273x; 1.0035x over previous
//
#include <hip/hip_runtime.h>
#include <math.h>

#define BB 4
#define HH 8
#define TT 4096
#define DD 64
#define NCC 64
#define WSZW 128
#define TPK 160          // widened f32 top-k; f64 rescore picks exact top-128
#define MEMN 1
#define KVW (MEMN + WSZW)   // 129
constexpr float EPSF = 1e-5f;
constexpr float SCALE = 0.125f;  // 64^-0.5

typedef __attribute__((ext_vector_type(8))) short bf16x8;
typedef __attribute__((ext_vector_type(4))) float f32x4;

// HW packed f32->bf16 (RNE), 1 instruction vs ~7 for the manual bit-twiddle
static __device__ __forceinline__ unsigned int pk2(float a, float b) {
    unsigned int r;
    asm("v_cvt_pk_bf16_f32 %0, %1, %2" : "=v"(r) : "v"(a), "v"(b));
    return r;
}
static __device__ __forceinline__ bf16x8 pack8(float4 a, float4 b) {
    union { unsigned int u[4]; bf16x8 v; } r;
    r.u[0] = pk2(a.x, a.y); r.u[1] = pk2(a.z, a.w);
    r.u[2] = pk2(b.x, b.y); r.u[3] = pk2(b.z, b.w);
    return r.v;
}
static __device__ __forceinline__ unsigned mono(float f) {
    unsigned b = __float_as_uint(f);
    return b ^ ((unsigned)(((int)b) >> 31) | 0x80000000u);
}

// ---------------- Kernel A: dists f32 GEMM + argmax + aux + f64 invnorm ---------
// f64 invnorm per token hoisted here (x already in regs) so rescore can skip
// its per-candidate f64 sqrt/div chain.
__global__ __launch_bounds__(256, 4) void dists_kernel(
    const float* __restrict__ q, const float* __restrict__ k,
    const float* __restrict__ means,
    float* __restrict__ distsQ, float* __restrict__ distsK,
    float* __restrict__ aux_part, double* __restrict__ invn)
{
    __shared__ float xS[64][68];   // [d][tok]; reused as dS[tok][c] after GEMM
    __shared__ float mS[64][68];   // [d][cluster]
    __shared__ float mqS[64];      // per-cluster ||m||^2

    const int chunks = (2 * TT) / 64;          // 128
    int bid = blockIdx.x;                      // 4096
    int bh = bid / chunks;
    int chunk = bid % chunks;
    int h = bh % HH;
    bool isQ = chunk < (TT / 64);
    int tbase = (isQ ? chunk : chunk - 64) * 64;
    const float* src = (isQ ? q : k) + ((size_t)bh * TT + tbase) * DD;
    float* dst = isQ ? distsQ : distsK;
    double* invdst = invn + (isQ ? 0 : (size_t)BB * HH * TT) + (size_t)bh * TT + tbase;

    int tid = threadIdx.x;
    int tok = tid >> 2, part = tid & 3;        // tok doubles as cluster idx below

    // ---- stage means (transposed) + per-cluster sumsq ----
    {
        const float* mp = means + ((size_t)h * NCC + tok) * DD + part * 16;
        float4 va[4];
        #pragma unroll
        for (int i = 0; i < 4; ++i) va[i] = *(const float4*)(mp + i * 4);
        float msq = 0.f;
        #pragma unroll
        for (int i = 0; i < 4; ++i) {
            msq += va[i].x*va[i].x + va[i].y*va[i].y + va[i].z*va[i].z + va[i].w*va[i].w;
            int d = part * 16 + i * 4;
            mS[d][tok] = va[i].x; mS[d+1][tok] = va[i].y;
            mS[d+2][tok] = va[i].z; mS[d+3][tok] = va[i].w;
        }
        msq += __shfl_xor(msq, 1);
        msq += __shfl_xor(msq, 2);
        if (part == 0) mqS[tok] = msq;
    }
    // ---- stage x normalized (transposed); f64 norm, store invnorm ----
    float ssn;
    {
        const float* xp = src + (size_t)tok * DD + part * 16;
        float4 va[4];
        #pragma unroll
        for (int i = 0; i < 4; ++i) va[i] = *(const float4*)(xp + i * 4);
        double ssd = 0.0;
        #pragma unroll
        for (int i = 0; i < 4; ++i)
            ssd += (double)va[i].x*va[i].x + (double)va[i].y*va[i].y
                 + (double)va[i].z*va[i].z + (double)va[i].w*va[i].w;
        ssd += __shfl_xor(ssd, 1);
        ssd += __shfl_xor(ssd, 2);
        double invd = 1.0 / fmax(sqrt(ssd), 1e-12);
        if (part == 0) invdst[tok] = invd;
        float inv = (float)invd;
        ssn = (float)(ssd * invd * invd);
        #pragma unroll
        for (int i = 0; i < 4; ++i) {
            int d = part * 16 + i * 4;
            xS[d][tok] = va[i].x*inv; xS[d+1][tok] = va[i].y*inv;
            xS[d+2][tok] = va[i].z*inv; xS[d+3][tok] = va[i].w*inv;
        }
    }
    __syncthreads();

    // ---- GEMM: thread = 4 tokens x 4 clusters ----
    int l = tid & 63, w = tid >> 6;
    int ti = l & 15;                 // token tile 4*ti..
    int ci = w * 4 + (l >> 4);       // cluster tile 4*ci..
    float acc[4][4];
    #pragma unroll
    for (int i = 0; i < 4; ++i)
        #pragma unroll
        for (int j = 0; j < 4; ++j) acc[i][j] = 0.f;

    #pragma unroll 16
    for (int kk = 0; kk < 64; ++kk) {
        float4 xv = *(const float4*)(&xS[kk][ti * 4]);
        float4 mv = *(const float4*)(&mS[kk][ci * 4]);
        float xa[4] = {xv.x, xv.y, xv.z, xv.w};
        float ma[4] = {mv.x, mv.y, mv.z, mv.w};
        #pragma unroll
        for (int i = 0; i < 4; ++i)
            #pragma unroll
            for (int j = 0; j < 4; ++j) acc[i][j] += xa[i] * ma[j];
    }

    // ---- store dists to global (coalesced float4 over tokens) ----
    {
        size_t rowb = (size_t)(bh * NCC) * TT;
        #pragma unroll
        for (int j = 0; j < 4; ++j) {
            int c = ci * 4 + j;
            float4 o;
            o.x = acc[0][j]; o.y = acc[1][j]; o.z = acc[2][j]; o.w = acc[3][j];
            *(float4*)&dst[rowb + (size_t)c * TT + tbase + ti * 4] = o;
        }
    }

    // ---- argmax + aux via LDS round-trip (reuse xS as dS[tok][c]) ----
    __syncthreads();
    #pragma unroll
    for (int i = 0; i < 4; ++i)
        #pragma unroll
        for (int j = 0; j < 4; ++j)
            xS[ti * 4 + i][ci * 4 + j] = acc[i][j];
    __syncthreads();

    float bv = -1e30f; int bc = 0;
    #pragma unroll
    for (int j = 0; j < 16; ++j) {
        int c = part * 16 + j;
        float vv = xS[tok][c];
        if (vv > bv) { bv = vv; bc = c; }
    }
    #pragma unroll
    for (int off = 1; off <= 2; off <<= 1) {
        float ov = __shfl_xor(bv, off);
        int   oc = __shfl_xor(bc, off);
        if (ov > bv || (ov == bv && oc < bc)) { bv = ov; bc = oc; }
    }
    float auxv = (part == 0) ? (ssn + mqS[bc] - 2.f * bv) : 0.f;
    #pragma unroll
    for (int off = 32; off; off >>= 1) auxv += __shfl_xor(auxv, off);
    if (l == 0) aux_part[bid * 4 + w] = auxv;
}

// ---------------- Kernel A2: reduce 16384 aux partials -> out[N] ----------------
__global__ __launch_bounds__(256) void aux_reduce_kernel(
    const float* __restrict__ aux_part, float* __restrict__ out)
{
    int t = threadIdx.x;
    float s = 0.f;
    for (int i = t; i < 16384; i += 256) s += aux_part[i];
    #pragma unroll
    for (int off = 32; off; off >>= 1) s += __shfl_xor(s, off);
    __shared__ float wsum[4];
    if ((t & 63) == 0) wsum[t >> 6] = s;
    __syncthreads();
    if (t == 0)
        out[(size_t)BB * HH * TT * DD] =
            (wsum[0] + wsum[1] + wsum[2] + wsum[3]) *
            (1.0f / (float)(BB * HH * 2 * TT * DD));
}

// ---------------- Kernel B: top-TPK per row, 3-pass radix (12/12/8 bits) -------
__global__ __launch_bounds__(256) void topk_kernel(
    const float* __restrict__ dists, int* __restrict__ idxOut)
{
    int row = blockIdx.x;
    const float* dv = dists + (size_t)row * TT;
    int t = threadIdx.x;
    int lane = t & 63, w = t >> 6;

    unsigned u[16];
    #pragma unroll
    for (int j0 = 0; j0 < 4; ++j0) {
        float4 f = *(const float4*)(dv + t * 16 + j0 * 4);
        u[j0*4+0] = mono(f.x); u[j0*4+1] = mono(f.y);
        u[j0*4+2] = mono(f.z); u[j0*4+3] = mono(f.w);
    }

    __shared__ int hist[4096];
    __shared__ int wtot[4];
    __shared__ int binSel, tgtS;
    __shared__ int nGtS, posS, eqPos;

    int target = TPK;
    unsigned prefix = 0;

    // ---- passes 1,2: 12-bit digits over 4096 bins ----
    #pragma unroll
    for (int pass = 0; pass < 2; ++pass) {
        int4* hz = (int4*)&hist[t * 16];
        hz[0] = (int4){0,0,0,0}; hz[1] = (int4){0,0,0,0};
        hz[2] = (int4){0,0,0,0}; hz[3] = (int4){0,0,0,0};
        __syncthreads();
        if (pass == 0) {
            #pragma unroll
            for (int j = 0; j < 16; ++j) atomicAdd(&hist[u[j] >> 20], 1);
        } else {
            #pragma unroll
            for (int j = 0; j < 16; ++j)
                if ((u[j] >> 20) == (prefix >> 20))
                    atomicAdd(&hist[(u[j] >> 8) & 0xFFF], 1);
        }
        __syncthreads();
        int cnt[16], ls[16];
        {
            const int4* hp = (const int4*)&hist[t * 16];
            int4 c0 = hp[0], c1 = hp[1], c2 = hp[2], c3 = hp[3];
            cnt[0]=c0.x; cnt[1]=c0.y; cnt[2]=c0.z; cnt[3]=c0.w;
            cnt[4]=c1.x; cnt[5]=c1.y; cnt[6]=c1.z; cnt[7]=c1.w;
            cnt[8]=c2.x; cnt[9]=c2.y; cnt[10]=c2.z; cnt[11]=c2.w;
            cnt[12]=c3.x; cnt[13]=c3.y; cnt[14]=c3.z; cnt[15]=c3.w;
        }
        int run = 0;
        #pragma unroll
        for (int i = 15; i >= 0; --i) { run += cnt[i]; ls[i] = run; }
        int S = run;
        #pragma unroll
        for (int off = 1; off < 64; off <<= 1) {
            int o = __shfl_down(S, off);
            if (lane + off < 64) S += o;
        }
        if (lane == 0) wtot[w] = S;
        __syncthreads();
        int after = 0;
        for (int ww = w + 1; ww < 4; ++ww) after += wtot[ww];
        int St1 = S - run + after;      // suffix of bins owned by later threads
        #pragma unroll
        for (int i = 0; i < 16; ++i) {
            int sfxb = ls[i] + St1;
            if (sfxb >= target && sfxb - cnt[i] < target) {
                binSel = t * 16 + i; tgtS = target - (sfxb - cnt[i]);
            }
        }
        __syncthreads();
        prefix |= (pass == 0) ? ((unsigned)binSel << 20) : ((unsigned)binSel << 8);
        target = tgtS;
        __syncthreads();
    }

    // ---- pass 3: low 8 bits (256 bins) ----
    hist[t] = 0;
    __syncthreads();
    #pragma unroll
    for (int j = 0; j < 16; ++j)
        if ((u[j] >> 8) == (prefix >> 8))
            atomicAdd(&hist[u[j] & 0xFF], 1);
    __syncthreads();
    {
        int cnt = hist[t];
        int S = cnt;
        #pragma unroll
        for (int off = 1; off < 64; off <<= 1) {
            int o = __shfl_down(S, off);
            if (lane + off < 64) S += o;
        }
        if (lane == 0) wtot[w] = S;
        __syncthreads();
        int after = 0;
        for (int ww = w + 1; ww < 4; ++ww) after += wtot[ww];
        int sfx = S + after;
        if (sfx >= target && sfx - cnt < target) { binSel = t; tgtS = target - (sfx - cnt); }
    }
    __syncthreads();
    unsigned pivot = prefix | (unsigned)binSel;

    // ---- epilogue: compact >pivot, then ==pivot (unordered, capped) ----
    if (t == 0) { nGtS = 0; posS = 0; eqPos = 0; }
    __syncthreads();
    int myg = 0;
    #pragma unroll
    for (int j = 0; j < 16; ++j) myg += (u[j] > pivot) ? 1 : 0;
    if (myg) atomicAdd(&nGtS, myg);
    __syncthreads();
    int n_gt = nGtS;
    int n_need = TPK - n_gt;
    int* out = idxOut + (size_t)row * TPK;
    #pragma unroll
    for (int j = 0; j < 16; ++j) {
        if (u[j] > pivot) {
            int p = atomicAdd(&posS, 1);
            out[p] = t * 16 + j;
        } else if (u[j] == pivot) {
            int p = atomicAdd(&eqPos, 1);
            if (p < n_need) out[n_gt + p] = t * 16 + j;
        }
    }
}

// ---------------- Kernel B2: f64 rescore (precomputed invnorm, 2-chain dot) ----
__global__ __launch_bounds__(640) void rescore_kernel(
    const float* __restrict__ q, const float* __restrict__ k,
    const float* __restrict__ means, const double* __restrict__ invn,
    const int* __restrict__ candQ, const int* __restrict__ candK,
    int* __restrict__ idxQ, int* __restrict__ idxK,
    int* __restrict__ counts)
{
    int rid = blockIdx.x;
    int side = rid >> 11;            // 0=Q, 1=K
    int row = rid & 2047;            // bh*NC + c
    int c = row & (NCC - 1);
    int bh = row >> 6;
    int h = bh % HH;

    const int* cand = (side ? candK : candQ) + (size_t)row * TPK;
    int* outIdx     = (side ? idxK : idxQ) + (size_t)row * WSZW;
    const float* xbase = (side ? k : q) + (size_t)bh * TT * DD;
    const double* invp = invn + (side ? (size_t)BB * HH * TT : 0) + (size_t)bh * TT;

    __shared__ double mD[DD];
    __shared__ double vS[TPK];
    __shared__ int    kiS[TPK];
    __shared__ int    rankS[TPK];

    int tid = threadIdx.x;
    if (tid < DD) mD[tid] = (double)means[((size_t)h * NCC + c) * DD + tid];
    __syncthreads();

    int g = tid >> 2;                // candidate 0..159
    int qt = tid & 3;                // quarter-row 0..3
    int tok = cand[g];
    const float* xp = xbase + (size_t)tok * DD + qt * 16;
    double inv = invp[tok];          // 4 lanes same addr -> broadcast
    double d0 = 0.0, d1 = 0.0;
    #pragma unroll
    for (int i = 0; i < 2; ++i) {
        float4 va = *(const float4*)(xp + i * 4);
        int d = qt * 16 + i * 4;
        d0 += (double)va.x * mD[d]   + (double)va.y * mD[d+1]
            + (double)va.z * mD[d+2] + (double)va.w * mD[d+3];
    }
    #pragma unroll
    for (int i = 2; i < 4; ++i) {
        float4 va = *(const float4*)(xp + i * 4);
        int d = qt * 16 + i * 4;
        d1 += (double)va.x * mD[d]   + (double)va.y * mD[d+1]
            + (double)va.z * mD[d+2] + (double)va.w * mD[d+3];
    }
    double dot = d0 + d1;
    dot += __shfl_xor(dot, 1); dot += __shfl_xor(dot, 2);
    double v = dot * inv;
    if (qt == 0) { vS[g] = v; kiS[g] = tok; }
    __syncthreads();

    // rank: each lane counts its 40-candidate quarter, combine in-group
    int rk = 0;
    #pragma unroll 8
    for (int i = 0; i < TPK / 4; ++i) {
        int j = qt * (TPK / 4) + i;
        double vj = vS[j];
        int kj = kiS[j];
        rk += (vj > v || (vj == v && kj < tok)) ? 1 : 0;
    }
    rk += __shfl_xor(rk, 1); rk += __shfl_xor(rk, 2);
    if (qt == 0) rankS[g] = rk;
    __syncthreads();

    if (tid < TPK) {
        int r = rankS[tid];
        if (r < WSZW) {
            outIdx[r] = kiS[tid];
            if (side == 0) atomicAdd(&counts[bh * TT + kiS[tid]], 1);
        }
    }
}

// ---------------- Kernel C: bf16 MFMA attention, swapped-QK^T, V transposed ----
__global__ __launch_bounds__(512, 2) void attn_kernel(
    const float* __restrict__ q, const float* __restrict__ k, const float* __restrict__ v,
    const float* __restrict__ mem_key, const float* __restrict__ mem_value,
    const int* __restrict__ idxQ, const int* __restrict__ idxK,
    float* __restrict__ so)
{
    // XCD-bijective swizzle (2048 % 8 == 0): 256 consecutive blks per XCD
    int bid = blockIdx.x;
    int blk = (bid & 7) * 256 + (bid >> 3);
    int c = blk % NCC;
    int bh = blk / NCC;
    int h = bh % HH;

    __shared__ __align__(16) unsigned short KsS[160 * 64];   // [kv][d] swizzled (temp V row-major in P1/P2)
    __shared__ __align__(16) unsigned short VtS[64 * 168];   // [d][kv], pad 168

    int tid = threadIdx.x;
    int w = tid >> 6, l = tid & 63;
    int lr = l & 15, lg = l >> 4;

    const float* memK = mem_key   + ((size_t)h * NCC + c) * (MEMN * DD);
    const float* memV = mem_value + ((size_t)h * NCC + c) * (MEMN * DD);

    // ---- Q frags early (independent of LDS phases) ----
    bf16x8 qf[2];
    {
        int tq = idxQ[(size_t)blk * WSZW + w * 16 + lr];
        const float* qp = q + ((size_t)bh * TT + tq) * DD;
        #pragma unroll
        for (int ks = 0; ks < 2; ++ks) {
            float4 a = *(const float4*)(qp + ks * 32 + lg * 8);
            float4 b = *(const float4*)(qp + ks * 32 + lg * 8 + 4);
            qf[ks] = pack8(a, b);
        }
    }

    // ---- P1: V -> row-major swizzled (in KsS space) ----
    for (int idx = tid; idx < 1280; idx += 512) {
        int row = idx >> 3, ch = idx & 7;
        uint4 vw = {0,0,0,0};
        if (row < KVW) {
            const float* vsrc = (row == 0) ? memV
                : v + ((size_t)bh * TT + idxK[(size_t)blk * WSZW + row - 1]) * DD;
            float4 a = *(const float4*)(vsrc + ch * 8);
            float4 b = *(const float4*)(vsrc + ch * 8 + 4);
            vw.x = pk2(a.x, a.y); vw.y = pk2(a.z, a.w);
            vw.z = pk2(b.x, b.y); vw.w = pk2(b.z, b.w);
        }
        *reinterpret_cast<uint4*>(&KsS[row * 64 + ((ch ^ (row & 7)) * 8)]) = vw;
    }
    __syncthreads();

    // ---- P2: Vt column segments -> regs; K gathers -> regs ----
    unsigned short vreg[3][8];
    #pragma unroll
    for (int s = 0; s < 3; ++s) {
        int idx = tid + s * 512;
        if (idx < 1280) {
            int d = idx & 63, rowblk = idx >> 6;
            #pragma unroll
            for (int i = 0; i < 8; ++i) {
                int row = rowblk * 8 + i;
                vreg[s][i] = KsS[row * 64 + (((d >> 3) ^ (row & 7)) * 8) + (d & 7)];
            }
        }
    }
    uint4 kreg[3];
    #pragma unroll
    for (int s = 0; s < 3; ++s) {
        int idx = tid + s * 512;
        kreg[s] = (uint4){0,0,0,0};
        if (idx < 1280) {
            int row = idx >> 3, ch = idx & 7;
            if (row < KVW) {
                const float* ksrc = (row == 0) ? memK
                    : k + ((size_t)bh * TT + idxK[(size_t)blk * WSZW + row - 1]) * DD;
                float4 a = *(const float4*)(ksrc + ch * 8);
                float4 b = *(const float4*)(ksrc + ch * 8 + 4);
                kreg[s].x = pk2(a.x, a.y); kreg[s].y = pk2(a.z, a.w);
                kreg[s].z = pk2(b.x, b.y); kreg[s].w = pk2(b.z, b.w);
            }
        }
    }
    __syncthreads();

    // ---- P3: write Vt (b128 rows) + K (b128 swizzled) ----
    #pragma unroll
    for (int s = 0; s < 3; ++s) {
        int idx = tid + s * 512;
        if (idx < 1280) {
            int d = idx & 63, rowblk = idx >> 6;
            uint4 ow;
            ow.x = (unsigned)vreg[s][0] | ((unsigned)vreg[s][1] << 16);
            ow.y = (unsigned)vreg[s][2] | ((unsigned)vreg[s][3] << 16);
            ow.z = (unsigned)vreg[s][4] | ((unsigned)vreg[s][5] << 16);
            ow.w = (unsigned)vreg[s][6] | ((unsigned)vreg[s][7] << 16);
            *reinterpret_cast<uint4*>(&VtS[d * 168 + rowblk * 8]) = ow;
        }
    }
    #pragma unroll
    for (int s = 0; s < 3; ++s) {
        int idx = tid + s * 512;
        if (idx < 1280) {
            int row = idx >> 3, ch = idx & 7;
            *reinterpret_cast<uint4*>(&KsS[row * 64 + ((ch ^ (row & 7)) * 8)]) = kreg[s];
        }
    }
    __syncthreads();

    // ---- compute (swapped QK^T, P in regs, Vt b128 B-frags) ----
    f32x4 acc[4];
    #pragma unroll
    for (int dt = 0; dt < 4; ++dt) acc[dt] = (f32x4){0.f, 0.f, 0.f, 0.f};
    float s_sum = 0.f;

    int src0 = lr + ((lg & 1) * 2) * 16;
    int src1 = src0 + 16;
    bool hi = (lg >> 1) != 0;

    for (int kb = 0; kb < 5; ++kb) {
        bf16x8 kf[2][2];
        #pragma unroll
        for (int kvt = 0; kvt < 2; ++kvt)
            #pragma unroll
            for (int ks = 0; ks < 2; ++ks) {
                int row = kb * 32 + kvt * 16 + lr;
                int chunk = ks * 4 + lg;
                int phys = chunk ^ (row & 7);
                kf[kvt][ks] = *reinterpret_cast<const bf16x8*>(&KsS[row * 64 + phys * 8]);
            }
        __builtin_amdgcn_s_setprio(1);
        unsigned pk[2][2];
        #pragma unroll
        for (int kvt = 0; kvt < 2; ++kvt) {
            f32x4 sf = __builtin_amdgcn_mfma_f32_16x16x32_bf16(
                kf[kvt][0], qf[0], (f32x4){0.f,0.f,0.f,0.f}, 0, 0, 0);
            sf = __builtin_amdgcn_mfma_f32_16x16x32_bf16(kf[kvt][1], qf[1], sf, 0, 0, 0);
            float e[4];
            #pragma unroll
            for (int r = 0; r < 4; ++r) {
                int kv = kb * 32 + kvt * 16 + lg * 4 + r;
                e[r] = (kv < KVW) ? __expf(sf[r] * SCALE) : 0.f;
                s_sum += e[r];
            }
            pk[kvt][0] = pk2(e[0], e[1]);
            pk[kvt][1] = pk2(e[2], e[3]);
        }
        unsigned a00 = __shfl(pk[0][0], src0), a01 = __shfl(pk[0][1], src0);
        unsigned a10 = __shfl(pk[1][0], src0), a11 = __shfl(pk[1][1], src0);
        unsigned b00 = __shfl(pk[0][0], src1), b01 = __shfl(pk[0][1], src1);
        unsigned b10 = __shfl(pk[1][0], src1), b11 = __shfl(pk[1][1], src1);
        union { unsigned u[4]; bf16x8 v; } pu;
        pu.u[0] = hi ? a10 : a00;
        pu.u[1] = hi ? a11 : a01;
        pu.u[2] = hi ? b10 : b00;
        pu.u[3] = hi ? b11 : b01;
        #pragma unroll
        for (int dt = 0; dt < 4; ++dt) {
            bf16x8 vf = *reinterpret_cast<const bf16x8*>(
                &VtS[(dt * 16 + lr) * 168 + kb * 32 + lg * 8]);
            acc[dt] = __builtin_amdgcn_mfma_f32_16x16x32_bf16(pu.v, vf, acc[dt], 0, 0, 0);
        }
        __builtin_amdgcn_s_setprio(0);
    }

    s_sum += __shfl_xor(s_sum, 16);
    s_sum += __shfl_xor(s_sum, 32);
    float sinv[4];
    #pragma unroll
    for (int r = 0; r < 4; ++r)
        sinv[r] = 1.f / __shfl(s_sum, lg * 4 + r);

    #pragma unroll
    for (int r = 0; r < 4; ++r) {
        int row = w * 16 + lg * 4 + r;
        float* op = so + (((size_t)blk * WSZW + row) * DD);
        #pragma unroll
        for (int dt = 0; dt < 4; ++dt)
            op[dt * 16 + lr] = acc[dt][r] * sinv[r];
    }
}

// ---------------- Kernel F: per-bh exclusive scan (4096 ints) ----------------
__global__ __launch_bounds__(256) void scan_kernel(
    const int* __restrict__ counts, int* __restrict__ offs)
{
    int bh = blockIdx.x;
    int t = threadIdx.x;
    const int* cb = counts + (size_t)bh * TT;
    int* ob = offs + (size_t)bh * TT;

    int loc[16]; int sum = 0;
    #pragma unroll
    for (int i = 0; i < 16; ++i) { loc[i] = sum; sum += cb[t * 16 + i]; }

    __shared__ int wsum[256];
    wsum[t] = sum;
    __syncthreads();
    for (int off = 1; off < 256; off <<= 1) {
        int vv = (t >= off) ? wsum[t - off] : 0;
        __syncthreads();
        wsum[t] += vv;
        __syncthreads();
    }
    int ex = (t == 0) ? 0 : wsum[t - 1];
    #pragma unroll
    for (int i = 0; i < 16; ++i) ob[t * 16 + i] = ex + loc[i];
}

// ---------------- Kernel G: fill CSR slot lists ----------------
__global__ __launch_bounds__(256) void fill_kernel(
    const int* __restrict__ idxQ, const int* __restrict__ offs,
    int* __restrict__ cur, int* __restrict__ csr)
{
    int i = blockIdx.x * 256 + threadIdx.x;
    int bh = i >> 13;
    int within = i & 8191;
    int tok = idxQ[i];
    int p = offs[bh * TT + tok] + atomicAdd(&cur[bh * TT + tok], 1);
    csr[((size_t)bh << 13) + p] = within;
}

// ---------------- Kernel H: gather-reduce + finalize ----------------
__global__ __launch_bounds__(256) void reduce_kernel(
    const float* __restrict__ so, const int* __restrict__ counts,
    const int* __restrict__ offs, const int* __restrict__ csr,
    float* __restrict__ out)
{
    int gt = blockIdx.x * 4 + (threadIdx.x >> 6);
    int lane = threadIdx.x & 63;
    int bh = gt >> 12;
    int n = counts[gt];
    int st = offs[gt];
    const int* cs = csr + ((size_t)bh << 13);
    float acc = 0.f;
    for (int j = 0; j < n; ++j) {
        int slot = cs[st + j];
        acc += so[(((size_t)bh << 13) + slot) * DD + lane];
    }
    out[(size_t)gt * DD + lane] = acc / ((float)n + EPSF);
}

extern "C" void kernel_launch(void* const* d_in, const int* in_sizes, int n_in,
                              void* d_out, int out_size, void* d_ws, size_t ws_size,
                              hipStream_t stream) {
    const float* q        = (const float*)d_in[0];
    const float* k        = (const float*)d_in[1];
    const float* v        = (const float*)d_in[2];
    const float* means    = (const float*)d_in[3];
    const float* mem_key  = (const float*)d_in[4];
    const float* mem_val  = (const float*)d_in[5];
    float* out = (float*)d_out;

    const size_t nRows = (size_t)BB * HH * NCC;             // 2048
    const size_t nTok  = (size_t)BB * HH * TT;              // 131072
    float* wsf    = (float*)d_ws;
    float* distsQ = wsf;                                    // 8388608 f
    float* distsK = distsQ + (size_t)BB * HH * NCC * TT;    // 8388608 f (contiguous after distsQ)
    float* so     = wsf;                                    // aliases dists; written after rescore
    int*   idxQ   = (int*)(distsK + (size_t)BB * HH * NCC * TT);  // 262144 i
    int*   idxK   = idxQ + nRows * WSZW;                    // 262144 i
    int*   counts = idxK + nRows * WSZW;                    // 131072 i
    int*   cur    = counts + nTok;                          // 131072 i
    float* auxp   = (float*)(cur + nTok);                   // 16384 f (per-wave partials)
    int*   offs   = (int*)(auxp + 16384);                   // 131072 i
    int*   csr    = offs + nTok;                            // 262144 i
    int*   candQ  = csr + nTok * 2;                         // 2048*160 i
    int*   candK  = candQ + nRows * TPK;                    // 2048*160 i (contiguous after candQ)
    uintptr_t ip  = (uintptr_t)(candK + nRows * TPK);
    ip = (ip + 15) & ~(uintptr_t)15;
    double* invn  = (double*)ip;                            // 2*131072 d (Q then K)

    hipMemsetAsync(counts, 0, 2 * nTok * sizeof(int), stream);

    dists_kernel<<<dim3(BB * HH * (2 * TT / 64)), dim3(256), 0, stream>>>(
        q, k, means, distsQ, distsK, auxp, invn);
    aux_reduce_kernel<<<dim3(1), dim3(256), 0, stream>>>(auxp, out);
    // single launch covers Q rows (0..2047 over distsQ/candQ) and K rows
    // (2048..4095 over distsK/candK) via buffer contiguity
    topk_kernel<<<dim3((unsigned)(2 * nRows)), dim3(256), 0, stream>>>(distsQ, candQ);
    rescore_kernel<<<dim3((unsigned)(2 * nRows)), dim3(640), 0, stream>>>(
        q, k, means, invn, candQ, candK, idxQ, idxK, counts);
    scan_kernel<<<dim3(BB * HH), dim3(256), 0, stream>>>(counts, offs);
    fill_kernel<<<dim3(1024), dim3(256), 0, stream>>>(idxQ, offs, cur, csr);
    attn_kernel<<<dim3((unsigned)nRows), dim3(512), 0, stream>>>(
        q, k, v, mem_key, mem_val, idxQ, idxK, so);
    reduce_kernel<<<dim3((unsigned)(nTok / 4)), dim3(256), 0, stream>>>(
        so, counts, offs, csr, out);
}

// Round 17
// 254.083 us; speedup vs baseline: 1.9478x; 1.0106x over previous
//
#include <hip/hip_runtime.h>
#include <math.h>

#define BB 4
#define HH 8
#define TT 4096
#define DD 64
#define NCC 64
#define WSZW 128
#define TPK 160          // widened f32 top-k; f64 rescore picks exact top-128
#define MEMN 1
#define KVW (MEMN + WSZW)   // 129
constexpr float EPSF = 1e-5f;
constexpr float SCALE = 0.125f;  // 64^-0.5

typedef __attribute__((ext_vector_type(8))) short bf16x8;
typedef __attribute__((ext_vector_type(4))) float f32x4;

// HW packed f32->bf16 (RNE), 1 instruction vs ~7 for the manual bit-twiddle
static __device__ __forceinline__ unsigned int pk2(float a, float b) {
    unsigned int r;
    asm("v_cvt_pk_bf16_f32 %0, %1, %2" : "=v"(r) : "v"(a), "v"(b));
    return r;
}
static __device__ __forceinline__ bf16x8 pack8(float4 a, float4 b) {
    union { unsigned int u[4]; bf16x8 v; } r;
    r.u[0] = pk2(a.x, a.y); r.u[1] = pk2(a.z, a.w);
    r.u[2] = pk2(b.x, b.y); r.u[3] = pk2(b.z, b.w);
    return r.v;
}
static __device__ __forceinline__ unsigned mono(float f) {
    unsigned b = __float_as_uint(f);
    return b ^ ((unsigned)(((int)b) >> 31) | 0x80000000u);
}

// ---------------- Kernel A: dists f32 GEMM + argmax + aux + f64 invnorm ---------
__global__ __launch_bounds__(256, 4) void dists_kernel(
    const float* __restrict__ q, const float* __restrict__ k,
    const float* __restrict__ means,
    float* __restrict__ distsQ, float* __restrict__ distsK,
    float* __restrict__ aux_part, double* __restrict__ invn)
{
    __shared__ float xS[64][68];   // [d][tok]; reused as dS[tok][c] after GEMM
    __shared__ float mS[64][68];   // [d][cluster]
    __shared__ float mqS[64];      // per-cluster ||m||^2

    const int chunks = (2 * TT) / 64;          // 128
    int bid = blockIdx.x;                      // 4096
    int bh = bid / chunks;
    int chunk = bid % chunks;
    int h = bh % HH;
    bool isQ = chunk < (TT / 64);
    int tbase = (isQ ? chunk : chunk - 64) * 64;
    const float* src = (isQ ? q : k) + ((size_t)bh * TT + tbase) * DD;
    float* dst = isQ ? distsQ : distsK;
    double* invdst = invn + (isQ ? 0 : (size_t)BB * HH * TT) + (size_t)bh * TT + tbase;

    int tid = threadIdx.x;
    int tok = tid >> 2, part = tid & 3;        // tok doubles as cluster idx below

    // ---- stage means (transposed) + per-cluster sumsq ----
    {
        const float* mp = means + ((size_t)h * NCC + tok) * DD + part * 16;
        float4 va[4];
        #pragma unroll
        for (int i = 0; i < 4; ++i) va[i] = *(const float4*)(mp + i * 4);
        float msq = 0.f;
        #pragma unroll
        for (int i = 0; i < 4; ++i) {
            msq += va[i].x*va[i].x + va[i].y*va[i].y + va[i].z*va[i].z + va[i].w*va[i].w;
            int d = part * 16 + i * 4;
            mS[d][tok] = va[i].x; mS[d+1][tok] = va[i].y;
            mS[d+2][tok] = va[i].z; mS[d+3][tok] = va[i].w;
        }
        msq += __shfl_xor(msq, 1);
        msq += __shfl_xor(msq, 2);
        if (part == 0) mqS[tok] = msq;
    }
    // ---- stage x normalized (transposed); f64 norm, store invnorm ----
    float ssn;
    {
        const float* xp = src + (size_t)tok * DD + part * 16;
        float4 va[4];
        #pragma unroll
        for (int i = 0; i < 4; ++i) va[i] = *(const float4*)(xp + i * 4);
        double ssd = 0.0;
        #pragma unroll
        for (int i = 0; i < 4; ++i)
            ssd += (double)va[i].x*va[i].x + (double)va[i].y*va[i].y
                 + (double)va[i].z*va[i].z + (double)va[i].w*va[i].w;
        ssd += __shfl_xor(ssd, 1);
        ssd += __shfl_xor(ssd, 2);
        double invd = 1.0 / fmax(sqrt(ssd), 1e-12);
        if (part == 0) invdst[tok] = invd;
        float inv = (float)invd;
        ssn = (float)(ssd * invd * invd);
        #pragma unroll
        for (int i = 0; i < 4; ++i) {
            int d = part * 16 + i * 4;
            xS[d][tok] = va[i].x*inv; xS[d+1][tok] = va[i].y*inv;
            xS[d+2][tok] = va[i].z*inv; xS[d+3][tok] = va[i].w*inv;
        }
    }
    __syncthreads();

    // ---- GEMM: thread = 4 tokens x 4 clusters ----
    int l = tid & 63, w = tid >> 6;
    int ti = l & 15;                 // token tile 4*ti..
    int ci = w * 4 + (l >> 4);       // cluster tile 4*ci..
    float acc[4][4];
    #pragma unroll
    for (int i = 0; i < 4; ++i)
        #pragma unroll
        for (int j = 0; j < 4; ++j) acc[i][j] = 0.f;

    #pragma unroll 16
    for (int kk = 0; kk < 64; ++kk) {
        float4 xv = *(const float4*)(&xS[kk][ti * 4]);
        float4 mv = *(const float4*)(&mS[kk][ci * 4]);
        float xa[4] = {xv.x, xv.y, xv.z, xv.w};
        float ma[4] = {mv.x, mv.y, mv.z, mv.w};
        #pragma unroll
        for (int i = 0; i < 4; ++i)
            #pragma unroll
            for (int j = 0; j < 4; ++j) acc[i][j] += xa[i] * ma[j];
    }

    // ---- store dists to global (coalesced float4 over tokens) ----
    {
        size_t rowb = (size_t)(bh * NCC) * TT;
        #pragma unroll
        for (int j = 0; j < 4; ++j) {
            int c = ci * 4 + j;
            float4 o;
            o.x = acc[0][j]; o.y = acc[1][j]; o.z = acc[2][j]; o.w = acc[3][j];
            *(float4*)&dst[rowb + (size_t)c * TT + tbase + ti * 4] = o;
        }
    }

    // ---- argmax + aux via LDS round-trip (reuse xS as dS[tok][c]) ----
    __syncthreads();
    #pragma unroll
    for (int i = 0; i < 4; ++i)
        #pragma unroll
        for (int j = 0; j < 4; ++j)
            xS[ti * 4 + i][ci * 4 + j] = acc[i][j];
    __syncthreads();

    float bv = -1e30f; int bc = 0;
    #pragma unroll
    for (int j = 0; j < 16; ++j) {
        int c = part * 16 + j;
        float vv = xS[tok][c];
        if (vv > bv) { bv = vv; bc = c; }
    }
    #pragma unroll
    for (int off = 1; off <= 2; off <<= 1) {
        float ov = __shfl_xor(bv, off);
        int   oc = __shfl_xor(bc, off);
        if (ov > bv || (ov == bv && oc < bc)) { bv = ov; bc = oc; }
    }
    float auxv = (part == 0) ? (ssn + mqS[bc] - 2.f * bv) : 0.f;
    #pragma unroll
    for (int off = 32; off; off >>= 1) auxv += __shfl_xor(auxv, off);
    if (l == 0) aux_part[bid * 4 + w] = auxv;
}

// ---------------- Kernel A2: reduce 16384 aux partials -> out[N] ----------------
__global__ __launch_bounds__(256) void aux_reduce_kernel(
    const float* __restrict__ aux_part, float* __restrict__ out)
{
    int t = threadIdx.x;
    float s = 0.f;
    for (int i = t; i < 16384; i += 256) s += aux_part[i];
    #pragma unroll
    for (int off = 32; off; off >>= 1) s += __shfl_xor(s, off);
    __shared__ float wsum[4];
    if ((t & 63) == 0) wsum[t >> 6] = s;
    __syncthreads();
    if (t == 0)
        out[(size_t)BB * HH * TT * DD] =
            (wsum[0] + wsum[1] + wsum[2] + wsum[3]) *
            (1.0f / (float)(BB * HH * 2 * TT * DD));
}

// ---------------- Kernel B: top-TPK per row, 3-pass radix (12/12/8 bits) -------
__global__ __launch_bounds__(256) void topk_kernel(
    const float* __restrict__ dists, int* __restrict__ idxOut)
{
    int row = blockIdx.x;
    const float* dv = dists + (size_t)row * TT;
    int t = threadIdx.x;
    int lane = t & 63, w = t >> 6;

    unsigned u[16];
    #pragma unroll
    for (int j0 = 0; j0 < 4; ++j0) {
        float4 f = *(const float4*)(dv + t * 16 + j0 * 4);
        u[j0*4+0] = mono(f.x); u[j0*4+1] = mono(f.y);
        u[j0*4+2] = mono(f.z); u[j0*4+3] = mono(f.w);
    }

    __shared__ int hist[4096];
    __shared__ int wtot[4];
    __shared__ int binSel, tgtS;
    __shared__ int nGtS, posS, eqPos;

    int target = TPK;
    unsigned prefix = 0;

    // ---- passes 1,2: 12-bit digits over 4096 bins ----
    #pragma unroll
    for (int pass = 0; pass < 2; ++pass) {
        int4* hz = (int4*)&hist[t * 16];
        hz[0] = (int4){0,0,0,0}; hz[1] = (int4){0,0,0,0};
        hz[2] = (int4){0,0,0,0}; hz[3] = (int4){0,0,0,0};
        __syncthreads();
        if (pass == 0) {
            #pragma unroll
            for (int j = 0; j < 16; ++j) atomicAdd(&hist[u[j] >> 20], 1);
        } else {
            #pragma unroll
            for (int j = 0; j < 16; ++j)
                if ((u[j] >> 20) == (prefix >> 20))
                    atomicAdd(&hist[(u[j] >> 8) & 0xFFF], 1);
        }
        __syncthreads();
        int cnt[16], ls[16];
        {
            const int4* hp = (const int4*)&hist[t * 16];
            int4 c0 = hp[0], c1 = hp[1], c2 = hp[2], c3 = hp[3];
            cnt[0]=c0.x; cnt[1]=c0.y; cnt[2]=c0.z; cnt[3]=c0.w;
            cnt[4]=c1.x; cnt[5]=c1.y; cnt[6]=c1.z; cnt[7]=c1.w;
            cnt[8]=c2.x; cnt[9]=c2.y; cnt[10]=c2.z; cnt[11]=c2.w;
            cnt[12]=c3.x; cnt[13]=c3.y; cnt[14]=c3.z; cnt[15]=c3.w;
        }
        int run = 0;
        #pragma unroll
        for (int i = 15; i >= 0; --i) { run += cnt[i]; ls[i] = run; }
        int S = run;
        #pragma unroll
        for (int off = 1; off < 64; off <<= 1) {
            int o = __shfl_down(S, off);
            if (lane + off < 64) S += o;
        }
        if (lane == 0) wtot[w] = S;
        __syncthreads();
        int after = 0;
        for (int ww = w + 1; ww < 4; ++ww) after += wtot[ww];
        int St1 = S - run + after;      // suffix of bins owned by later threads
        #pragma unroll
        for (int i = 0; i < 16; ++i) {
            int sfxb = ls[i] + St1;
            if (sfxb >= target && sfxb - cnt[i] < target) {
                binSel = t * 16 + i; tgtS = target - (sfxb - cnt[i]);
            }
        }
        __syncthreads();
        prefix |= (pass == 0) ? ((unsigned)binSel << 20) : ((unsigned)binSel << 8);
        target = tgtS;
        __syncthreads();
    }

    // ---- pass 3: low 8 bits (256 bins) ----
    hist[t] = 0;
    __syncthreads();
    #pragma unroll
    for (int j = 0; j < 16; ++j)
        if ((u[j] >> 8) == (prefix >> 8))
            atomicAdd(&hist[u[j] & 0xFF], 1);
    __syncthreads();
    {
        int cnt = hist[t];
        int S = cnt;
        #pragma unroll
        for (int off = 1; off < 64; off <<= 1) {
            int o = __shfl_down(S, off);
            if (lane + off < 64) S += o;
        }
        if (lane == 0) wtot[w] = S;
        __syncthreads();
        int after = 0;
        for (int ww = w + 1; ww < 4; ++ww) after += wtot[ww];
        int sfx = S + after;
        if (sfx >= target && sfx - cnt < target) { binSel = t; tgtS = target - (sfx - cnt); }
    }
    __syncthreads();
    unsigned pivot = prefix | (unsigned)binSel;

    // ---- epilogue: compact >pivot, then ==pivot (unordered, capped) ----
    if (t == 0) { nGtS = 0; posS = 0; eqPos = 0; }
    __syncthreads();
    int myg = 0;
    #pragma unroll
    for (int j = 0; j < 16; ++j) myg += (u[j] > pivot) ? 1 : 0;
    if (myg) atomicAdd(&nGtS, myg);
    __syncthreads();
    int n_gt = nGtS;
    int n_need = TPK - n_gt;
    int* out = idxOut + (size_t)row * TPK;
    #pragma unroll
    for (int j = 0; j < 16; ++j) {
        if (u[j] > pivot) {
            int p = atomicAdd(&posS, 1);
            out[p] = t * 16 + j;
        } else if (u[j] == pivot) {
            int p = atomicAdd(&eqPos, 1);
            if (p < n_need) out[n_gt + p] = t * 16 + j;
        }
    }
}

// ---------------- Kernel B2: f64 rescore (precomputed invnorm, 2-chain dot) ----
__global__ __launch_bounds__(640) void rescore_kernel(
    const float* __restrict__ q, const float* __restrict__ k,
    const float* __restrict__ means, const double* __restrict__ invn,
    const int* __restrict__ candQ, const int* __restrict__ candK,
    int* __restrict__ idxQ, int* __restrict__ idxK,
    int* __restrict__ counts)
{
    int rid = blockIdx.x;
    int side = rid >> 11;            // 0=Q, 1=K
    int row = rid & 2047;            // bh*NC + c
    int c = row & (NCC - 1);
    int bh = row >> 6;
    int h = bh % HH;

    const int* cand = (side ? candK : candQ) + (size_t)row * TPK;
    int* outIdx     = (side ? idxK : idxQ) + (size_t)row * WSZW;
    const float* xbase = (side ? k : q) + (size_t)bh * TT * DD;
    const double* invp = invn + (side ? (size_t)BB * HH * TT : 0) + (size_t)bh * TT;

    __shared__ double mD[DD];
    __shared__ double vS[TPK];
    __shared__ int    kiS[TPK];
    __shared__ int    rankS[TPK];

    int tid = threadIdx.x;
    if (tid < DD) mD[tid] = (double)means[((size_t)h * NCC + c) * DD + tid];
    __syncthreads();

    int g = tid >> 2;                // candidate 0..159
    int qt = tid & 3;                // quarter-row 0..3
    int tok = cand[g];
    const float* xp = xbase + (size_t)tok * DD + qt * 16;
    double inv = invp[tok];          // 4 lanes same addr -> broadcast
    double d0 = 0.0, d1 = 0.0;
    #pragma unroll
    for (int i = 0; i < 2; ++i) {
        float4 va = *(const float4*)(xp + i * 4);
        int d = qt * 16 + i * 4;
        d0 += (double)va.x * mD[d]   + (double)va.y * mD[d+1]
            + (double)va.z * mD[d+2] + (double)va.w * mD[d+3];
    }
    #pragma unroll
    for (int i = 2; i < 4; ++i) {
        float4 va = *(const float4*)(xp + i * 4);
        int d = qt * 16 + i * 4;
        d1 += (double)va.x * mD[d]   + (double)va.y * mD[d+1]
            + (double)va.z * mD[d+2] + (double)va.w * mD[d+3];
    }
    double dot = d0 + d1;
    dot += __shfl_xor(dot, 1); dot += __shfl_xor(dot, 2);
    double v = dot * inv;
    if (qt == 0) { vS[g] = v; kiS[g] = tok; }
    __syncthreads();

    // rank: each lane counts its 40-candidate quarter, combine in-group
    int rk = 0;
    #pragma unroll 8
    for (int i = 0; i < TPK / 4; ++i) {
        int j = qt * (TPK / 4) + i;
        double vj = vS[j];
        int kj = kiS[j];
        rk += (vj > v || (vj == v && kj < tok)) ? 1 : 0;
    }
    rk += __shfl_xor(rk, 1); rk += __shfl_xor(rk, 2);
    if (qt == 0) rankS[g] = rk;
    __syncthreads();

    if (tid < TPK) {
        int r = rankS[tid];
        if (r < WSZW) {
            outIdx[r] = kiS[tid];
            if (side == 0) atomicAdd(&counts[bh * TT + kiS[tid]], 1);
        }
    }
}

// ---------------- Kernel C: bf16 MFMA attention, chase-free batched staging ----
// All idxK gathers hoisted to entry (one idx window); K+V row gathers issued as
// two batched register windows before any LDS write. Same swizzles/compute as
// round 13-16.
__global__ __launch_bounds__(512, 2) void attn_kernel(
    const float* __restrict__ q, const float* __restrict__ k, const float* __restrict__ v,
    const float* __restrict__ mem_key, const float* __restrict__ mem_value,
    const int* __restrict__ idxQ, const int* __restrict__ idxK,
    float* __restrict__ so)
{
    // XCD-bijective swizzle (2048 % 8 == 0): 256 consecutive blks per XCD
    int bid = blockIdx.x;
    int blk = (bid & 7) * 256 + (bid >> 3);
    int c = blk % NCC;
    int bh = blk / NCC;
    int h = bh % HH;

    __shared__ __align__(16) unsigned short KsS[160 * 64];   // [kv][d] swizzled (temp V in P1/P2)
    __shared__ __align__(16) unsigned short VtS[64 * 168];   // [d][kv], pad 168

    int tid = threadIdx.x;
    int w = tid >> 6, l = tid & 63;
    int lr = l & 15, lg = l >> 4;

    const float* memK = mem_key   + ((size_t)h * NCC + c) * (MEMN * DD);
    const float* memV = mem_value + ((size_t)h * NCC + c) * (MEMN * DD);

    // ---- entry: resolve staging rows + issue ALL token-index gathers ----
    int stRow[3], stCh[3];
    bool stOk[3];
    const float *vsrcR[3], *ksrcR[3];
    #pragma unroll
    for (int s = 0; s < 3; ++s) {
        int idx = tid + s * 512;
        stOk[s] = idx < 1280;
        stRow[s] = idx >> 3; stCh[s] = idx & 7;
        vsrcR[s] = nullptr; ksrcR[s] = nullptr;
        if (stOk[s] && stRow[s] < KVW) {
            if (stRow[s] == 0) { vsrcR[s] = memV; ksrcR[s] = memK; }
            else {
                int tk = idxK[(size_t)blk * WSZW + stRow[s] - 1];
                vsrcR[s] = v + ((size_t)bh * TT + tk) * DD;
                ksrcR[s] = k + ((size_t)bh * TT + tk) * DD;
            }
        }
    }

    // ---- Q frags (independent chase, overlaps everything) ----
    bf16x8 qf[2];
    {
        int tq = idxQ[(size_t)blk * WSZW + w * 16 + lr];
        const float* qp = q + ((size_t)bh * TT + tq) * DD;
        #pragma unroll
        for (int ks = 0; ks < 2; ++ks) {
            float4 a = *(const float4*)(qp + ks * 32 + lg * 8);
            float4 b = *(const float4*)(qp + ks * 32 + lg * 8 + 4);
            qf[ks] = pack8(a, b);
        }
    }

    // ---- V gather window (batched) ----
    uint4 vw[3];
    #pragma unroll
    for (int s = 0; s < 3; ++s) {
        vw[s] = (uint4){0,0,0,0};
        if (vsrcR[s]) {
            float4 a = *(const float4*)(vsrcR[s] + stCh[s] * 8);
            float4 b = *(const float4*)(vsrcR[s] + stCh[s] * 8 + 4);
            vw[s].x = pk2(a.x, a.y); vw[s].y = pk2(a.z, a.w);
            vw[s].z = pk2(b.x, b.y); vw[s].w = pk2(b.z, b.w);
        }
    }
    // ---- K gather window (batched) ----
    uint4 kw[3];
    #pragma unroll
    for (int s = 0; s < 3; ++s) {
        kw[s] = (uint4){0,0,0,0};
        if (ksrcR[s]) {
            float4 a = *(const float4*)(ksrcR[s] + stCh[s] * 8);
            float4 b = *(const float4*)(ksrcR[s] + stCh[s] * 8 + 4);
            kw[s].x = pk2(a.x, a.y); kw[s].y = pk2(a.z, a.w);
            kw[s].z = pk2(b.x, b.y); kw[s].w = pk2(b.z, b.w);
        }
    }

    // ---- P1: V -> row-major swizzled (in KsS space) ----
    #pragma unroll
    for (int s = 0; s < 3; ++s)
        if (stOk[s])
            *reinterpret_cast<uint4*>(
                &KsS[stRow[s] * 64 + ((stCh[s] ^ (stRow[s] & 7)) * 8)]) = vw[s];
    __syncthreads();

    // ---- P2: Vt column segments -> regs (scalar broadcast-class reads) ----
    unsigned short vreg[3][8];
    #pragma unroll
    for (int s = 0; s < 3; ++s) {
        int idx = tid + s * 512;
        if (idx < 1280) {
            int d = idx & 63, rowblk = idx >> 6;
            #pragma unroll
            for (int i = 0; i < 8; ++i) {
                int row = rowblk * 8 + i;
                vreg[s][i] = KsS[row * 64 + (((d >> 3) ^ (row & 7)) * 8) + (d & 7)];
            }
        }
    }
    __syncthreads();

    // ---- P3: write Vt (b128 rows) + K (b128 swizzled) ----
    #pragma unroll
    for (int s = 0; s < 3; ++s) {
        int idx = tid + s * 512;
        if (idx < 1280) {
            int d = idx & 63, rowblk = idx >> 6;
            uint4 ow;
            ow.x = (unsigned)vreg[s][0] | ((unsigned)vreg[s][1] << 16);
            ow.y = (unsigned)vreg[s][2] | ((unsigned)vreg[s][3] << 16);
            ow.z = (unsigned)vreg[s][4] | ((unsigned)vreg[s][5] << 16);
            ow.w = (unsigned)vreg[s][6] | ((unsigned)vreg[s][7] << 16);
            *reinterpret_cast<uint4*>(&VtS[d * 168 + rowblk * 8]) = ow;
        }
    }
    #pragma unroll
    for (int s = 0; s < 3; ++s)
        if (stOk[s])
            *reinterpret_cast<uint4*>(
                &KsS[stRow[s] * 64 + ((stCh[s] ^ (stRow[s] & 7)) * 8)]) = kw[s];
    __syncthreads();

    // ---- compute (swapped QK^T, P in regs, Vt b128 B-frags) ----
    f32x4 acc[4];
    #pragma unroll
    for (int dt = 0; dt < 4; ++dt) acc[dt] = (f32x4){0.f, 0.f, 0.f, 0.f};
    float s_sum = 0.f;

    int src0 = lr + ((lg & 1) * 2) * 16;
    int src1 = src0 + 16;
    bool hi = (lg >> 1) != 0;

    for (int kb = 0; kb < 5; ++kb) {
        bf16x8 kf[2][2];
        #pragma unroll
        for (int kvt = 0; kvt < 2; ++kvt)
            #pragma unroll
            for (int ks = 0; ks < 2; ++ks) {
                int row = kb * 32 + kvt * 16 + lr;
                int chunk = ks * 4 + lg;
                int phys = chunk ^ (row & 7);
                kf[kvt][ks] = *reinterpret_cast<const bf16x8*>(&KsS[row * 64 + phys * 8]);
            }
        __builtin_amdgcn_s_setprio(1);
        unsigned pk[2][2];
        #pragma unroll
        for (int kvt = 0; kvt < 2; ++kvt) {
            f32x4 sf = __builtin_amdgcn_mfma_f32_16x16x32_bf16(
                kf[kvt][0], qf[0], (f32x4){0.f,0.f,0.f,0.f}, 0, 0, 0);
            sf = __builtin_amdgcn_mfma_f32_16x16x32_bf16(kf[kvt][1], qf[1], sf, 0, 0, 0);
            float e[4];
            #pragma unroll
            for (int r = 0; r < 4; ++r) {
                int kv = kb * 32 + kvt * 16 + lg * 4 + r;
                e[r] = (kv < KVW) ? __expf(sf[r] * SCALE) : 0.f;
                s_sum += e[r];
            }
            pk[kvt][0] = pk2(e[0], e[1]);
            pk[kvt][1] = pk2(e[2], e[3]);
        }
        unsigned a00 = __shfl(pk[0][0], src0), a01 = __shfl(pk[0][1], src0);
        unsigned a10 = __shfl(pk[1][0], src0), a11 = __shfl(pk[1][1], src0);
        unsigned b00 = __shfl(pk[0][0], src1), b01 = __shfl(pk[0][1], src1);
        unsigned b10 = __shfl(pk[1][0], src1), b11 = __shfl(pk[1][1], src1);
        union { unsigned u[4]; bf16x8 v; } pu;
        pu.u[0] = hi ? a10 : a00;
        pu.u[1] = hi ? a11 : a01;
        pu.u[2] = hi ? b10 : b00;
        pu.u[3] = hi ? b11 : b01;
        #pragma unroll
        for (int dt = 0; dt < 4; ++dt) {
            bf16x8 vf = *reinterpret_cast<const bf16x8*>(
                &VtS[(dt * 16 + lr) * 168 + kb * 32 + lg * 8]);
            acc[dt] = __builtin_amdgcn_mfma_f32_16x16x32_bf16(pu.v, vf, acc[dt], 0, 0, 0);
        }
        __builtin_amdgcn_s_setprio(0);
    }

    s_sum += __shfl_xor(s_sum, 16);
    s_sum += __shfl_xor(s_sum, 32);
    float sinv[4];
    #pragma unroll
    for (int r = 0; r < 4; ++r)
        sinv[r] = 1.f / __shfl(s_sum, lg * 4 + r);

    #pragma unroll
    for (int r = 0; r < 4; ++r) {
        int row = w * 16 + lg * 4 + r;
        float* op = so + (((size_t)blk * WSZW + row) * DD);
        #pragma unroll
        for (int dt = 0; dt < 4; ++dt)
            op[dt * 16 + lr] = acc[dt][r] * sinv[r];
    }
}

// ---------------- Kernel F: per-bh exclusive scan (4096 ints) ----------------
__global__ __launch_bounds__(256) void scan_kernel(
    const int* __restrict__ counts, int* __restrict__ offs)
{
    int bh = blockIdx.x;
    int t = threadIdx.x;
    const int* cb = counts + (size_t)bh * TT;
    int* ob = offs + (size_t)bh * TT;

    int loc[16]; int sum = 0;
    #pragma unroll
    for (int i = 0; i < 16; ++i) { loc[i] = sum; sum += cb[t * 16 + i]; }

    __shared__ int wsum[256];
    wsum[t] = sum;
    __syncthreads();
    for (int off = 1; off < 256; off <<= 1) {
        int vv = (t >= off) ? wsum[t - off] : 0;
        __syncthreads();
        wsum[t] += vv;
        __syncthreads();
    }
    int ex = (t == 0) ? 0 : wsum[t - 1];
    #pragma unroll
    for (int i = 0; i < 16; ++i) ob[t * 16 + i] = ex + loc[i];
}

// ---------------- Kernel G: fill CSR slot lists ----------------
__global__ __launch_bounds__(256) void fill_kernel(
    const int* __restrict__ idxQ, const int* __restrict__ offs,
    int* __restrict__ cur, int* __restrict__ csr)
{
    int i = blockIdx.x * 256 + threadIdx.x;
    int bh = i >> 13;
    int within = i & 8191;
    int tok = idxQ[i];
    int p = offs[bh * TT + tok] + atomicAdd(&cur[bh * TT + tok], 1);
    csr[((size_t)bh << 13) + p] = within;
}

// ---------------- Kernel H: gather-reduce + finalize ----------------
__global__ __launch_bounds__(256) void reduce_kernel(
    const float* __restrict__ so, const int* __restrict__ counts,
    const int* __restrict__ offs, const int* __restrict__ csr,
    float* __restrict__ out)
{
    int gt = blockIdx.x * 4 + (threadIdx.x >> 6);
    int lane = threadIdx.x & 63;
    int bh = gt >> 12;
    int n = counts[gt];
    int st = offs[gt];
    const int* cs = csr + ((size_t)bh << 13);
    float acc = 0.f;
    for (int j = 0; j < n; ++j) {
        int slot = cs[st + j];
        acc += so[(((size_t)bh << 13) + slot) * DD + lane];
    }
    out[(size_t)gt * DD + lane] = acc / ((float)n + EPSF);
}

extern "C" void kernel_launch(void* const* d_in, const int* in_sizes, int n_in,
                              void* d_out, int out_size, void* d_ws, size_t ws_size,
                              hipStream_t stream) {
    const float* q        = (const float*)d_in[0];
    const float* k        = (const float*)d_in[1];
    const float* v        = (const float*)d_in[2];
    const float* means    = (const float*)d_in[3];
    const float* mem_key  = (const float*)d_in[4];
    const float* mem_val  = (const float*)d_in[5];
    float* out = (float*)d_out;

    const size_t nRows = (size_t)BB * HH * NCC;             // 2048
    const size_t nTok  = (size_t)BB * HH * TT;              // 131072
    float* wsf    = (float*)d_ws;
    float* distsQ = wsf;                                    // 8388608 f
    float* distsK = distsQ + (size_t)BB * HH * NCC * TT;    // 8388608 f (contiguous after distsQ)
    float* so     = wsf;                                    // aliases dists; written after rescore
    int*   idxQ   = (int*)(distsK + (size_t)BB * HH * NCC * TT);  // 262144 i
    int*   idxK   = idxQ + nRows * WSZW;                    // 262144 i
    int*   counts = idxK + nRows * WSZW;                    // 131072 i
    int*   cur    = counts + nTok;                          // 131072 i
    float* auxp   = (float*)(cur + nTok);                   // 16384 f (per-wave partials)
    int*   offs   = (int*)(auxp + 16384);                   // 131072 i
    int*   csr    = offs + nTok;                            // 262144 i
    int*   candQ  = csr + nTok * 2;                         // 2048*160 i
    int*   candK  = candQ + nRows * TPK;                    // 2048*160 i (contiguous after candQ)
    uintptr_t ip  = (uintptr_t)(candK + nRows * TPK);
    ip = (ip + 15) & ~(uintptr_t)15;
    double* invn  = (double*)ip;                            // 2*131072 d (Q then K)

    hipMemsetAsync(counts, 0, 2 * nTok * sizeof(int), stream);

    dists_kernel<<<dim3(BB * HH * (2 * TT / 64)), dim3(256), 0, stream>>>(
        q, k, means, distsQ, distsK, auxp, invn);
    aux_reduce_kernel<<<dim3(1), dim3(256), 0, stream>>>(auxp, out);
    // single launch covers Q rows (0..2047 over distsQ/candQ) and K rows
    // (2048..4095 over distsK/candK) via buffer contiguity
    topk_kernel<<<dim3((unsigned)(2 * nRows)), dim3(256), 0, stream>>>(distsQ, candQ);
    rescore_kernel<<<dim3((unsigned)(2 * nRows)), dim3(640), 0, stream>>>(
        q, k, means, invn, candQ, candK, idxQ, idxK, counts);
    scan_kernel<<<dim3(BB * HH), dim3(256), 0, stream>>>(counts, offs);
    fill_kernel<<<dim3(1024), dim3(256), 0, stream>>>(idxQ, offs, cur, csr);
    attn_kernel<<<dim3((unsigned)nRows), dim3(512), 0, stream>>>(
        q, k, v, mem_key, mem_val, idxQ, idxK, so);
    reduce_kernel<<<dim3((unsigned)(nTok / 4)), dim3(256), 0, stream>>>(
        so, counts, offs, csr, out);
}